// Round 10
// baseline (6922.855 us; speedup 1.0000x reference)
//
#include <hip/hip_runtime.h>
#include <cmath>

// Problem constants
#define Bb   64
#define Tt   128
#define Dd   2048
#define Hh   512
#define Gg   2048      // 4*H
#define Cc   101
#define ROWS 8192      // B*T

typedef unsigned short u16;
typedef __attribute__((ext_vector_type(8))) short bf16x8;
typedef __attribute__((ext_vector_type(4))) float f32x4;

// ---------------- bf16 hi/lo split helpers ----------------
__device__ __forceinline__ u16 bf16rne(float x) {
  unsigned u = __float_as_uint(x);
  unsigned r = (u + 0x7fffu + ((u >> 16) & 1u)) >> 16;
  return (u16)r;
}
__device__ __forceinline__ void split_bf16(float x, u16& h, u16& l) {
  h = bf16rne(x);
  l = bf16rne(x - __uint_as_float(((unsigned)h) << 16));
}
__device__ __forceinline__ float sigm(float x) { return 1.f / (1.f + expf(-x)); }

__device__ __forceinline__ f32x4 mm3(f32x4 acc, bf16x8 ah, bf16x8 al,
                                     bf16x8 bh, bf16x8 bl) {
  acc = __builtin_amdgcn_mfma_f32_16x16x32_bf16(ah, bh, acc, 0, 0, 0);
  acc = __builtin_amdgcn_mfma_f32_16x16x32_bf16(ah, bl, acc, 0, 0, 0);
  acc = __builtin_amdgcn_mfma_f32_16x16x32_bf16(al, bh, acc, 0, 0, 0);
  return acc;
}

// X [ROWS x Dd] fp32 -> Xhi, Xlo bf16 (same layout)
__global__ __launch_bounds__(256)
void convert_hilo(const float* __restrict__ src, u16* __restrict__ hi,
                  u16* __restrict__ lo, int n4) {
  for (int i = blockIdx.x * 256 + threadIdx.x; i < n4; i += gridDim.x * 256) {
    const float4 v = ((const float4*)src)[i];
    ushort4 h, l;
    split_bf16(v.x, h.x, l.x);
    split_bf16(v.y, h.y, l.y);
    split_bf16(v.z, h.z, l.z);
    split_bf16(v.w, h.w, l.w);
    ((ushort4*)hi)[i] = h;
    ((ushort4*)lo)[i] = l;
  }
}

// W1 top [Dd x Gg] -> W1T hi/lo [Gg x Dd] bf16  (for gemm1 B operand)
__global__ __launch_bounds__(256)
void convertT_w1(const float* __restrict__ W1, u16* __restrict__ Th,
                 u16* __restrict__ Tl) {
  __shared__ float tl[32][33];
  const int tx = threadIdx.x, ty = threadIdx.y;   // 32, 8
  const int k0 = blockIdx.x * 32, c0 = blockIdx.y * 32;
#pragma unroll
  for (int j = 0; j < 4; ++j)
    tl[ty + j * 8][tx] = W1[(size_t)(k0 + ty + j * 8) * Gg + (c0 + tx)];
  __syncthreads();
#pragma unroll
  for (int j = 0; j < 4; ++j) {
    const float v = tl[tx][ty + j * 8];
    u16 h, l;
    split_bf16(v, h, l);
    const size_t o = (size_t)(c0 + ty + j * 8) * Dd + (k0 + tx);
    Th[o] = h;
    Tl[o] = l;
  }
}

// Recurrent weights, permuted + split for the persistent kernel:
// WQ[cb 32][vc 64][K], vc = gate*16 + ml for col = gate*512 + cb*16 + ml.
__global__ __launch_bounds__(256)
void permuteW2(const float* __restrict__ src, u16* __restrict__ dh,
               u16* __restrict__ dl, int K) {
  __shared__ float tl[32][33];
  const int tx = threadIdx.x, ty = threadIdx.y;   // 32, 8
  const int k0 = blockIdx.x * 32, c0 = blockIdx.y * 32;
#pragma unroll
  for (int j = 0; j < 4; ++j)
    tl[ty + j * 8][tx] = src[(size_t)(k0 + ty + j * 8) * Gg + (c0 + tx)];
  __syncthreads();
#pragma unroll
  for (int j = 0; j < 4; ++j) {
    const int col  = c0 + ty + j * 8;
    const int gate = col >> 9, hcol = col & 511;
    const int cb = hcol >> 4, ml = hcol & 15;
    const float v = tl[tx][ty + j * 8];
    u16 h, l;
    split_bf16(v, h, l);
    const size_t o = ((size_t)cb * 64 + gate * 16 + ml) * K + k0 + tx;
    dh[o] = h;
    dl[o] = l;
  }
}

__global__ void init_bar(unsigned* bar) {
  if (threadIdx.x < 64) bar[threadIdx.x] = 0;
}

// ---------------- MFMA bf16x3 GEMM: pre = X @ W1 + b1 ----------------
__global__ __launch_bounds__(256)
void gemm1_mfma(const u16* __restrict__ Ah, const u16* __restrict__ Al,
                const u16* __restrict__ Bh, const u16* __restrict__ Bl,
                const float* __restrict__ bias, float* __restrict__ C) {
  __shared__ u16 Ash[128][40];
  __shared__ u16 Asl[128][40];
  __shared__ u16 Bsh[128][40];
  __shared__ u16 Bsl[128][40];
  const int tid  = threadIdx.x;
  const int lane = tid & 63, wave = tid >> 6;
  const int wm = wave >> 1, wn = wave & 1;
  const int l15 = lane & 15, k8 = (lane >> 4) * 8, r4 = (lane >> 4) * 4;
  const int row0 = blockIdx.y * 128, col0 = blockIdx.x * 128;
  const int srow = tid >> 1, sk = (tid & 1) * 16;

  const u16* pAh = Ah + (size_t)(row0 + srow) * Dd + sk;
  const u16* pAl = Al + (size_t)(row0 + srow) * Dd + sk;
  const u16* pBh = Bh + (size_t)(col0 + srow) * Dd + sk;
  const u16* pBl = Bl + (size_t)(col0 + srow) * Dd + sk;

  f32x4 acc[4][4];
#pragma unroll
  for (int i = 0; i < 4; ++i)
#pragma unroll
    for (int j = 0; j < 4; ++j) acc[i][j] = (f32x4){0.f, 0.f, 0.f, 0.f};

  for (int k0 = 0; k0 < Dd; k0 += 32) {
    *(bf16x8*)(&Ash[srow][sk])     = *(const bf16x8*)(pAh + k0);
    *(bf16x8*)(&Ash[srow][sk + 8]) = *(const bf16x8*)(pAh + k0 + 8);
    *(bf16x8*)(&Asl[srow][sk])     = *(const bf16x8*)(pAl + k0);
    *(bf16x8*)(&Asl[srow][sk + 8]) = *(const bf16x8*)(pAl + k0 + 8);
    *(bf16x8*)(&Bsh[srow][sk])     = *(const bf16x8*)(pBh + k0);
    *(bf16x8*)(&Bsh[srow][sk + 8]) = *(const bf16x8*)(pBh + k0 + 8);
    *(bf16x8*)(&Bsl[srow][sk])     = *(const bf16x8*)(pBl + k0);
    *(bf16x8*)(&Bsl[srow][sk + 8]) = *(const bf16x8*)(pBl + k0 + 8);
    __syncthreads();

    bf16x8 afh[4], afl[4], bfh[4], bfl[4];
#pragma unroll
    for (int mt = 0; mt < 4; ++mt) {
      afh[mt] = *(const bf16x8*)(&Ash[wm * 64 + mt * 16 + l15][k8]);
      afl[mt] = *(const bf16x8*)(&Asl[wm * 64 + mt * 16 + l15][k8]);
    }
#pragma unroll
    for (int nt = 0; nt < 4; ++nt) {
      bfh[nt] = *(const bf16x8*)(&Bsh[wn * 64 + nt * 16 + l15][k8]);
      bfl[nt] = *(const bf16x8*)(&Bsl[wn * 64 + nt * 16 + l15][k8]);
    }
#pragma unroll
    for (int mt = 0; mt < 4; ++mt)
#pragma unroll
      for (int nt = 0; nt < 4; ++nt) {
        acc[mt][nt] = __builtin_amdgcn_mfma_f32_16x16x32_bf16(
            afh[mt], bfh[nt], acc[mt][nt], 0, 0, 0);
        acc[mt][nt] = __builtin_amdgcn_mfma_f32_16x16x32_bf16(
            afh[mt], bfl[nt], acc[mt][nt], 0, 0, 0);
        acc[mt][nt] = __builtin_amdgcn_mfma_f32_16x16x32_bf16(
            afl[mt], bfh[nt], acc[mt][nt], 0, 0, 0);
      }
    __syncthreads();
  }

#pragma unroll
  for (int nt = 0; nt < 4; ++nt) {
    const int col = col0 + wn * 64 + nt * 16 + l15;
    const float bj = bias[col];
#pragma unroll
    for (int mt = 0; mt < 4; ++mt) {
      float* Cp = C + (size_t)(row0 + wm * 64 + mt * 16 + r4) * Gg + col;
#pragma unroll
      for (int r = 0; r < 4; ++r)
        Cp[(size_t)r * Gg] = acc[mt][nt][r] + bj;
    }
  }
}

// ---------------- SGEMM (fp32 fallback if ws too small) ----------------
#define BM 128
#define BN 128
#define BK 16

__global__ __launch_bounds__(256)
void sgemm_bias(const float* __restrict__ A, const float* __restrict__ B,
                const float* __restrict__ bias, float* __restrict__ C,
                int M, int N, int K) {
  __shared__ float As[BK][BM];
  __shared__ float Bs[BK][BN];
  const int tid  = threadIdx.x;
  const int row0 = blockIdx.y * BM, col0 = blockIdx.x * BN;
  const int tr = (tid >> 4) << 3;
  const int tc = (tid & 15) << 3;

  float acc[8][8];
#pragma unroll
  for (int i = 0; i < 8; ++i)
#pragma unroll
    for (int j = 0; j < 8; ++j) acc[i][j] = 0.f;

  const int arow = tid >> 1;
  const int acol = (tid & 1) << 3;
  const int brow = tid >> 4;
  const int bcol = (tid & 15) << 3;
  const float* Ap = A + (size_t)(row0 + arow) * K + acol;
  const float* Bp = B + (size_t)brow * N + (col0 + bcol);

  for (int k0 = 0; k0 < K; k0 += BK) {
    const float4 a0 = *(const float4*)(Ap + k0);
    const float4 a1 = *(const float4*)(Ap + k0 + 4);
    const float4 bv0 = *(const float4*)(Bp + (size_t)k0 * N);
    const float4 bv1 = *(const float4*)(Bp + (size_t)k0 * N + 4);
    As[acol + 0][arow] = a0.x;
    As[acol + 1][arow] = a0.y;
    As[acol + 2][arow] = a0.z;
    As[acol + 3][arow] = a0.w;
    As[acol + 4][arow] = a1.x;
    As[acol + 5][arow] = a1.y;
    As[acol + 6][arow] = a1.z;
    As[acol + 7][arow] = a1.w;
    *(float4*)(&Bs[brow][bcol])     = bv0;
    *(float4*)(&Bs[brow][bcol + 4]) = bv1;
    __syncthreads();
#pragma unroll
    for (int k = 0; k < BK; ++k) {
      float a[8], b[8];
      *(float4*)(a)     = *(const float4*)(&As[k][tr]);
      *(float4*)(a + 4) = *(const float4*)(&As[k][tr + 4]);
      *(float4*)(b)     = *(const float4*)(&Bs[k][tc]);
      *(float4*)(b + 4) = *(const float4*)(&Bs[k][tc + 4]);
#pragma unroll
      for (int i = 0; i < 8; ++i)
#pragma unroll
        for (int j = 0; j < 8; ++j)
          acc[i][j] = fmaf(a[i], b[j], acc[i][j]);
    }
    __syncthreads();
  }

  float bj[8];
#pragma unroll
  for (int j = 0; j < 8; ++j) bj[j] = bias[col0 + tc + j];
#pragma unroll
  for (int i = 0; i < 8; ++i) {
    float* Cp = C + (size_t)(row0 + tr + i) * N + (col0 + tc);
    float4 o0, o1;
    o0.x = acc[i][0] + bj[0]; o0.y = acc[i][1] + bj[1];
    o0.z = acc[i][2] + bj[2]; o0.w = acc[i][3] + bj[3];
    o1.x = acc[i][4] + bj[4]; o1.y = acc[i][5] + bj[5];
    o1.z = acc[i][6] + bj[6]; o1.w = acc[i][7] + bj[7];
    *(float4*)(Cp)     = o0;
    *(float4*)(Cp + 4) = o1;
  }
}

// ---------------- persistent recurrence, per-batch-group barriers --------
// 128 blocks = 4 batch-groups x 32 col-blocks; 512 thr = 8 waves.
// Block (grp, cb): batches grp*16.., h-cols cb*16.. for BOTH layers.
// Waves 0-3: L1 gate nf (K=512). Waves 4-7: L2 gate nf (K=1024 = [h1;h2]).
// Cell state in registers. Sync: 32-block barrier per group per phase
// (batch groups are fully independent -> no global barrier).
__global__ __launch_bounds__(512)
void lstm_persist(const float* __restrict__ pre,
                  const u16* __restrict__ WQ1h, const u16* __restrict__ WQ1l,
                  const u16* __restrict__ WQ2h, const u16* __restrict__ WQ2l,
                  const float* __restrict__ b2,
                  u16* __restrict__ h1hi, u16* __restrict__ h1lo,
                  u16* __restrict__ h2hi, u16* __restrict__ h2lo,
                  float* __restrict__ h2all, unsigned* __restrict__ bar) {
  __shared__ float ex[2][64][17];
  const int tid  = threadIdx.x;
  const int lane = tid & 63, w = tid >> 6;
  const int grp = blockIdx.x >> 5;          // 0..3
  const int cb  = blockIdx.x & 31;          // 0..31
  const int b0  = grp * 16;
  const int nf  = w & 3;                    // gate index for this wave
  const bool isL1w = (w < 4);
  const int l15 = lane & 15, f8 = (lane >> 4) * 8, r4 = (lane >> 4) * 4;

  // B-frag row pointers (phase-invariant): WQ row = cb*64 + nf*16 + l15
  const u16* B1h = WQ1h + ((size_t)cb * 64 + nf * 16 + l15) * 512 + f8;
  const u16* B1l = WQ1l + ((size_t)cb * 64 + nf * 16 + l15) * 512 + f8;
  const u16* B2h = WQ2h + ((size_t)cb * 64 + nf * 16 + l15) * 1024 + f8;
  const u16* B2l = WQ2l + ((size_t)cb * 64 + nf * 16 + l15) * 1024 + f8;

  // epilogue ownership: tid<256 -> L1 (b=eb, m=em); tid>=256 -> L2
  const int eb = (tid >> 4) & 15;
  const int em = tid & 15;
  const int hcol = cb * 16 + em;
  const int hoff = (b0 + eb) * 512 + hcol;   // offset within one ring slot
  float b2i = 0.f, b2j = 0.f, b2f = 0.f, b2o = 0.f;
  if (tid >= 256) {
    b2i = b2[hcol];        b2j = b2[512 + hcol];
    b2f = b2[1024 + hcol]; b2o = b2[1536 + hcol];
  }
  float c1r = 0.f, c2r = 0.f;

  for (int t = 0; t <= Tt; ++t) {
    // L1 epilogue inputs (prefetch; hidden under matmul)
    float p0 = 0.f, p1 = 0.f, p2 = 0.f, p3 = 0.f;
    if (tid < 256 && t < Tt) {
      const float* pp = pre + ((size_t)(b0 + eb) * Tt + t) * Gg + hcol;
      p0 = pp[0]; p1 = pp[512]; p2 = pp[1024]; p3 = pp[1536];
    }

    f32x4 ae = {0.f, 0.f, 0.f, 0.f}, ao = {0.f, 0.f, 0.f, 0.f};
    if (isL1w) {
      if (t > 0 && t < Tt) {
        const int sl = (t - 1) & 1;
        const u16* A_h = h1hi + (sl << 15) + (b0 + l15) * 512 + f8;
        const u16* A_l = h1lo + (sl << 15) + (b0 + l15) * 512 + f8;
#pragma unroll
        for (int kc = 0; kc < 16; ++kc) {
          const bf16x8 ah = *(const bf16x8*)(A_h + kc * 32);
          const bf16x8 al = *(const bf16x8*)(A_l + kc * 32);
          const bf16x8 bh = *(const bf16x8*)(B1h + kc * 32);
          const bf16x8 bl = *(const bf16x8*)(B1l + kc * 32);
          if (kc & 1) ao = mm3(ao, ah, al, bh, bl);
          else        ae = mm3(ae, ah, al, bh, bl);
        }
      }
    } else {
      if (t >= 1) {
        {  // K half 1: h1[t-1] @ W2[0:512]
          const int sl = (t - 1) & 1;
          const u16* A_h = h1hi + (sl << 15) + (b0 + l15) * 512 + f8;
          const u16* A_l = h1lo + (sl << 15) + (b0 + l15) * 512 + f8;
#pragma unroll
          for (int kc = 0; kc < 16; ++kc) {
            const bf16x8 ah = *(const bf16x8*)(A_h + kc * 32);
            const bf16x8 al = *(const bf16x8*)(A_l + kc * 32);
            const bf16x8 bh = *(const bf16x8*)(B2h + kc * 32);
            const bf16x8 bl = *(const bf16x8*)(B2l + kc * 32);
            if (kc & 1) ao = mm3(ao, ah, al, bh, bl);
            else        ae = mm3(ae, ah, al, bh, bl);
          }
        }
        if (t >= 2) {  // K half 2: h2[t-2] @ W2[512:1024]
          const int sl = (t - 2) & 1;
          const u16* A_h = h2hi + (sl << 15) + (b0 + l15) * 512 + f8;
          const u16* A_l = h2lo + (sl << 15) + (b0 + l15) * 512 + f8;
#pragma unroll
          for (int kc = 0; kc < 16; ++kc) {
            const bf16x8 ah = *(const bf16x8*)(A_h + kc * 32);
            const bf16x8 al = *(const bf16x8*)(A_l + kc * 32);
            const bf16x8 bh = *(const bf16x8*)(B2h + 512 + kc * 32);
            const bf16x8 bl = *(const bf16x8*)(B2l + 512 + kc * 32);
            if (kc & 1) ao = mm3(ao, ah, al, bh, bl);
            else        ae = mm3(ae, ah, al, bh, bl);
          }
        }
      }
    }

    // publish: ex[side][vc = nf*16 + (C col = l15)][batch = r4 + r]
    const int side = isL1w ? 0 : 1;
#pragma unroll
    for (int r = 0; r < 4; ++r)
      ex[side][nf * 16 + l15][r4 + r] = ae[r] + ao[r];
    __syncthreads();

    // epilogues (256 threads each side); c-state lives in registers
    if (tid < 256) {
      if (t < Tt) {
        const float gi = p0 + ex[0][em][eb];
        const float gj = p1 + ex[0][16 + em][eb];
        const float gf = p2 + ex[0][32 + em][eb];
        const float go = p3 + ex[0][48 + em][eb];
        c1r = fmaf(c1r, sigm(gf + 1.f), sigm(gi) * tanhf(gj));
        const float nh = tanhf(c1r) * sigm(go);
        u16 hh, hl;
        split_bf16(nh, hh, hl);
        h1hi[((t & 1) << 15) + hoff] = hh;
        h1lo[((t & 1) << 15) + hoff] = hl;
      }
    } else {
      if (t >= 1) {
        const float gi = b2i + ex[1][em][eb];
        const float gj = b2j + ex[1][16 + em][eb];
        const float gf = b2f + ex[1][32 + em][eb];
        const float go = b2o + ex[1][48 + em][eb];
        c2r = fmaf(c2r, sigm(gf + 1.f), sigm(gi) * tanhf(gj));
        const float nh = tanhf(c2r) * sigm(go);
        h2all[((size_t)(b0 + eb) * Tt + (t - 1)) * Hh + hcol] = nh;
        u16 hh, hl;
        split_bf16(nh, hh, hl);
        h2hi[(((t - 1) & 1) << 15) + hoff] = hh;
        h2lo[(((t - 1) & 1) << 15) + hoff] = hl;
      }
    }

    // per-group barrier (32 blocks). R4-proven fence pattern, 8x less
    // contention (per-group counters on separate cachelines).
    if (t < Tt) {
      __syncthreads();
      __threadfence();                       // release (every wave)
      if (tid == 0) {
        __hip_atomic_fetch_add(&bar[grp * 16], 1u, __ATOMIC_ACQ_REL,
                               __HIP_MEMORY_SCOPE_AGENT);
        const unsigned tgt = (unsigned)(t + 1) * 32u;
        while (__hip_atomic_load(&bar[grp * 16], __ATOMIC_ACQUIRE,
                                 __HIP_MEMORY_SCOPE_AGENT) < tgt)
          __builtin_amdgcn_s_sleep(2);
      }
      __syncthreads();
      __threadfence();                       // acquire (every wave)
    }
  }
}

// ---------------- Output projection + softmax + CE ----------------
__global__ __launch_bounds__(128)
void proj_softmax(const float* __restrict__ h2, const float* __restrict__ Wout,
                  const float* __restrict__ bout, const int* __restrict__ labels,
                  float* __restrict__ preds, float* __restrict__ ce) {
  __shared__ float hs[8][Hh];
  __shared__ float wred[2][2];
  const int tid = threadIdx.x;
  const int wid = tid >> 6;
  const int r0  = blockIdx.x * 8;

  for (int i = tid; i < 8 * (Hh / 4); i += 128) {
    const int row = i >> 7;
    const int c4  = i & 127;
    ((float4*)hs[row])[c4] =
        ((const float4*)(h2 + ((size_t)(r0 + row) * Hh)))[c4];
  }
  __syncthreads();

  const bool act = (tid < Cc);
  float acc[8];
  {
    const float bj = act ? bout[tid] : 0.f;
#pragma unroll
    for (int i = 0; i < 8; ++i) acc[i] = bj;
  }
  if (act) {
#pragma unroll 4
    for (int k = 0; k < Hh; ++k) {
      const float w = Wout[k * Cc + tid];
#pragma unroll
      for (int i = 0; i < 8; ++i) acc[i] = fmaf(hs[i][k], w, acc[i]);
    }
  }

  for (int row = 0; row < 8; ++row) {
    const float v = act ? acc[row] : -INFINITY;
    float mw = v;
#pragma unroll
    for (int off = 32; off > 0; off >>= 1) mw = fmaxf(mw, __shfl_xor(mw, off));
    if ((tid & 63) == 0) wred[0][wid] = mw;
    __syncthreads();
    const float mx = fmaxf(wred[0][0], wred[0][1]);
    const float e = act ? expf(v - mx) : 0.f;
    float sw = e;
#pragma unroll
    for (int off = 32; off > 0; off >>= 1) sw += __shfl_xor(sw, off);
    if ((tid & 63) == 0) wred[1][wid] = sw;
    __syncthreads();
    const float sum = wred[1][0] + wred[1][1];
    if (act) preds[(size_t)(r0 + row) * Cc + tid] = e / sum;
    const int lab = labels[r0 + row];
    if (tid == lab) ce[r0 + row] = logf(sum) + mx - v;
    __syncthreads();
  }
}

__global__ __launch_bounds__(256)
void reduce_cost(const float* __restrict__ ce, float* __restrict__ out) {
  __shared__ float red[256];
  const int tid = threadIdx.x;
  float s = 0.f;
  for (int i = tid; i < ROWS; i += 256) s += ce[i];
  red[tid] = s;
  __syncthreads();
  for (int st = 128; st > 0; st >>= 1) {
    if (tid < st) red[tid] += red[tid + st];
    __syncthreads();
  }
  if (tid == 0) out[0] = red[0] / (float)Bb;
}

// ---------------- launch ----------------
extern "C" void kernel_launch(void* const* d_in, const int* in_sizes, int n_in,
                              void* d_out, int out_size, void* d_ws, size_t ws_size,
                              hipStream_t stream) {
  const float* inputs = (const float*)d_in[0];
  const int*   labels = (const int*)d_in[1];
  const float* W1     = (const float*)d_in[2];
  const float* b1     = (const float*)d_in[3];
  const float* W2     = (const float*)d_in[4];
  const float* b2     = (const float*)d_in[5];
  const float* Wout   = (const float*)d_in[6];
  const float* bout   = (const float*)d_in[7];
  float* out = (float*)d_out;

  float* ws    = (float*)d_ws;
  float* pre   = ws;                               // ROWS*Gg   (64 MB)
  float* h2all = pre   + (size_t)ROWS * Gg;        // ROWS*Hh
  float* ceb   = h2all + (size_t)ROWS * Hh;        // ROWS
  u16* h1hi = (u16*)(ceb + ROWS);                  // [2][64][512]
  u16* h1lo = h1hi + 2 * 64 * 512;
  u16* h2hi = h1lo + 2 * 64 * 512;
  u16* h2lo = h2hi + 2 * 64 * 512;
  u16* WQ1h = h2lo + 2 * 64 * 512;                 // 32*64*512
  u16* WQ1l = WQ1h + 32 * 64 * 512;
  u16* WQ2h = WQ1l + 32 * 64 * 512;                // 32*64*1024
  u16* WQ2l = WQ2h + 32 * 64 * 1024;
  unsigned* bar = (unsigned*)(WQ2l + 32 * 64 * 1024);   // 64 dwords
  u16* Xhi  = (u16*)(bar + 64);                    // ROWS*Dd
  u16* Xlo  = Xhi  + (size_t)ROWS * Dd;
  u16* W1Th = Xlo  + (size_t)ROWS * Dd;            // Gg*Dd
  u16* W1Tl = W1Th + (size_t)Gg * Dd;
  const size_t need = (size_t)((char*)(W1Tl + (size_t)Gg * Dd) - (char*)d_ws);
  const bool use_mfma = ws_size >= need;

  init_bar<<<1, 64, 0, stream>>>(bar);
  // recurrent weights: permute+split once
  permuteW2<<<dim3(16, 64), dim3(32, 8), 0, stream>>>(
      W1 + (size_t)Dd * Gg, WQ1h, WQ1l, 512);
  permuteW2<<<dim3(32, 64), dim3(32, 8), 0, stream>>>(W2, WQ2h, WQ2l, 1024);

  // Layer 1 input projection: pre = X @ W1[0:D,:] + b1
  if (use_mfma) {
    convert_hilo<<<2048, 256, 0, stream>>>(inputs, Xhi, Xlo, ROWS * Dd / 4);
    convertT_w1<<<dim3(64, 64), dim3(32, 8), 0, stream>>>(W1, W1Th, W1Tl);
    gemm1_mfma<<<dim3(Gg / 128, ROWS / 128), 256, 0, stream>>>(
        Xhi, Xlo, W1Th, W1Tl, b1, pre);
  } else {
    sgemm_bias<<<dim3(Gg / BN, ROWS / BM), dim3(256), 0, stream>>>(
        inputs, W1, b1, pre, ROWS, Gg, Dd);
  }

  // Entire recurrence in ONE dispatch (4 independent batch groups,
  // 32-block barriers within each group)
  lstm_persist<<<128, 512, 0, stream>>>(pre, WQ1h, WQ1l, WQ2h, WQ2l, b2,
                                        h1hi, h1lo, h2hi, h2lo, h2all, bar);

  proj_softmax<<<ROWS / 8, 128, 0, stream>>>(h2all, Wout, bout, labels, out, ceb);
  reduce_cost<<<1, 256, 0, stream>>>(ceb, out + (size_t)ROWS * Cc);
}

// Round 11
// 2756.307 us; speedup vs baseline: 2.5116x; 2.5116x over previous
//
#include <hip/hip_runtime.h>
#include <cmath>

// Problem constants
#define Bb   64
#define Tt   128
#define Dd   2048
#define Hh   512
#define Gg   2048      // 4*H
#define Cc   101
#define ROWS 8192      // B*T

typedef unsigned short u16;
typedef __attribute__((ext_vector_type(8))) short bf16x8;
typedef __attribute__((ext_vector_type(4))) float f32x4;

// ---------------- bf16 hi/lo split helpers ----------------
__device__ __forceinline__ u16 bf16rne(float x) {
  unsigned u = __float_as_uint(x);
  unsigned r = (u + 0x7fffu + ((u >> 16) & 1u)) >> 16;
  return (u16)r;
}
__device__ __forceinline__ void split_bf16(float x, u16& h, u16& l) {
  h = bf16rne(x);
  l = bf16rne(x - __uint_as_float(((unsigned)h) << 16));
}
__device__ __forceinline__ float sigm(float x) { return 1.f / (1.f + expf(-x)); }

__device__ __forceinline__ f32x4 mm3(f32x4 acc, bf16x8 ah, bf16x8 al,
                                     bf16x8 bh, bf16x8 bl) {
  acc = __builtin_amdgcn_mfma_f32_16x16x32_bf16(ah, bh, acc, 0, 0, 0);
  acc = __builtin_amdgcn_mfma_f32_16x16x32_bf16(ah, bl, acc, 0, 0, 0);
  acc = __builtin_amdgcn_mfma_f32_16x16x32_bf16(al, bh, acc, 0, 0, 0);
  return acc;
}

// X [ROWS x Dd] fp32 -> Xhi, Xlo bf16 (same layout)
__global__ __launch_bounds__(256)
void convert_hilo(const float* __restrict__ src, u16* __restrict__ hi,
                  u16* __restrict__ lo, int n4) {
  for (int i = blockIdx.x * 256 + threadIdx.x; i < n4; i += gridDim.x * 256) {
    const float4 v = ((const float4*)src)[i];
    ushort4 h, l;
    split_bf16(v.x, h.x, l.x);
    split_bf16(v.y, h.y, l.y);
    split_bf16(v.z, h.z, l.z);
    split_bf16(v.w, h.w, l.w);
    ((ushort4*)hi)[i] = h;
    ((ushort4*)lo)[i] = l;
  }
}

// W1 top [Dd x Gg] -> W1T hi/lo [Gg x Dd] bf16  (for gemm1 B operand)
__global__ __launch_bounds__(256)
void convertT_w1(const float* __restrict__ W1, u16* __restrict__ Th,
                 u16* __restrict__ Tl) {
  __shared__ float tl[32][33];
  const int tx = threadIdx.x, ty = threadIdx.y;   // 32, 8
  const int k0 = blockIdx.x * 32, c0 = blockIdx.y * 32;
#pragma unroll
  for (int j = 0; j < 4; ++j)
    tl[ty + j * 8][tx] = W1[(size_t)(k0 + ty + j * 8) * Gg + (c0 + tx)];
  __syncthreads();
#pragma unroll
  for (int j = 0; j < 4; ++j) {
    const float v = tl[tx][ty + j * 8];
    u16 h, l;
    split_bf16(v, h, l);
    const size_t o = (size_t)(c0 + ty + j * 8) * Dd + (k0 + tx);
    Th[o] = h;
    Tl[o] = l;
  }
}

// Recurrent W1 rows, permuted + split: WQ1[cb 32][vc 64][512], vc = gate*16+ml
// for col = gate*512 + cb*16 + ml.
__global__ __launch_bounds__(256)
void permuteW2(const float* __restrict__ src, u16* __restrict__ dh,
               u16* __restrict__ dl, int K) {
  __shared__ float tl[32][33];
  const int tx = threadIdx.x, ty = threadIdx.y;   // 32, 8
  const int k0 = blockIdx.x * 32, c0 = blockIdx.y * 32;
#pragma unroll
  for (int j = 0; j < 4; ++j)
    tl[ty + j * 8][tx] = src[(size_t)(k0 + ty + j * 8) * Gg + (c0 + tx)];
  __syncthreads();
#pragma unroll
  for (int j = 0; j < 4; ++j) {
    const int col  = c0 + ty + j * 8;
    const int gate = col >> 9, hcol = col & 511;
    const int cb = hcol >> 4, ml = hcol & 15;
    const float v = tl[tx][ty + j * 8];
    u16 h, l;
    split_bf16(v, h, l);
    const size_t o = ((size_t)cb * 64 + gate * 16 + ml) * K + k0 + tx;
    dh[o] = h;
    dl[o] = l;
  }
}

// W2 [1024 x 2048] -> WQ2[cb2 64][vc 32][1024], vc = gate*8+ml for
// col = gate*512 + cb2*8 + ml.
__global__ __launch_bounds__(256)
void permuteW3(const float* __restrict__ src, u16* __restrict__ dh,
               u16* __restrict__ dl) {
  __shared__ float tl[32][33];
  const int tx = threadIdx.x, ty = threadIdx.y;   // 32, 8
  const int k0 = blockIdx.x * 32, c0 = blockIdx.y * 32;
#pragma unroll
  for (int j = 0; j < 4; ++j)
    tl[ty + j * 8][tx] = src[(size_t)(k0 + ty + j * 8) * Gg + (c0 + tx)];
  __syncthreads();
#pragma unroll
  for (int j = 0; j < 4; ++j) {
    const int col  = c0 + ty + j * 8;
    const int gate = col >> 9, hcol = col & 511;
    const int cb2 = hcol >> 3, ml = hcol & 7;
    const float v = tl[tx][ty + j * 8];
    u16 h, l;
    split_bf16(v, h, l);
    const size_t o = ((size_t)cb2 * 32 + gate * 8 + ml) * 1024 + k0 + tx;
    dh[o] = h;
    dl[o] = l;
  }
}

__global__ void init_bar(unsigned* bar) {
  if (threadIdx.x < 64) bar[threadIdx.x] = 0;
}

// ---------------- MFMA bf16x3 GEMM: pre = X @ W1 + b1 ----------------
__global__ __launch_bounds__(256)
void gemm1_mfma(const u16* __restrict__ Ah, const u16* __restrict__ Al,
                const u16* __restrict__ Bh, const u16* __restrict__ Bl,
                const float* __restrict__ bias, float* __restrict__ C) {
  __shared__ u16 Ash[128][40];
  __shared__ u16 Asl[128][40];
  __shared__ u16 Bsh[128][40];
  __shared__ u16 Bsl[128][40];
  const int tid  = threadIdx.x;
  const int lane = tid & 63, wave = tid >> 6;
  const int wm = wave >> 1, wn = wave & 1;
  const int l15 = lane & 15, k8 = (lane >> 4) * 8, r4 = (lane >> 4) * 4;
  const int row0 = blockIdx.y * 128, col0 = blockIdx.x * 128;
  const int srow = tid >> 1, sk = (tid & 1) * 16;

  const u16* pAh = Ah + (size_t)(row0 + srow) * Dd + sk;
  const u16* pAl = Al + (size_t)(row0 + srow) * Dd + sk;
  const u16* pBh = Bh + (size_t)(col0 + srow) * Dd + sk;
  const u16* pBl = Bl + (size_t)(col0 + srow) * Dd + sk;

  f32x4 acc[4][4];
#pragma unroll
  for (int i = 0; i < 4; ++i)
#pragma unroll
    for (int j = 0; j < 4; ++j) acc[i][j] = (f32x4){0.f, 0.f, 0.f, 0.f};

  for (int k0 = 0; k0 < Dd; k0 += 32) {
    *(bf16x8*)(&Ash[srow][sk])     = *(const bf16x8*)(pAh + k0);
    *(bf16x8*)(&Ash[srow][sk + 8]) = *(const bf16x8*)(pAh + k0 + 8);
    *(bf16x8*)(&Asl[srow][sk])     = *(const bf16x8*)(pAl + k0);
    *(bf16x8*)(&Asl[srow][sk + 8]) = *(const bf16x8*)(pAl + k0 + 8);
    *(bf16x8*)(&Bsh[srow][sk])     = *(const bf16x8*)(pBh + k0);
    *(bf16x8*)(&Bsh[srow][sk + 8]) = *(const bf16x8*)(pBh + k0 + 8);
    *(bf16x8*)(&Bsl[srow][sk])     = *(const bf16x8*)(pBl + k0);
    *(bf16x8*)(&Bsl[srow][sk + 8]) = *(const bf16x8*)(pBl + k0 + 8);
    __syncthreads();

    bf16x8 afh[4], afl[4], bfh[4], bfl[4];
#pragma unroll
    for (int mt = 0; mt < 4; ++mt) {
      afh[mt] = *(const bf16x8*)(&Ash[wm * 64 + mt * 16 + l15][k8]);
      afl[mt] = *(const bf16x8*)(&Asl[wm * 64 + mt * 16 + l15][k8]);
    }
#pragma unroll
    for (int nt = 0; nt < 4; ++nt) {
      bfh[nt] = *(const bf16x8*)(&Bsh[wn * 64 + nt * 16 + l15][k8]);
      bfl[nt] = *(const bf16x8*)(&Bsl[wn * 64 + nt * 16 + l15][k8]);
    }
#pragma unroll
    for (int mt = 0; mt < 4; ++mt)
#pragma unroll
      for (int nt = 0; nt < 4; ++nt) {
        acc[mt][nt] = __builtin_amdgcn_mfma_f32_16x16x32_bf16(
            afh[mt], bfh[nt], acc[mt][nt], 0, 0, 0);
        acc[mt][nt] = __builtin_amdgcn_mfma_f32_16x16x32_bf16(
            afh[mt], bfl[nt], acc[mt][nt], 0, 0, 0);
        acc[mt][nt] = __builtin_amdgcn_mfma_f32_16x16x32_bf16(
            afl[mt], bfh[nt], acc[mt][nt], 0, 0, 0);
      }
    __syncthreads();
  }

#pragma unroll
  for (int nt = 0; nt < 4; ++nt) {
    const int col = col0 + wn * 64 + nt * 16 + l15;
    const float bj = bias[col];
#pragma unroll
    for (int mt = 0; mt < 4; ++mt) {
      float* Cp = C + (size_t)(row0 + wm * 64 + mt * 16 + r4) * Gg + col;
#pragma unroll
      for (int r = 0; r < 4; ++r)
        Cp[(size_t)r * Gg] = acc[mt][nt][r] + bj;
    }
  }
}

// ---------------- SGEMM (fp32 fallback if ws too small) ----------------
#define BM 128
#define BN 128
#define BK 16

__global__ __launch_bounds__(256)
void sgemm_bias(const float* __restrict__ A, const float* __restrict__ B,
                const float* __restrict__ bias, float* __restrict__ C,
                int M, int N, int K) {
  __shared__ float As[BK][BM];
  __shared__ float Bs[BK][BN];
  const int tid  = threadIdx.x;
  const int row0 = blockIdx.y * BM, col0 = blockIdx.x * BN;
  const int tr = (tid >> 4) << 3;
  const int tc = (tid & 15) << 3;

  float acc[8][8];
#pragma unroll
  for (int i = 0; i < 8; ++i)
#pragma unroll
    for (int j = 0; j < 8; ++j) acc[i][j] = 0.f;

  const int arow = tid >> 1;
  const int acol = (tid & 1) << 3;
  const int brow = tid >> 4;
  const int bcol = (tid & 15) << 3;
  const float* Ap = A + (size_t)(row0 + arow) * K + acol;
  const float* Bp = B + (size_t)brow * N + (col0 + bcol);

  for (int k0 = 0; k0 < K; k0 += BK) {
    const float4 a0 = *(const float4*)(Ap + k0);
    const float4 a1 = *(const float4*)(Ap + k0 + 4);
    const float4 bv0 = *(const float4*)(Bp + (size_t)k0 * N);
    const float4 bv1 = *(const float4*)(Bp + (size_t)k0 * N + 4);
    As[acol + 0][arow] = a0.x;
    As[acol + 1][arow] = a0.y;
    As[acol + 2][arow] = a0.z;
    As[acol + 3][arow] = a0.w;
    As[acol + 4][arow] = a1.x;
    As[acol + 5][arow] = a1.y;
    As[acol + 6][arow] = a1.z;
    As[acol + 7][arow] = a1.w;
    *(float4*)(&Bs[brow][bcol])     = bv0;
    *(float4*)(&Bs[brow][bcol + 4]) = bv1;
    __syncthreads();
#pragma unroll
    for (int k = 0; k < BK; ++k) {
      float a[8], b[8];
      *(float4*)(a)     = *(const float4*)(&As[k][tr]);
      *(float4*)(a + 4) = *(const float4*)(&As[k][tr + 4]);
      *(float4*)(b)     = *(const float4*)(&Bs[k][tc]);
      *(float4*)(b + 4) = *(const float4*)(&Bs[k][tc + 4]);
#pragma unroll
      for (int i = 0; i < 8; ++i)
#pragma unroll
        for (int j = 0; j < 8; ++j)
          acc[i][j] = fmaf(a[i], b[j], acc[i][j]);
    }
    __syncthreads();
  }

  float bj[8];
#pragma unroll
  for (int j = 0; j < 8; ++j) bj[j] = bias[col0 + tc + j];
#pragma unroll
  for (int i = 0; i < 8; ++i) {
    float* Cp = C + (size_t)(row0 + tr + i) * N + (col0 + tc);
    float4 o0, o1;
    o0.x = acc[i][0] + bj[0]; o0.y = acc[i][1] + bj[1];
    o0.z = acc[i][2] + bj[2]; o0.w = acc[i][3] + bj[3];
    o1.x = acc[i][4] + bj[4]; o1.y = acc[i][5] + bj[5];
    o1.z = acc[i][6] + bj[6]; o1.w = acc[i][7] + bj[7];
    *(float4*)(Cp)     = o0;
    *(float4*)(Cp + 4) = o1;
  }
}

// ---------------- persistent recurrence v3: weight-stationary + lean barrier
// 192 blocks = 2 batch-groups(32 b) x (32 L1-blocks[16 cols] + 64 L2-blocks[8 cols]).
// W slice lives in LDS (loaded once) -> immune to the acquire invalidates.
// Barrier: tid0-only RELEASE fetch_add (1 wbl2) + RELAXED spin + 1 ACQUIRE
// load (1 inv). No all-wave threadfence (that was R4/R10's 50-90 us/phase).
__global__ __launch_bounds__(512, 1)
void lstm_persist2(const float* __restrict__ pre,
                   const u16* __restrict__ WQ1h, const u16* __restrict__ WQ1l,
                   const u16* __restrict__ WQ2h, const u16* __restrict__ WQ2l,
                   const float* __restrict__ b2,
                   u16* __restrict__ h1hi, u16* __restrict__ h1lo,
                   u16* __restrict__ h2hi, u16* __restrict__ h2lo,
                   float* __restrict__ h2all, unsigned* __restrict__ bar) {
  __shared__ u16 Wh[64 * 520];    // L1: [64][520]; L2 uses [32][1032]
  __shared__ u16 Wl[64 * 520];
  __shared__ float ex[2304];      // L1: [32][68]; L2: [2][32][36]

  const int tid  = threadIdx.x;
  const int lane = tid & 63, w = tid >> 6;
  const int l15 = lane & 15, f8 = (lane >> 4) * 8, r4 = (lane >> 4) * 4;
  const int grp = blockIdx.x / 96;
  const int rr  = blockIdx.x % 96;
  const bool isL1 = rr < 32;
  const int cb1 = rr;             // L1 col-block (16 cols)
  const int cb2 = rr - 32;        // L2 col-block (8 cols)
  const int gb0 = grp * 32;

  // ---- stage W slice into LDS once (row pad +8 elems: conflict-free b128)
  if (isL1) {
    const u16* sh = WQ1h + (size_t)cb1 * 64 * 512;
    const u16* sl = WQ1l + (size_t)cb1 * 64 * 512;
    for (int i = tid; i < 64 * 64; i += 512) {
      const int row = i >> 6, c = (i & 63) * 8;
      *(bf16x8*)&Wh[row * 520 + c] = *(const bf16x8*)(sh + row * 512 + c);
      *(bf16x8*)&Wl[row * 520 + c] = *(const bf16x8*)(sl + row * 512 + c);
    }
  } else {
    const u16* sh = WQ2h + (size_t)cb2 * 32 * 1024;
    const u16* sl = WQ2l + (size_t)cb2 * 32 * 1024;
    for (int i = tid; i < 32 * 128; i += 512) {
      const int row = i >> 7, c = (i & 127) * 8;
      *(bf16x8*)&Wh[row * 1032 + c] = *(const bf16x8*)(sh + row * 1024 + c);
      *(bf16x8*)&Wl[row * 1032 + c] = *(const bf16x8*)(sl + row * 1024 + c);
    }
  }
  __syncthreads();

  // wave roles
  const int mt = w >> 2;          // batch tile (both layers)
  const int ng = w & 3;           // L1 gate group
  const int nt = (w >> 1) & 1;    // L2 col tile
  const int kh = w & 1;           // L2 K half (0: h1, 1: h2)

  // epilogue ownership
  const int eb1 = tid >> 4, em1 = tid & 15;        // L1 (all 512 threads)
  const int eb2 = (tid >> 3) & 31, em2 = tid & 7;  // L2 (tid < 256)
  const int col1 = cb1 * 16 + em1;
  const int col2 = cb2 * 8 + em2;
  float b2i = 0.f, b2j = 0.f, b2f = 0.f, b2o = 0.f;
  if (!isL1 && tid < 256) {
    b2i = b2[col2];        b2j = b2[512 + col2];
    b2f = b2[1024 + col2]; b2o = b2[1536 + col2];
  }
  float creg = 0.f;
  unsigned* ctr = &bar[grp * 16];

  for (int t = 0; t <= Tt; ++t) {
    float p0 = 0.f, p1 = 0.f, p2 = 0.f, p3 = 0.f;
    if (isL1 && t < Tt) {
      const float* pp = pre + ((size_t)(gb0 + eb1) * Tt + t) * Gg + col1;
      p0 = pp[0]; p1 = pp[512]; p2 = pp[1024]; p3 = pp[1536];
    }

    f32x4 ae = {0.f, 0.f, 0.f, 0.f}, ao = {0.f, 0.f, 0.f, 0.f};
    if (isL1) {
      if (t > 0 && t < Tt) {
        const int sl = (t - 1) & 1;
        const u16* A_h = h1hi + (sl << 15) + (gb0 + mt * 16 + l15) * 512 + f8;
        const u16* A_l = h1lo + (sl << 15) + (gb0 + mt * 16 + l15) * 512 + f8;
        const u16* B_h = &Wh[(ng * 16 + l15) * 520 + f8];
        const u16* B_l = &Wl[(ng * 16 + l15) * 520 + f8];
#pragma unroll
        for (int kc = 0; kc < 16; ++kc) {
          const bf16x8 ah = *(const bf16x8*)(A_h + kc * 32);
          const bf16x8 al = *(const bf16x8*)(A_l + kc * 32);
          const bf16x8 bh = *(const bf16x8*)(B_h + kc * 32);
          const bf16x8 bl = *(const bf16x8*)(B_l + kc * 32);
          if (kc & 1) ao = mm3(ao, ah, al, bh, bl);
          else        ae = mm3(ae, ah, al, bh, bl);
        }
      }
#pragma unroll
      for (int r = 0; r < 4; ++r)
        ex[(mt * 16 + r4 + r) * 68 + ng * 16 + l15] = ae[r] + ao[r];
    } else {
      const bool act = kh ? (t >= 2) : (t >= 1);
      if (act) {
        const int sl = (t - 1 - kh) & 1;
        const u16* hb = kh ? h2hi : h1hi;
        const u16* lb = kh ? h2lo : h1lo;
        const u16* A_h = hb + (sl << 15) + (gb0 + mt * 16 + l15) * 512 + f8;
        const u16* A_l = lb + (sl << 15) + (gb0 + mt * 16 + l15) * 512 + f8;
        const u16* B_h = &Wh[(nt * 16 + l15) * 1032 + kh * 512 + f8];
        const u16* B_l = &Wl[(nt * 16 + l15) * 1032 + kh * 512 + f8];
#pragma unroll
        for (int kc = 0; kc < 16; ++kc) {
          const bf16x8 ah = *(const bf16x8*)(A_h + kc * 32);
          const bf16x8 al = *(const bf16x8*)(A_l + kc * 32);
          const bf16x8 bh = *(const bf16x8*)(B_h + kc * 32);
          const bf16x8 bl = *(const bf16x8*)(B_l + kc * 32);
          if (kc & 1) ao = mm3(ao, ah, al, bh, bl);
          else        ae = mm3(ae, ah, al, bh, bl);
        }
      }
#pragma unroll
      for (int r = 0; r < 4; ++r)
        ex[kh * 1152 + (mt * 16 + r4 + r) * 36 + nt * 16 + l15] = ae[r] + ao[r];
    }
    __syncthreads();

    // epilogues; cell state in registers
    if (isL1) {
      if (t < Tt) {
        const float gi = p0 + ex[eb1 * 68 + em1];
        const float gj = p1 + ex[eb1 * 68 + 16 + em1];
        const float gf = p2 + ex[eb1 * 68 + 32 + em1];
        const float go = p3 + ex[eb1 * 68 + 48 + em1];
        creg = fmaf(creg, sigm(gf + 1.f), sigm(gi) * tanhf(gj));
        const float nh = tanhf(creg) * sigm(go);
        u16 hh, hl;
        split_bf16(nh, hh, hl);
        const int o = ((t & 1) << 15) + (gb0 + eb1) * 512 + col1;
        h1hi[o] = hh;
        h1lo[o] = hl;
      }
    } else {
      if (tid < 256 && t >= 1) {
        const int bix = eb2 * 36 + em2;
        const float gi = b2i + ex[bix]      + ex[1152 + bix];
        const float gj = b2j + ex[bix + 8]  + ex[1152 + bix + 8];
        const float gf = b2f + ex[bix + 16] + ex[1152 + bix + 16];
        const float go = b2o + ex[bix + 24] + ex[1152 + bix + 24];
        creg = fmaf(creg, sigm(gf + 1.f), sigm(gi) * tanhf(gj));
        const float nh = tanhf(creg) * sigm(go);
        h2all[((size_t)(gb0 + eb2) * Tt + (t - 1)) * Hh + col2] = nh;
        u16 hh, hl;
        split_bf16(nh, hh, hl);
        const int o = (((t - 1) & 1) << 15) + (gb0 + eb2) * 512 + col2;
        h2hi[o] = hh;
        h2lo[o] = hl;
      }
    }

    // lean per-group barrier (96 blocks): tid0-only; cache ops come from
    // the RELEASE add (wbl2) and the final ACQUIRE load (inv) ONLY.
    if (t < Tt) {
      __syncthreads();   // drains each wave's vmcnt -> stores in L2
      if (tid == 0) {
        __hip_atomic_fetch_add(ctr, 1u, __ATOMIC_RELEASE,
                               __HIP_MEMORY_SCOPE_AGENT);
        const unsigned tgt = (unsigned)(t + 1) * 96u;
        while (__hip_atomic_load(ctr, __ATOMIC_RELAXED,
                                 __HIP_MEMORY_SCOPE_AGENT) < tgt)
          __builtin_amdgcn_s_sleep(2);
        unsigned fv = __hip_atomic_load(ctr, __ATOMIC_ACQUIRE,
                                        __HIP_MEMORY_SCOPE_AGENT);
        asm volatile("" :: "v"(fv));
      }
      __syncthreads();
    }
  }
}

// ---------------- Output projection + softmax + CE ----------------
__global__ __launch_bounds__(128)
void proj_softmax(const float* __restrict__ h2, const float* __restrict__ Wout,
                  const float* __restrict__ bout, const int* __restrict__ labels,
                  float* __restrict__ preds, float* __restrict__ ce) {
  __shared__ float hs[8][Hh];
  __shared__ float wred[2][2];
  const int tid = threadIdx.x;
  const int wid = tid >> 6;
  const int r0  = blockIdx.x * 8;

  for (int i = tid; i < 8 * (Hh / 4); i += 128) {
    const int row = i >> 7;
    const int c4  = i & 127;
    ((float4*)hs[row])[c4] =
        ((const float4*)(h2 + ((size_t)(r0 + row) * Hh)))[c4];
  }
  __syncthreads();

  const bool act = (tid < Cc);
  float acc[8];
  {
    const float bj = act ? bout[tid] : 0.f;
#pragma unroll
    for (int i = 0; i < 8; ++i) acc[i] = bj;
  }
  if (act) {
#pragma unroll 4
    for (int k = 0; k < Hh; ++k) {
      const float w = Wout[k * Cc + tid];
#pragma unroll
      for (int i = 0; i < 8; ++i) acc[i] = fmaf(hs[i][k], w, acc[i]);
    }
  }

  for (int row = 0; row < 8; ++row) {
    const float v = act ? acc[row] : -INFINITY;
    float mw = v;
#pragma unroll
    for (int off = 32; off > 0; off >>= 1) mw = fmaxf(mw, __shfl_xor(mw, off));
    if ((tid & 63) == 0) wred[0][wid] = mw;
    __syncthreads();
    const float mx = fmaxf(wred[0][0], wred[0][1]);
    const float e = act ? expf(v - mx) : 0.f;
    float sw = e;
#pragma unroll
    for (int off = 32; off > 0; off >>= 1) sw += __shfl_xor(sw, off);
    if ((tid & 63) == 0) wred[1][wid] = sw;
    __syncthreads();
    const float sum = wred[1][0] + wred[1][1];
    if (act) preds[(size_t)(r0 + row) * Cc + tid] = e / sum;
    const int lab = labels[r0 + row];
    if (tid == lab) ce[r0 + row] = logf(sum) + mx - v;
    __syncthreads();
  }
}

__global__ __launch_bounds__(256)
void reduce_cost(const float* __restrict__ ce, float* __restrict__ out) {
  __shared__ float red[256];
  const int tid = threadIdx.x;
  float s = 0.f;
  for (int i = tid; i < ROWS; i += 256) s += ce[i];
  red[tid] = s;
  __syncthreads();
  for (int st = 128; st > 0; st >>= 1) {
    if (tid < st) red[tid] += red[tid + st];
    __syncthreads();
  }
  if (tid == 0) out[0] = red[0] / (float)Bb;
}

// ---------------- launch ----------------
extern "C" void kernel_launch(void* const* d_in, const int* in_sizes, int n_in,
                              void* d_out, int out_size, void* d_ws, size_t ws_size,
                              hipStream_t stream) {
  const float* inputs = (const float*)d_in[0];
  const int*   labels = (const int*)d_in[1];
  const float* W1     = (const float*)d_in[2];
  const float* b1     = (const float*)d_in[3];
  const float* W2     = (const float*)d_in[4];
  const float* b2     = (const float*)d_in[5];
  const float* Wout   = (const float*)d_in[6];
  const float* bout   = (const float*)d_in[7];
  float* out = (float*)d_out;

  float* ws    = (float*)d_ws;
  float* pre   = ws;                               // ROWS*Gg   (64 MB)
  float* h2all = pre   + (size_t)ROWS * Gg;        // ROWS*Hh
  float* ceb   = h2all + (size_t)ROWS * Hh;        // ROWS
  u16* h1hi = (u16*)(ceb + ROWS);                  // [2][64][512]
  u16* h1lo = h1hi + 2 * 64 * 512;
  u16* h2hi = h1lo + 2 * 64 * 512;
  u16* h2lo = h2hi + 2 * 64 * 512;
  u16* WQ1h = h2lo + 2 * 64 * 512;                 // 32*64*512
  u16* WQ1l = WQ1h + 32 * 64 * 512;
  u16* WQ2h = WQ1l + 32 * 64 * 512;                // 64*32*1024
  u16* WQ2l = WQ2h + 64 * 32 * 1024;
  unsigned* bar = (unsigned*)(WQ2l + 64 * 32 * 1024);   // 64 dwords
  u16* Xhi  = (u16*)(bar + 64);                    // ROWS*Dd
  u16* Xlo  = Xhi  + (size_t)ROWS * Dd;
  u16* W1Th = Xlo  + (size_t)ROWS * Dd;            // Gg*Dd
  u16* W1Tl = W1Th + (size_t)Gg * Dd;
  const size_t need = (size_t)((char*)(W1Tl + (size_t)Gg * Dd) - (char*)d_ws);
  const bool use_mfma = ws_size >= need;

  init_bar<<<1, 64, 0, stream>>>(bar);
  // recurrent weights: permute+split once
  permuteW2<<<dim3(16, 64), dim3(32, 8), 0, stream>>>(
      W1 + (size_t)Dd * Gg, WQ1h, WQ1l, 512);
  permuteW3<<<dim3(32, 64), dim3(32, 8), 0, stream>>>(W2, WQ2h, WQ2l);

  // Layer 1 input projection: pre = X @ W1[0:D,:] + b1
  if (use_mfma) {
    convert_hilo<<<2048, 256, 0, stream>>>(inputs, Xhi, Xlo, ROWS * Dd / 4);
    convertT_w1<<<dim3(64, 64), dim3(32, 8), 0, stream>>>(W1, W1Th, W1Tl);
    gemm1_mfma<<<dim3(Gg / 128, ROWS / 128), 256, 0, stream>>>(
        Xhi, Xlo, W1Th, W1Tl, b1, pre);
  } else {
    sgemm_bias<<<dim3(Gg / BN, ROWS / BM), dim3(256), 0, stream>>>(
        inputs, W1, b1, pre, ROWS, Gg, Dd);
  }

  // Entire recurrence in ONE dispatch (2 independent batch groups,
  // 96-block lean barriers within each group; W stays in LDS)
  lstm_persist2<<<192, 512, 0, stream>>>(pre, WQ1h, WQ1l, WQ2h, WQ2l, b2,
                                         h1hi, h1lo, h2hi, h2lo, h2all, bar);

  proj_softmax<<<ROWS / 8, 128, 0, stream>>>(h2all, Wout, bout, labels, out, ceb);
  reduce_cost<<<1, 256, 0, stream>>>(ceb, out + (size_t)ROWS * Cc);
}

// Round 12
// 2270.619 us; speedup vs baseline: 3.0489x; 1.2139x over previous
//
#include <hip/hip_runtime.h>
#include <cmath>

// Problem constants
#define Bb   64
#define Tt   128
#define Dd   2048
#define Hh   512
#define Gg   2048      // 4*H
#define Cc   101
#define ROWS 8192      // B*T

typedef unsigned short u16;
typedef __attribute__((ext_vector_type(8))) short bf16x8;
typedef __attribute__((ext_vector_type(4))) float f32x4;

// ---------------- bf16 hi/lo split helpers ----------------
__device__ __forceinline__ u16 bf16rne(float x) {
  unsigned u = __float_as_uint(x);
  unsigned r = (u + 0x7fffu + ((u >> 16) & 1u)) >> 16;
  return (u16)r;
}
__device__ __forceinline__ void split_bf16(float x, u16& h, u16& l) {
  h = bf16rne(x);
  l = bf16rne(x - __uint_as_float(((unsigned)h) << 16));
}
__device__ __forceinline__ float sigm(float x) { return 1.f / (1.f + expf(-x)); }

__device__ __forceinline__ f32x4 mm3(f32x4 acc, bf16x8 ah, bf16x8 al,
                                     bf16x8 bh, bf16x8 bl) {
  acc = __builtin_amdgcn_mfma_f32_16x16x32_bf16(ah, bh, acc, 0, 0, 0);
  acc = __builtin_amdgcn_mfma_f32_16x16x32_bf16(ah, bl, acc, 0, 0, 0);
  acc = __builtin_amdgcn_mfma_f32_16x16x32_bf16(al, bh, acc, 0, 0, 0);
  return acc;
}

// X [ROWS x Dd] fp32 -> Xhi, Xlo bf16 (same layout)
__global__ __launch_bounds__(256)
void convert_hilo(const float* __restrict__ src, u16* __restrict__ hi,
                  u16* __restrict__ lo, int n4) {
  for (int i = blockIdx.x * 256 + threadIdx.x; i < n4; i += gridDim.x * 256) {
    const float4 v = ((const float4*)src)[i];
    ushort4 h, l;
    split_bf16(v.x, h.x, l.x);
    split_bf16(v.y, h.y, l.y);
    split_bf16(v.z, h.z, l.z);
    split_bf16(v.w, h.w, l.w);
    ((ushort4*)hi)[i] = h;
    ((ushort4*)lo)[i] = l;
  }
}

// W1 top [Dd x Gg] -> W1T hi/lo [Gg x Dd] bf16  (for gemm1 B operand)
__global__ __launch_bounds__(256)
void convertT_w1(const float* __restrict__ W1, u16* __restrict__ Th,
                 u16* __restrict__ Tl) {
  __shared__ float tl[32][33];
  const int tx = threadIdx.x, ty = threadIdx.y;   // 32, 8
  const int k0 = blockIdx.x * 32, c0 = blockIdx.y * 32;
#pragma unroll
  for (int j = 0; j < 4; ++j)
    tl[ty + j * 8][tx] = W1[(size_t)(k0 + ty + j * 8) * Gg + (c0 + tx)];
  __syncthreads();
#pragma unroll
  for (int j = 0; j < 4; ++j) {
    const float v = tl[tx][ty + j * 8];
    u16 h, l;
    split_bf16(v, h, l);
    const size_t o = (size_t)(c0 + ty + j * 8) * Dd + (k0 + tx);
    Th[o] = h;
    Tl[o] = l;
  }
}

// Recurrent W1 rows, permuted + split: WQ1[cb 32][vc 64][512], vc = gate*16+ml
__global__ __launch_bounds__(256)
void permuteW2(const float* __restrict__ src, u16* __restrict__ dh,
               u16* __restrict__ dl, int K) {
  __shared__ float tl[32][33];
  const int tx = threadIdx.x, ty = threadIdx.y;   // 32, 8
  const int k0 = blockIdx.x * 32, c0 = blockIdx.y * 32;
#pragma unroll
  for (int j = 0; j < 4; ++j)
    tl[ty + j * 8][tx] = src[(size_t)(k0 + ty + j * 8) * Gg + (c0 + tx)];
  __syncthreads();
#pragma unroll
  for (int j = 0; j < 4; ++j) {
    const int col  = c0 + ty + j * 8;
    const int gate = col >> 9, hcol = col & 511;
    const int cb = hcol >> 4, ml = hcol & 15;
    const float v = tl[tx][ty + j * 8];
    u16 h, l;
    split_bf16(v, h, l);
    const size_t o = ((size_t)cb * 64 + gate * 16 + ml) * K + k0 + tx;
    dh[o] = h;
    dl[o] = l;
  }
}

// W2 [1024 x 2048] -> WQ2[cb2 64][vc 32][1024], vc = gate*8+ml
__global__ __launch_bounds__(256)
void permuteW3(const float* __restrict__ src, u16* __restrict__ dh,
               u16* __restrict__ dl) {
  __shared__ float tl[32][33];
  const int tx = threadIdx.x, ty = threadIdx.y;   // 32, 8
  const int k0 = blockIdx.x * 32, c0 = blockIdx.y * 32;
#pragma unroll
  for (int j = 0; j < 4; ++j)
    tl[ty + j * 8][tx] = src[(size_t)(k0 + ty + j * 8) * Gg + (c0 + tx)];
  __syncthreads();
#pragma unroll
  for (int j = 0; j < 4; ++j) {
    const int col  = c0 + ty + j * 8;
    const int gate = col >> 9, hcol = col & 511;
    const int cb2 = hcol >> 3, ml = hcol & 7;
    const float v = tl[tx][ty + j * 8];
    u16 h, l;
    split_bf16(v, h, l);
    const size_t o = ((size_t)cb2 * 32 + gate * 8 + ml) * 1024 + k0 + tx;
    dh[o] = h;
    dl[o] = l;
  }
}

__global__ void init_slots(unsigned* slots) {
  for (int i = threadIdx.x; i < 4096; i += 256) slots[i] = 0;
}

// ---------------- MFMA bf16x3 GEMM: pre = X @ W1 + b1 ----------------
__global__ __launch_bounds__(256)
void gemm1_mfma(const u16* __restrict__ Ah, const u16* __restrict__ Al,
                const u16* __restrict__ Bh, const u16* __restrict__ Bl,
                const float* __restrict__ bias, float* __restrict__ C) {
  __shared__ u16 Ash[128][40];
  __shared__ u16 Asl[128][40];
  __shared__ u16 Bsh[128][40];
  __shared__ u16 Bsl[128][40];
  const int tid  = threadIdx.x;
  const int lane = tid & 63, wave = tid >> 6;
  const int wm = wave >> 1, wn = wave & 1;
  const int l15 = lane & 15, k8 = (lane >> 4) * 8, r4 = (lane >> 4) * 4;
  const int row0 = blockIdx.y * 128, col0 = blockIdx.x * 128;
  const int srow = tid >> 1, sk = (tid & 1) * 16;

  const u16* pAh = Ah + (size_t)(row0 + srow) * Dd + sk;
  const u16* pAl = Al + (size_t)(row0 + srow) * Dd + sk;
  const u16* pBh = Bh + (size_t)(col0 + srow) * Dd + sk;
  const u16* pBl = Bl + (size_t)(col0 + srow) * Dd + sk;

  f32x4 acc[4][4];
#pragma unroll
  for (int i = 0; i < 4; ++i)
#pragma unroll
    for (int j = 0; j < 4; ++j) acc[i][j] = (f32x4){0.f, 0.f, 0.f, 0.f};

  for (int k0 = 0; k0 < Dd; k0 += 32) {
    *(bf16x8*)(&Ash[srow][sk])     = *(const bf16x8*)(pAh + k0);
    *(bf16x8*)(&Ash[srow][sk + 8]) = *(const bf16x8*)(pAh + k0 + 8);
    *(bf16x8*)(&Asl[srow][sk])     = *(const bf16x8*)(pAl + k0);
    *(bf16x8*)(&Asl[srow][sk + 8]) = *(const bf16x8*)(pAl + k0 + 8);
    *(bf16x8*)(&Bsh[srow][sk])     = *(const bf16x8*)(pBh + k0);
    *(bf16x8*)(&Bsh[srow][sk + 8]) = *(const bf16x8*)(pBh + k0 + 8);
    *(bf16x8*)(&Bsl[srow][sk])     = *(const bf16x8*)(pBl + k0);
    *(bf16x8*)(&Bsl[srow][sk + 8]) = *(const bf16x8*)(pBl + k0 + 8);
    __syncthreads();

    bf16x8 afh[4], afl[4], bfh[4], bfl[4];
#pragma unroll
    for (int mt = 0; mt < 4; ++mt) {
      afh[mt] = *(const bf16x8*)(&Ash[wm * 64 + mt * 16 + l15][k8]);
      afl[mt] = *(const bf16x8*)(&Asl[wm * 64 + mt * 16 + l15][k8]);
    }
#pragma unroll
    for (int nt = 0; nt < 4; ++nt) {
      bfh[nt] = *(const bf16x8*)(&Bsh[wn * 64 + nt * 16 + l15][k8]);
      bfl[nt] = *(const bf16x8*)(&Bsl[wn * 64 + nt * 16 + l15][k8]);
    }
#pragma unroll
    for (int mt = 0; mt < 4; ++mt)
#pragma unroll
      for (int nt = 0; nt < 4; ++nt) {
        acc[mt][nt] = __builtin_amdgcn_mfma_f32_16x16x32_bf16(
            afh[mt], bfh[nt], acc[mt][nt], 0, 0, 0);
        acc[mt][nt] = __builtin_amdgcn_mfma_f32_16x16x32_bf16(
            afh[mt], bfl[nt], acc[mt][nt], 0, 0, 0);
        acc[mt][nt] = __builtin_amdgcn_mfma_f32_16x16x32_bf16(
            afl[mt], bfh[nt], acc[mt][nt], 0, 0, 0);
      }
    __syncthreads();
  }

#pragma unroll
  for (int nt = 0; nt < 4; ++nt) {
    const int col = col0 + wn * 64 + nt * 16 + l15;
    const float bj = bias[col];
#pragma unroll
    for (int mt = 0; mt < 4; ++mt) {
      float* Cp = C + (size_t)(row0 + wm * 64 + mt * 16 + r4) * Gg + col;
#pragma unroll
      for (int r = 0; r < 4; ++r)
        Cp[(size_t)r * Gg] = acc[mt][nt][r] + bj;
    }
  }
}

// ---------------- SGEMM (fp32 fallback if ws too small) ----------------
#define BM 128
#define BN 128
#define BK 16

__global__ __launch_bounds__(256)
void sgemm_bias(const float* __restrict__ A, const float* __restrict__ B,
                const float* __restrict__ bias, float* __restrict__ C,
                int M, int N, int K) {
  __shared__ float As[BK][BM];
  __shared__ float Bs[BK][BN];
  const int tid  = threadIdx.x;
  const int row0 = blockIdx.y * BM, col0 = blockIdx.x * BN;
  const int tr = (tid >> 4) << 3;
  const int tc = (tid & 15) << 3;

  float acc[8][8];
#pragma unroll
  for (int i = 0; i < 8; ++i)
#pragma unroll
    for (int j = 0; j < 8; ++j) acc[i][j] = 0.f;

  const int arow = tid >> 1;
  const int acol = (tid & 1) << 3;
  const int brow = tid >> 4;
  const int bcol = (tid & 15) << 3;
  const float* Ap = A + (size_t)(row0 + arow) * K + acol;
  const float* Bp = B + (size_t)brow * N + (col0 + bcol);

  for (int k0 = 0; k0 < K; k0 += BK) {
    const float4 a0 = *(const float4*)(Ap + k0);
    const float4 a1 = *(const float4*)(Ap + k0 + 4);
    const float4 bv0 = *(const float4*)(Bp + (size_t)k0 * N);
    const float4 bv1 = *(const float4*)(Bp + (size_t)k0 * N + 4);
    As[acol + 0][arow] = a0.x;
    As[acol + 1][arow] = a0.y;
    As[acol + 2][arow] = a0.z;
    As[acol + 3][arow] = a0.w;
    As[acol + 4][arow] = a1.x;
    As[acol + 5][arow] = a1.y;
    As[acol + 6][arow] = a1.z;
    As[acol + 7][arow] = a1.w;
    *(float4*)(&Bs[brow][bcol])     = bv0;
    *(float4*)(&Bs[brow][bcol + 4]) = bv1;
    __syncthreads();
#pragma unroll
    for (int k = 0; k < BK; ++k) {
      float a[8], b[8];
      *(float4*)(a)     = *(const float4*)(&As[k][tr]);
      *(float4*)(a + 4) = *(const float4*)(&As[k][tr + 4]);
      *(float4*)(b)     = *(const float4*)(&Bs[k][tc]);
      *(float4*)(b + 4) = *(const float4*)(&Bs[k][tc + 4]);
#pragma unroll
      for (int i = 0; i < 8; ++i)
#pragma unroll
        for (int j = 0; j < 8; ++j)
          acc[i][j] = fmaf(a[i], b[j], acc[i][j]);
    }
    __syncthreads();
  }

  float bj[8];
#pragma unroll
  for (int j = 0; j < 8; ++j) bj[j] = bias[col0 + tc + j];
#pragma unroll
  for (int i = 0; i < 8; ++i) {
    float* Cp = C + (size_t)(row0 + tr + i) * N + (col0 + tc);
    float4 o0, o1;
    o0.x = acc[i][0] + bj[0]; o0.y = acc[i][1] + bj[1];
    o0.z = acc[i][2] + bj[2]; o0.w = acc[i][3] + bj[3];
    o1.x = acc[i][4] + bj[4]; o1.y = acc[i][5] + bj[5];
    o1.z = acc[i][6] + bj[6]; o1.w = acc[i][7] + bj[7];
    *(float4*)(Cp)     = o0;
    *(float4*)(Cp + 4) = o1;
  }
}

// ---------------- slot-based group wait (wave 0 of each block) ----------
// Polls 32 L1 slots (lanes 0..15, 2 each) and 64 L2 slots (lanes 16..47,
// 2 each) until >= targets, then one ACQUIRE load (cache inv). Slots are
// 64B apart (no line sharing); arrival is a plain RELEASE store.
__device__ __forceinline__ void group_wait(unsigned* slA, unsigned* slB,
                                           unsigned tgtA, unsigned tgtB,
                                           int lane) {
  while (true) {
    int ok = 1;
    if (lane < 16) {
      const unsigned a = __hip_atomic_load(slA + (2 * lane) * 16,
                                           __ATOMIC_RELAXED,
                                           __HIP_MEMORY_SCOPE_AGENT);
      const unsigned b = __hip_atomic_load(slA + (2 * lane + 1) * 16,
                                           __ATOMIC_RELAXED,
                                           __HIP_MEMORY_SCOPE_AGENT);
      ok = (a >= tgtA) && (b >= tgtA);
    } else if (lane < 48) {
      const int j = lane - 16;
      const unsigned a = __hip_atomic_load(slB + (2 * j) * 16,
                                           __ATOMIC_RELAXED,
                                           __HIP_MEMORY_SCOPE_AGENT);
      const unsigned b = __hip_atomic_load(slB + (2 * j + 1) * 16,
                                           __ATOMIC_RELAXED,
                                           __HIP_MEMORY_SCOPE_AGENT);
      ok = (a >= tgtB) && (b >= tgtB);
    }
    if (__all(ok)) break;
    __builtin_amdgcn_s_sleep(1);
  }
  const unsigned f = __hip_atomic_load(slA, __ATOMIC_ACQUIRE,
                                       __HIP_MEMORY_SCOPE_AGENT);
  asm volatile("" :: "v"(f));
}

// ---------------- persistent recurrence v4: slot barrier, decoupled L1/L2
// 192 blocks = 2 batch-groups(32 b) x (32 L1-blocks[16 cols] + 64 L2[8 cols]).
// W slice in LDS (loaded once). h1 ring-4, h2 ring-2. L1 chain syncs only
// its 32 peers (+slack-3 check on L2); L2 runs ~1 phase behind concurrently.
__global__ __launch_bounds__(512, 1)
void lstm_persist3(const float* __restrict__ pre,
                   const u16* __restrict__ WQ1h, const u16* __restrict__ WQ1l,
                   const u16* __restrict__ WQ2h, const u16* __restrict__ WQ2l,
                   const float* __restrict__ b2,
                   u16* __restrict__ h1hi, u16* __restrict__ h1lo,
                   u16* __restrict__ h2hi, u16* __restrict__ h2lo,
                   float* __restrict__ h2all, unsigned* __restrict__ slots) {
  __shared__ u16 Wh[64 * 520];    // L1: [64][520]; L2 uses [32][1032]
  __shared__ u16 Wl[64 * 520];
  __shared__ float ex[2304];      // L1: [32][68]; L2: [2][32][36]

  const int tid  = threadIdx.x;
  const int lane = tid & 63, w = tid >> 6;
  const int l15 = lane & 15, f8 = (lane >> 4) * 8, r4 = (lane >> 4) * 4;
  const int grp = blockIdx.x / 96;
  const int rr  = blockIdx.x % 96;
  const bool isL1 = rr < 32;
  const int gb0 = grp * 32;

  unsigned* slA = slots + grp * 512;           // 32 L1 slots * 16 stride
  unsigned* slB = slots + 1024 + grp * 1024;   // 64 L2 slots * 16 stride

  if (isL1) {
    const int cb1 = rr;
    {  // stage W1 slice into LDS (row pad +8: conflict-light b128 reads)
      const u16* sh = WQ1h + (size_t)cb1 * 64 * 512;
      const u16* sl = WQ1l + (size_t)cb1 * 64 * 512;
      for (int i = tid; i < 64 * 64; i += 512) {
        const int row = i >> 6, c = (i & 63) * 8;
        *(bf16x8*)&Wh[row * 520 + c] = *(const bf16x8*)(sh + row * 512 + c);
        *(bf16x8*)&Wl[row * 520 + c] = *(const bf16x8*)(sl + row * 512 + c);
      }
    }
    __syncthreads();

    const int mt = w >> 2, ng = w & 3;           // 8 waves: 2 b-tiles x 4 gates
    const int eb1 = tid >> 4, em1 = tid & 15;
    const int col1 = cb1 * 16 + em1;
    float creg = 0.f;
    unsigned* my = slA + rr * 16;

    for (int t = 0; t < Tt; ++t) {
      if (w == 0 && t > 0)
        group_wait(slA, slB, (unsigned)t,
                   (unsigned)(t > 3 ? t - 3 : 0), lane);
      __syncthreads();                            // S1: wait done

      const float* pp = pre + ((size_t)(gb0 + eb1) * Tt + t) * Gg + col1;
      const float p0 = pp[0], p1 = pp[512], p2 = pp[1024], p3 = pp[1536];

      f32x4 ae = {0.f, 0.f, 0.f, 0.f}, ao = {0.f, 0.f, 0.f, 0.f};
      if (t > 0) {
        const int sl = (t - 1) & 3;
        const u16* A_h = h1hi + (sl << 15) + (gb0 + mt * 16 + l15) * 512 + f8;
        const u16* A_l = h1lo + (sl << 15) + (gb0 + mt * 16 + l15) * 512 + f8;
        const u16* B_h = &Wh[(ng * 16 + l15) * 520 + f8];
        const u16* B_l = &Wl[(ng * 16 + l15) * 520 + f8];
#pragma unroll
        for (int kc = 0; kc < 16; ++kc) {
          const bf16x8 ah = *(const bf16x8*)(A_h + kc * 32);
          const bf16x8 al = *(const bf16x8*)(A_l + kc * 32);
          const bf16x8 bh = *(const bf16x8*)(B_h + kc * 32);
          const bf16x8 bl = *(const bf16x8*)(B_l + kc * 32);
          if (kc & 1) ao = mm3(ao, ah, al, bh, bl);
          else        ae = mm3(ae, ah, al, bh, bl);
        }
      }
#pragma unroll
      for (int r = 0; r < 4; ++r)
        ex[(mt * 16 + r4 + r) * 68 + ng * 16 + l15] = ae[r] + ao[r];
      __syncthreads();                            // S2: ex ready

      {
        const float gi = p0 + ex[eb1 * 68 + em1];
        const float gj = p1 + ex[eb1 * 68 + 16 + em1];
        const float gf = p2 + ex[eb1 * 68 + 32 + em1];
        const float go = p3 + ex[eb1 * 68 + 48 + em1];
        creg = fmaf(creg, sigm(gf + 1.f), sigm(gi) * tanhf(gj));
        const float nh = tanhf(creg) * sigm(go);
        u16 hh, hl;
        split_bf16(nh, hh, hl);
        const int o = ((t & 3) << 15) + (gb0 + eb1) * 512 + col1;
        h1hi[o] = hh;
        h1lo[o] = hl;
      }
      __syncthreads();                            // S3: drains all stores
      if (tid == 0)
        __hip_atomic_store(my, (unsigned)(t + 1), __ATOMIC_RELEASE,
                           __HIP_MEMORY_SCOPE_AGENT);
    }
  } else {
    const int cb2 = rr - 32;
    {  // stage W2 slice into LDS
      const u16* sh = WQ2h + (size_t)cb2 * 32 * 1024;
      const u16* sl = WQ2l + (size_t)cb2 * 32 * 1024;
      for (int i = tid; i < 32 * 128; i += 512) {
        const int row = i >> 7, c = (i & 127) * 8;
        *(bf16x8*)&Wh[row * 1032 + c] = *(const bf16x8*)(sh + row * 1024 + c);
        *(bf16x8*)&Wl[row * 1032 + c] = *(const bf16x8*)(sl + row * 1024 + c);
      }
    }
    __syncthreads();

    const int mt = w >> 2;          // 2 batch tiles
    const int nt = (w >> 1) & 1;    // 2 col tiles
    const int kh = w & 1;           // K half (0: h1, 1: h2)
    const int eb2 = (tid >> 3) & 31, em2 = tid & 7;
    const int col2 = cb2 * 8 + em2;
    float b2i = 0.f, b2j = 0.f, b2f = 0.f, b2o = 0.f;
    if (tid < 256) {
      b2i = b2[col2];        b2j = b2[512 + col2];
      b2f = b2[1024 + col2]; b2o = b2[1536 + col2];
    }
    float creg = 0.f;
    unsigned* my = slB + cb2 * 16;

    for (int p = 1; p <= Tt; ++p) {
      if (w == 0)
        group_wait(slA, slB, (unsigned)p, (unsigned)(p - 1), lane);
      __syncthreads();                            // S1

      f32x4 ae = {0.f, 0.f, 0.f, 0.f}, ao = {0.f, 0.f, 0.f, 0.f};
      const bool act = kh ? (p >= 2) : true;
      if (act) {
        const u16 *hb, *lb;
        if (kh) {
          const int sl = (p - 2) & 1;
          hb = h2hi + (sl << 15);
          lb = h2lo + (sl << 15);
        } else {
          const int sl = (p - 1) & 3;
          hb = h1hi + (sl << 15);
          lb = h1lo + (sl << 15);
        }
        const u16* A_h = hb + (gb0 + mt * 16 + l15) * 512 + f8;
        const u16* A_l = lb + (gb0 + mt * 16 + l15) * 512 + f8;
        const u16* B_h = &Wh[(nt * 16 + l15) * 1032 + kh * 512 + f8];
        const u16* B_l = &Wl[(nt * 16 + l15) * 1032 + kh * 512 + f8];
#pragma unroll
        for (int kc = 0; kc < 16; ++kc) {
          const bf16x8 ah = *(const bf16x8*)(A_h + kc * 32);
          const bf16x8 al = *(const bf16x8*)(A_l + kc * 32);
          const bf16x8 bh = *(const bf16x8*)(B_h + kc * 32);
          const bf16x8 bl = *(const bf16x8*)(B_l + kc * 32);
          if (kc & 1) ao = mm3(ao, ah, al, bh, bl);
          else        ae = mm3(ae, ah, al, bh, bl);
        }
      }
#pragma unroll
      for (int r = 0; r < 4; ++r)
        ex[kh * 1152 + (mt * 16 + r4 + r) * 36 + nt * 16 + l15] = ae[r] + ao[r];
      __syncthreads();                            // S2

      if (tid < 256) {
        const int bix = eb2 * 36 + em2;
        const float gi = b2i + ex[bix]      + ex[1152 + bix];
        const float gj = b2j + ex[bix + 8]  + ex[1152 + bix + 8];
        const float gf = b2f + ex[bix + 16] + ex[1152 + bix + 16];
        const float go = b2o + ex[bix + 24] + ex[1152 + bix + 24];
        creg = fmaf(creg, sigm(gf + 1.f), sigm(gi) * tanhf(gj));
        const float nh = tanhf(creg) * sigm(go);
        h2all[((size_t)(gb0 + eb2) * Tt + (p - 1)) * Hh + col2] = nh;
        u16 hh, hl;
        split_bf16(nh, hh, hl);
        const int o = (((p - 1) & 1) << 15) + (gb0 + eb2) * 512 + col2;
        h2hi[o] = hh;
        h2lo[o] = hl;
      }
      __syncthreads();                            // S3
      if (tid == 0)
        __hip_atomic_store(my, (unsigned)p, __ATOMIC_RELEASE,
                           __HIP_MEMORY_SCOPE_AGENT);
    }
  }
}

// ---------------- Output projection + softmax + CE ----------------
__global__ __launch_bounds__(128)
void proj_softmax(const float* __restrict__ h2, const float* __restrict__ Wout,
                  const float* __restrict__ bout, const int* __restrict__ labels,
                  float* __restrict__ preds, float* __restrict__ ce) {
  __shared__ float hs[8][Hh];
  __shared__ float wred[2][2];
  const int tid = threadIdx.x;
  const int wid = tid >> 6;
  const int r0  = blockIdx.x * 8;

  for (int i = tid; i < 8 * (Hh / 4); i += 128) {
    const int row = i >> 7;
    const int c4  = i & 127;
    ((float4*)hs[row])[c4] =
        ((const float4*)(h2 + ((size_t)(r0 + row) * Hh)))[c4];
  }
  __syncthreads();

  const bool act = (tid < Cc);
  float acc[8];
  {
    const float bj = act ? bout[tid] : 0.f;
#pragma unroll
    for (int i = 0; i < 8; ++i) acc[i] = bj;
  }
  if (act) {
#pragma unroll 4
    for (int k = 0; k < Hh; ++k) {
      const float w = Wout[k * Cc + tid];
#pragma unroll
      for (int i = 0; i < 8; ++i) acc[i] = fmaf(hs[i][k], w, acc[i]);
    }
  }

  for (int row = 0; row < 8; ++row) {
    const float v = act ? acc[row] : -INFINITY;
    float mw = v;
#pragma unroll
    for (int off = 32; off > 0; off >>= 1) mw = fmaxf(mw, __shfl_xor(mw, off));
    if ((tid & 63) == 0) wred[0][wid] = mw;
    __syncthreads();
    const float mx = fmaxf(wred[0][0], wred[0][1]);
    const float e = act ? expf(v - mx) : 0.f;
    float sw = e;
#pragma unroll
    for (int off = 32; off > 0; off >>= 1) sw += __shfl_xor(sw, off);
    if ((tid & 63) == 0) wred[1][wid] = sw;
    __syncthreads();
    const float sum = wred[1][0] + wred[1][1];
    if (act) preds[(size_t)(r0 + row) * Cc + tid] = e / sum;
    const int lab = labels[r0 + row];
    if (tid == lab) ce[r0 + row] = logf(sum) + mx - v;
    __syncthreads();
  }
}

__global__ __launch_bounds__(256)
void reduce_cost(const float* __restrict__ ce, float* __restrict__ out) {
  __shared__ float red[256];
  const int tid = threadIdx.x;
  float s = 0.f;
  for (int i = tid; i < ROWS; i += 256) s += ce[i];
  red[tid] = s;
  __syncthreads();
  for (int st = 128; st > 0; st >>= 1) {
    if (tid < st) red[tid] += red[tid + st];
    __syncthreads();
  }
  if (tid == 0) out[0] = red[0] / (float)Bb;
}

// ---------------- launch ----------------
extern "C" void kernel_launch(void* const* d_in, const int* in_sizes, int n_in,
                              void* d_out, int out_size, void* d_ws, size_t ws_size,
                              hipStream_t stream) {
  const float* inputs = (const float*)d_in[0];
  const int*   labels = (const int*)d_in[1];
  const float* W1     = (const float*)d_in[2];
  const float* b1     = (const float*)d_in[3];
  const float* W2     = (const float*)d_in[4];
  const float* b2     = (const float*)d_in[5];
  const float* Wout   = (const float*)d_in[6];
  const float* bout   = (const float*)d_in[7];
  float* out = (float*)d_out;

  float* ws    = (float*)d_ws;
  float* pre   = ws;                               // ROWS*Gg   (64 MB)
  float* h2all = pre   + (size_t)ROWS * Gg;        // ROWS*Hh
  float* ceb   = h2all + (size_t)ROWS * Hh;        // ROWS
  u16* h1hi = (u16*)(ceb + ROWS);                  // [4][64][512]
  u16* h1lo = h1hi + 4 * 64 * 512;
  u16* h2hi = h1lo + 4 * 64 * 512;                 // [2][64][512]
  u16* h2lo = h2hi + 2 * 64 * 512;
  u16* WQ1h = h2lo + 2 * 64 * 512;                 // 32*64*512
  u16* WQ1l = WQ1h + 32 * 64 * 512;
  u16* WQ2h = WQ1l + 32 * 64 * 512;                // 64*32*1024
  u16* WQ2l = WQ2h + 64 * 32 * 1024;
  unsigned* slots = (unsigned*)(WQ2l + 64 * 32 * 1024);   // 4096 u32
  u16* Xhi  = (u16*)(slots + 4096);                // ROWS*Dd
  u16* Xlo  = Xhi  + (size_t)ROWS * Dd;
  u16* W1Th = Xlo  + (size_t)ROWS * Dd;            // Gg*Dd
  u16* W1Tl = W1Th + (size_t)Gg * Dd;
  const size_t need = (size_t)((char*)(W1Tl + (size_t)Gg * Dd) - (char*)d_ws);
  const bool use_mfma = ws_size >= need;

  init_slots<<<1, 256, 0, stream>>>(slots);
  // recurrent weights: permute+split once
  permuteW2<<<dim3(16, 64), dim3(32, 8), 0, stream>>>(
      W1 + (size_t)Dd * Gg, WQ1h, WQ1l, 512);
  permuteW3<<<dim3(32, 64), dim3(32, 8), 0, stream>>>(W2, WQ2h, WQ2l);

  // Layer 1 input projection: pre = X @ W1[0:D,:] + b1
  if (use_mfma) {
    convert_hilo<<<2048, 256, 0, stream>>>(inputs, Xhi, Xlo, ROWS * Dd / 4);
    convertT_w1<<<dim3(64, 64), dim3(32, 8), 0, stream>>>(W1, W1Th, W1Tl);
    gemm1_mfma<<<dim3(Gg / 128, ROWS / 128), 256, 0, stream>>>(
        Xhi, Xlo, W1Th, W1Tl, b1, pre);
  } else {
    sgemm_bias<<<dim3(Gg / BN, ROWS / BM), dim3(256), 0, stream>>>(
        inputs, W1, b1, pre, ROWS, Gg, Dd);
  }

  // Entire recurrence in ONE dispatch: slot-signaled, decoupled L1/L2
  lstm_persist3<<<192, 512, 0, stream>>>(pre, WQ1h, WQ1l, WQ2h, WQ2l, b2,
                                         h1hi, h1lo, h2hi, h2lo, h2all, slots);

  proj_softmax<<<ROWS / 8, 128, 0, stream>>>(h2all, Wout, bout, labels, out, ceb);
  reduce_cost<<<1, 256, 0, stream>>>(ceb, out + (size_t)ROWS * Cc);
}

// Round 13
// 1822.131 us; speedup vs baseline: 3.7993x; 1.2461x over previous
//
#include <hip/hip_runtime.h>
#include <cmath>

// Problem constants
#define Bb   64
#define Tt   128
#define Dd   2048
#define Hh   512
#define Gg   2048      // 4*H
#define Cc   101
#define ROWS 8192      // B*T

typedef unsigned short u16;
typedef __attribute__((ext_vector_type(8))) short bf16x8;
typedef __attribute__((ext_vector_type(4))) float f32x4;

// ---------------- bf16 hi/lo split helpers ----------------
__device__ __forceinline__ u16 bf16rne(float x) {
  unsigned u = __float_as_uint(x);
  unsigned r = (u + 0x7fffu + ((u >> 16) & 1u)) >> 16;
  return (u16)r;
}
__device__ __forceinline__ void split_bf16(float x, u16& h, u16& l) {
  h = bf16rne(x);
  l = bf16rne(x - __uint_as_float(((unsigned)h) << 16));
}
__device__ __forceinline__ float sigm(float x) { return 1.f / (1.f + expf(-x)); }

// X [ROWS x Dd] fp32 -> Xhi, Xlo bf16 (same layout)
__global__ __launch_bounds__(256)
void convert_hilo(const float* __restrict__ src, u16* __restrict__ hi,
                  u16* __restrict__ lo, int n4) {
  for (int i = blockIdx.x * 256 + threadIdx.x; i < n4; i += gridDim.x * 256) {
    const float4 v = ((const float4*)src)[i];
    ushort4 h, l;
    split_bf16(v.x, h.x, l.x);
    split_bf16(v.y, h.y, l.y);
    split_bf16(v.z, h.z, l.z);
    split_bf16(v.w, h.w, l.w);
    ((ushort4*)hi)[i] = h;
    ((ushort4*)lo)[i] = l;
  }
}

// W1 top [Dd x Gg] -> W1T hi/lo [Gg x Dd] bf16  (for gemm1 B operand)
__global__ __launch_bounds__(256)
void convertT_w1(const float* __restrict__ W1, u16* __restrict__ Th,
                 u16* __restrict__ Tl) {
  __shared__ float tl[32][33];
  const int tx = threadIdx.x, ty = threadIdx.y;   // 32, 8
  const int k0 = blockIdx.x * 32, c0 = blockIdx.y * 32;
#pragma unroll
  for (int j = 0; j < 4; ++j)
    tl[ty + j * 8][tx] = W1[(size_t)(k0 + ty + j * 8) * Gg + (c0 + tx)];
  __syncthreads();
#pragma unroll
  for (int j = 0; j < 4; ++j) {
    const float v = tl[tx][ty + j * 8];
    u16 h, l;
    split_bf16(v, h, l);
    const size_t o = (size_t)(c0 + ty + j * 8) * Dd + (k0 + tx);
    Th[o] = h;
    Tl[o] = l;
  }
}

// Recurrent weights, permuted + split:
// WP[cg 128][vc 16][K], vc = g*4 + m for col = g*512 + cg*4 + m.
__global__ __launch_bounds__(256)
void permuteW(const float* __restrict__ src, u16* __restrict__ dh,
              u16* __restrict__ dl, int K) {
  __shared__ float tl[32][33];
  const int tx = threadIdx.x, ty = threadIdx.y;   // 32, 8
  const int k0 = blockIdx.x * 32, c0 = blockIdx.y * 32;
#pragma unroll
  for (int j = 0; j < 4; ++j)
    tl[ty + j * 8][tx] = src[(size_t)(k0 + ty + j * 8) * Gg + (c0 + tx)];
  __syncthreads();
#pragma unroll
  for (int j = 0; j < 4; ++j) {
    const int col = c0 + ty + j * 8;
    const int g = col >> 9, mg = col & 511;
    const int cg = mg >> 2, m = mg & 3;
    const float v = tl[tx][ty + j * 8];
    u16 h, l;
    split_bf16(v, h, l);
    const size_t o = (size_t)(cg * 16 + g * 4 + m) * K + k0 + tx;
    dh[o] = h;
    dl[o] = l;
  }
}

// ---------------- MFMA bf16x3 GEMM: pre = X @ W1 + b1 ----------------
__global__ __launch_bounds__(256)
void gemm1_mfma(const u16* __restrict__ Ah, const u16* __restrict__ Al,
                const u16* __restrict__ Bh, const u16* __restrict__ Bl,
                const float* __restrict__ bias, float* __restrict__ C) {
  __shared__ u16 Ash[128][40];
  __shared__ u16 Asl[128][40];
  __shared__ u16 Bsh[128][40];
  __shared__ u16 Bsl[128][40];
  const int tid  = threadIdx.x;
  const int lane = tid & 63, wave = tid >> 6;
  const int wm = wave >> 1, wn = wave & 1;
  const int l15 = lane & 15, k8 = (lane >> 4) * 8, r4 = (lane >> 4) * 4;
  const int row0 = blockIdx.y * 128, col0 = blockIdx.x * 128;
  const int srow = tid >> 1, sk = (tid & 1) * 16;

  const u16* pAh = Ah + (size_t)(row0 + srow) * Dd + sk;
  const u16* pAl = Al + (size_t)(row0 + srow) * Dd + sk;
  const u16* pBh = Bh + (size_t)(col0 + srow) * Dd + sk;
  const u16* pBl = Bl + (size_t)(col0 + srow) * Dd + sk;

  f32x4 acc[4][4];
#pragma unroll
  for (int i = 0; i < 4; ++i)
#pragma unroll
    for (int j = 0; j < 4; ++j) acc[i][j] = (f32x4){0.f, 0.f, 0.f, 0.f};

  for (int k0 = 0; k0 < Dd; k0 += 32) {
    *(bf16x8*)(&Ash[srow][sk])     = *(const bf16x8*)(pAh + k0);
    *(bf16x8*)(&Ash[srow][sk + 8]) = *(const bf16x8*)(pAh + k0 + 8);
    *(bf16x8*)(&Asl[srow][sk])     = *(const bf16x8*)(pAl + k0);
    *(bf16x8*)(&Asl[srow][sk + 8]) = *(const bf16x8*)(pAl + k0 + 8);
    *(bf16x8*)(&Bsh[srow][sk])     = *(const bf16x8*)(pBh + k0);
    *(bf16x8*)(&Bsh[srow][sk + 8]) = *(const bf16x8*)(pBh + k0 + 8);
    *(bf16x8*)(&Bsl[srow][sk])     = *(const bf16x8*)(pBl + k0);
    *(bf16x8*)(&Bsl[srow][sk + 8]) = *(const bf16x8*)(pBl + k0 + 8);
    __syncthreads();

    bf16x8 afh[4], afl[4], bfh[4], bfl[4];
#pragma unroll
    for (int mt = 0; mt < 4; ++mt) {
      afh[mt] = *(const bf16x8*)(&Ash[wm * 64 + mt * 16 + l15][k8]);
      afl[mt] = *(const bf16x8*)(&Asl[wm * 64 + mt * 16 + l15][k8]);
    }
#pragma unroll
    for (int nt = 0; nt < 4; ++nt) {
      bfh[nt] = *(const bf16x8*)(&Bsh[wn * 64 + nt * 16 + l15][k8]);
      bfl[nt] = *(const bf16x8*)(&Bsl[wn * 64 + nt * 16 + l15][k8]);
    }
#pragma unroll
    for (int mt = 0; mt < 4; ++mt)
#pragma unroll
      for (int nt = 0; nt < 4; ++nt) {
        acc[mt][nt] = __builtin_amdgcn_mfma_f32_16x16x32_bf16(
            afh[mt], bfh[nt], acc[mt][nt], 0, 0, 0);
        acc[mt][nt] = __builtin_amdgcn_mfma_f32_16x16x32_bf16(
            afh[mt], bfl[nt], acc[mt][nt], 0, 0, 0);
        acc[mt][nt] = __builtin_amdgcn_mfma_f32_16x16x32_bf16(
            afl[mt], bfh[nt], acc[mt][nt], 0, 0, 0);
      }
    __syncthreads();
  }

#pragma unroll
  for (int nt = 0; nt < 4; ++nt) {
    const int col = col0 + wn * 64 + nt * 16 + l15;
    const float bj = bias[col];
#pragma unroll
    for (int mt = 0; mt < 4; ++mt) {
      float* Cp = C + (size_t)(row0 + wm * 64 + mt * 16 + r4) * Gg + col;
#pragma unroll
      for (int r = 0; r < 4; ++r)
        Cp[(size_t)r * Gg] = acc[mt][nt][r] + bj;
    }
  }
}

// ---------------- SGEMM (fp32 fallback if ws too small) ----------------
#define BM 128
#define BN 128
#define BK 16

__global__ __launch_bounds__(256)
void sgemm_bias(const float* __restrict__ A, const float* __restrict__ B,
                const float* __restrict__ bias, float* __restrict__ C,
                int M, int N, int K) {
  __shared__ float As[BK][BM];
  __shared__ float Bs[BK][BN];
  const int tid  = threadIdx.x;
  const int row0 = blockIdx.y * BM, col0 = blockIdx.x * BN;
  const int tr = (tid >> 4) << 3;
  const int tc = (tid & 15) << 3;

  float acc[8][8];
#pragma unroll
  for (int i = 0; i < 8; ++i)
#pragma unroll
    for (int j = 0; j < 8; ++j) acc[i][j] = 0.f;

  const int arow = tid >> 1;
  const int acol = (tid & 1) << 3;
  const int brow = tid >> 4;
  const int bcol = (tid & 15) << 3;
  const float* Ap = A + (size_t)(row0 + arow) * K + acol;
  const float* Bp = B + (size_t)brow * N + (col0 + bcol);

  for (int k0 = 0; k0 < K; k0 += BK) {
    const float4 a0 = *(const float4*)(Ap + k0);
    const float4 a1 = *(const float4*)(Ap + k0 + 4);
    const float4 bv0 = *(const float4*)(Bp + (size_t)k0 * N);
    const float4 bv1 = *(const float4*)(Bp + (size_t)k0 * N + 4);
    As[acol + 0][arow] = a0.x;
    As[acol + 1][arow] = a0.y;
    As[acol + 2][arow] = a0.z;
    As[acol + 3][arow] = a0.w;
    As[acol + 4][arow] = a1.x;
    As[acol + 5][arow] = a1.y;
    As[acol + 6][arow] = a1.z;
    As[acol + 7][arow] = a1.w;
    *(float4*)(&Bs[brow][bcol])     = bv0;
    *(float4*)(&Bs[brow][bcol + 4]) = bv1;
    __syncthreads();
#pragma unroll
    for (int k = 0; k < BK; ++k) {
      float a[8], b[8];
      *(float4*)(a)     = *(const float4*)(&As[k][tr]);
      *(float4*)(a + 4) = *(const float4*)(&As[k][tr + 4]);
      *(float4*)(b)     = *(const float4*)(&Bs[k][tc]);
      *(float4*)(b + 4) = *(const float4*)(&Bs[k][tc + 4]);
#pragma unroll
      for (int i = 0; i < 8; ++i)
#pragma unroll
        for (int j = 0; j < 8; ++j)
          acc[i][j] = fmaf(a[i], b[j], acc[i][j]);
    }
    __syncthreads();
  }

  float bj[8];
#pragma unroll
  for (int j = 0; j < 8; ++j) bj[j] = bias[col0 + tc + j];
#pragma unroll
  for (int i = 0; i < 8; ++i) {
    float* Cp = C + (size_t)(row0 + tr + i) * N + (col0 + tc);
    float4 o0, o1;
    o0.x = acc[i][0] + bj[0]; o0.y = acc[i][1] + bj[1];
    o0.z = acc[i][2] + bj[2]; o0.w = acc[i][3] + bj[3];
    o1.x = acc[i][4] + bj[4]; o1.y = acc[i][5] + bj[5];
    o1.z = acc[i][6] + bj[6]; o1.w = acc[i][7] + bj[7];
    *(float4*)(Cp)     = o0;
    *(float4*)(Cp + 4) = o1;
  }
}

// ---------------- MFMA fused step (R7 structure, 128-k chunks) ----------
// One launch per phase t: blocks 0..127 = L1 step t (cg = blockIdx),
// 128..255 = L2 step t-1 (K=1024 = [h1[t-1]; h2[t-2]]).
// Block: all 64 batches x 16 strided cols {g*512 + cg*4 + m}.
// wave w = batch tile (16 rows). Double-buffered 128-k chunks: barriers
// per 512-K half drop 17 -> 5 (the measured phase cost was barrier-bound).
__device__ __forceinline__ void mm_half(
    const u16* __restrict__ hh_src, const u16* __restrict__ hl_src,
    const u16* __restrict__ wph, const u16* __restrict__ wpl, int Kw,
    f32x4& acc, u16 (*Ah)[64][136], u16 (*Al)[64][136],
    u16 (*Bh)[16][136], u16 (*Bl)[16][136], int tid, int lane, int w) {
  const int hr = tid >> 2, hk = (tid & 3) * 32;   // h: 4 thr/row, 32 u16 each
  const int wv = tid >> 4, wk = (tid & 15) * 8;   // W: 16 thr/row, 8 u16 each
  const int fr = lane & 15, f8 = (lane >> 4) * 8;

  bf16x8 rh[4], rl[4], rwh, rwl;
#pragma unroll
  for (int j = 0; j < 4; ++j) {
    rh[j] = *(const bf16x8*)(hh_src + hr * 512 + hk + j * 8);
    rl[j] = *(const bf16x8*)(hl_src + hr * 512 + hk + j * 8);
  }
  rwh = *(const bf16x8*)(wph + (size_t)wv * Kw + wk);
  rwl = *(const bf16x8*)(wpl + (size_t)wv * Kw + wk);
#pragma unroll
  for (int j = 0; j < 4; ++j) {
    *(bf16x8*)&Ah[0][hr][hk + j * 8] = rh[j];
    *(bf16x8*)&Al[0][hr][hk + j * 8] = rl[j];
  }
  *(bf16x8*)&Bh[0][wv][wk] = rwh;
  *(bf16x8*)&Bl[0][wv][wk] = rwl;
  __syncthreads();

  for (int kc = 0; kc < 4; ++kc) {
    const int cur = kc & 1;
    if (kc < 3) {
      const int ko = (kc + 1) * 128;
#pragma unroll
      for (int j = 0; j < 4; ++j) {
        rh[j] = *(const bf16x8*)(hh_src + hr * 512 + ko + hk + j * 8);
        rl[j] = *(const bf16x8*)(hl_src + hr * 512 + ko + hk + j * 8);
      }
      rwh = *(const bf16x8*)(wph + (size_t)wv * Kw + ko + wk);
      rwl = *(const bf16x8*)(wpl + (size_t)wv * Kw + ko + wk);
    }
#pragma unroll
    for (int s = 0; s < 4; ++s) {
      const bf16x8 afh = *(const bf16x8*)&Ah[cur][w * 16 + fr][s * 32 + f8];
      const bf16x8 afl = *(const bf16x8*)&Al[cur][w * 16 + fr][s * 32 + f8];
      const bf16x8 bfh = *(const bf16x8*)&Bh[cur][fr][s * 32 + f8];
      const bf16x8 bfl = *(const bf16x8*)&Bl[cur][fr][s * 32 + f8];
      acc = __builtin_amdgcn_mfma_f32_16x16x32_bf16(afh, bfh, acc, 0, 0, 0);
      acc = __builtin_amdgcn_mfma_f32_16x16x32_bf16(afh, bfl, acc, 0, 0, 0);
      acc = __builtin_amdgcn_mfma_f32_16x16x32_bf16(afl, bfh, acc, 0, 0, 0);
    }
    if (kc < 3) {
      const int nb = cur ^ 1;
#pragma unroll
      for (int j = 0; j < 4; ++j) {
        *(bf16x8*)&Ah[nb][hr][hk + j * 8] = rh[j];
        *(bf16x8*)&Al[nb][hr][hk + j * 8] = rl[j];
      }
      *(bf16x8*)&Bh[nb][wv][wk] = rwh;
      *(bf16x8*)&Bl[nb][wv][wk] = rwl;
    }
    __syncthreads();
  }
}

__global__ __launch_bounds__(256, 1)
void fused_step2(const float* __restrict__ pre,
                 const u16* __restrict__ WP1h, const u16* __restrict__ WP1l,
                 const u16* __restrict__ WP2h, const u16* __restrict__ WP2l,
                 const float* __restrict__ b2,
                 u16* __restrict__ h1hi, u16* __restrict__ h1lo,
                 u16* __restrict__ h2hi, u16* __restrict__ h2lo,
                 float* __restrict__ h2all,
                 float* __restrict__ c1, float* __restrict__ c2, int t) {
  __shared__ u16 Ah[2][64][136], Al[2][64][136];
  __shared__ u16 Bh[2][16][136], Bl[2][16][136];
  __shared__ float ex[4][16][17];
  const int tid = threadIdx.x;
  const int lane = tid & 63, w = tid >> 6;
  const int fr = lane & 15;
  const bool isL2 = blockIdx.x >= 128;
  const int cg = blockIdx.x & 127;

  f32x4 acc = {0.f, 0.f, 0.f, 0.f};
  bool have = false;

  if (!isL2) {
    if (t >= Tt) return;
    if (t > 0) {
      const int sl = (t - 1) & 1;
      mm_half(h1hi + (sl << 15), h1lo + (sl << 15),
              WP1h + (size_t)cg * 16 * 512, WP1l + (size_t)cg * 16 * 512, 512,
              acc, Ah, Al, Bh, Bl, tid, lane, w);
      have = true;
    }
  } else {
    if (t < 1) return;
    const u16* ph = WP2h + (size_t)cg * 16 * 1024;
    const u16* pl = WP2l + (size_t)cg * 16 * 1024;
    {
      const int sl = (t - 1) & 1;
      mm_half(h1hi + (sl << 15), h1lo + (sl << 15), ph, pl, 1024,
              acc, Ah, Al, Bh, Bl, tid, lane, w);
    }
    if (t >= 2) {
      const int sl = (t - 2) & 1;
      mm_half(h2hi + (sl << 15), h2lo + (sl << 15), ph + 512, pl + 512, 1024,
              acc, Ah, Al, Bh, Bl, tid, lane, w);
    }
    have = true;
  }

  if (have) {
#pragma unroll
    for (int r = 0; r < 4; ++r)
      ex[w][(lane >> 4) * 4 + r][fr] = acc[r];
  }
  __syncthreads();

  // epilogue: thread -> (batch b, local m); col = cg*4 + m
  const int b = tid >> 2, m = tid & 3;
  float s0 = 0.f, s1 = 0.f, s2 = 0.f, s3 = 0.f;
  if (have) {
    s0 = ex[b >> 4][b & 15][0 + m];
    s1 = ex[b >> 4][b & 15][4 + m];
    s2 = ex[b >> 4][b & 15][8 + m];
    s3 = ex[b >> 4][b & 15][12 + m];
  }
  const int col = cg * 4 + m;
  const int ci = b * Hh + col;
  if (!isL2) {
    const float* pp = pre + ((size_t)b * Tt + t) * Gg + col;
    const float gi = pp[0] + s0, gj = pp[512] + s1;
    const float gf = pp[1024] + s2, go = pp[1536] + s3;
    const float cp = (t > 0) ? c1[ci] : 0.f;
    const float nc = fmaf(cp, sigm(gf + 1.f), sigm(gi) * tanhf(gj));
    c1[ci] = nc;
    const float nh = tanhf(nc) * sigm(go);
    u16 hh, hl;
    split_bf16(nh, hh, hl);
    const int hidx = ((t & 1) << 15) + ci;
    h1hi[hidx] = hh;
    h1lo[hidx] = hl;
  } else {
    const float gi = b2[col] + s0, gj = b2[512 + col] + s1;
    const float gf = b2[1024 + col] + s2, go = b2[1536 + col] + s3;
    const float cp = (t >= 2) ? c2[ci] : 0.f;
    const float nc = fmaf(cp, sigm(gf + 1.f), sigm(gi) * tanhf(gj));
    c2[ci] = nc;
    const float nh = tanhf(nc) * sigm(go);
    h2all[((size_t)b * Tt + (t - 1)) * Hh + col] = nh;
    u16 hh, hl;
    split_bf16(nh, hh, hl);
    const int hidx = (((t - 1) & 1) << 15) + ci;
    h2hi[hidx] = hh;
    h2lo[hidx] = hl;
  }
}

// ---------------- Output projection + softmax + CE ----------------
__global__ __launch_bounds__(128)
void proj_softmax(const float* __restrict__ h2, const float* __restrict__ Wout,
                  const float* __restrict__ bout, const int* __restrict__ labels,
                  float* __restrict__ preds, float* __restrict__ ce) {
  __shared__ float hs[8][Hh];
  __shared__ float wred[2][2];
  const int tid = threadIdx.x;
  const int wid = tid >> 6;
  const int r0  = blockIdx.x * 8;

  for (int i = tid; i < 8 * (Hh / 4); i += 128) {
    const int row = i >> 7;
    const int c4  = i & 127;
    ((float4*)hs[row])[c4] =
        ((const float4*)(h2 + ((size_t)(r0 + row) * Hh)))[c4];
  }
  __syncthreads();

  const bool act = (tid < Cc);
  float acc[8];
  {
    const float bj = act ? bout[tid] : 0.f;
#pragma unroll
    for (int i = 0; i < 8; ++i) acc[i] = bj;
  }
  if (act) {
#pragma unroll 4
    for (int k = 0; k < Hh; ++k) {
      const float w = Wout[k * Cc + tid];
#pragma unroll
      for (int i = 0; i < 8; ++i) acc[i] = fmaf(hs[i][k], w, acc[i]);
    }
  }

  for (int row = 0; row < 8; ++row) {
    const float v = act ? acc[row] : -INFINITY;
    float mw = v;
#pragma unroll
    for (int off = 32; off > 0; off >>= 1) mw = fmaxf(mw, __shfl_xor(mw, off));
    if ((tid & 63) == 0) wred[0][wid] = mw;
    __syncthreads();
    const float mx = fmaxf(wred[0][0], wred[0][1]);
    const float e = act ? expf(v - mx) : 0.f;
    float sw = e;
#pragma unroll
    for (int off = 32; off > 0; off >>= 1) sw += __shfl_xor(sw, off);
    if ((tid & 63) == 0) wred[1][wid] = sw;
    __syncthreads();
    const float sum = wred[1][0] + wred[1][1];
    if (act) preds[(size_t)(r0 + row) * Cc + tid] = e / sum;
    const int lab = labels[r0 + row];
    if (tid == lab) ce[r0 + row] = logf(sum) + mx - v;
    __syncthreads();
  }
}

__global__ __launch_bounds__(256)
void reduce_cost(const float* __restrict__ ce, float* __restrict__ out) {
  __shared__ float red[256];
  const int tid = threadIdx.x;
  float s = 0.f;
  for (int i = tid; i < ROWS; i += 256) s += ce[i];
  red[tid] = s;
  __syncthreads();
  for (int st = 128; st > 0; st >>= 1) {
    if (tid < st) red[tid] += red[tid + st];
    __syncthreads();
  }
  if (tid == 0) out[0] = red[0] / (float)Bb;
}

// ---------------- launch ----------------
extern "C" void kernel_launch(void* const* d_in, const int* in_sizes, int n_in,
                              void* d_out, int out_size, void* d_ws, size_t ws_size,
                              hipStream_t stream) {
  const float* inputs = (const float*)d_in[0];
  const int*   labels = (const int*)d_in[1];
  const float* W1     = (const float*)d_in[2];
  const float* b1     = (const float*)d_in[3];
  const float* W2     = (const float*)d_in[4];
  const float* b2     = (const float*)d_in[5];
  const float* Wout   = (const float*)d_in[6];
  const float* bout   = (const float*)d_in[7];
  float* out = (float*)d_out;

  float* ws    = (float*)d_ws;
  float* pre   = ws;                               // ROWS*Gg   (16M f32)
  float* h2all = pre   + (size_t)ROWS * Gg;        // ROWS*Hh   (4M)
  float* c1    = h2all + (size_t)ROWS * Hh;        // 64*512
  float* c2    = c1    + (size_t)Bb * Hh;
  float* ceb   = c2    + (size_t)Bb * Hh;          // ROWS
  u16* h1hi = (u16*)(ceb + ROWS);                  // [2][64][512]
  u16* h1lo = h1hi + 2 * 64 * 512;
  u16* h2hi = h1lo + 2 * 64 * 512;
  u16* h2lo = h2hi + 2 * 64 * 512;
  u16* WP1h = h2lo + 2 * 64 * 512;                 // 128*16*512
  u16* WP1l = WP1h + 128 * 16 * 512;
  u16* WP2h = WP1l + 128 * 16 * 512;               // 128*16*1024
  u16* WP2l = WP2h + 128 * 16 * 1024;
  u16* Xhi  = WP2l + 128 * 16 * 1024;              // ROWS*Dd
  u16* Xlo  = Xhi  + (size_t)ROWS * Dd;
  u16* W1Th = Xlo  + (size_t)ROWS * Dd;            // Gg*Dd
  u16* W1Tl = W1Th + (size_t)Gg * Dd;
  const size_t need = (size_t)((char*)(W1Tl + (size_t)Gg * Dd) - (char*)d_ws);
  const bool use_mfma = ws_size >= need;

  // recurrent weights: permute+split once
  permuteW<<<dim3(16, 64), dim3(32, 8), 0, stream>>>(
      W1 + (size_t)Dd * Gg, WP1h, WP1l, 512);
  permuteW<<<dim3(32, 64), dim3(32, 8), 0, stream>>>(W2, WP2h, WP2l, 1024);

  // Layer 1 input projection: pre = X @ W1[0:D,:] + b1
  if (use_mfma) {
    convert_hilo<<<2048, 256, 0, stream>>>(inputs, Xhi, Xlo, ROWS * Dd / 4);
    convertT_w1<<<dim3(64, 64), dim3(32, 8), 0, stream>>>(W1, W1Th, W1Tl);
    gemm1_mfma<<<dim3(Gg / 128, ROWS / 128), 256, 0, stream>>>(
        Xhi, Xlo, W1Th, W1Tl, b1, pre);
  } else {
    sgemm_bias<<<dim3(Gg / BN, ROWS / BM), dim3(256), 0, stream>>>(
        inputs, W1, b1, pre, ROWS, Gg, Dd);
  }

  // Recurrence: phase t = L1 step t (blocks 0..127) + L2 step t-1 (128..255)
  for (int t = 0; t <= Tt; ++t)
    fused_step2<<<256, 256, 0, stream>>>(pre, WP1h, WP1l, WP2h, WP2l, b2,
                                         h1hi, h1lo, h2hi, h2lo,
                                         h2all, c1, c2, t);

  proj_softmax<<<ROWS / 8, 128, 0, stream>>>(h2all, Wout, bout, labels, out, ceb);
  reduce_cost<<<1, 256, 0, stream>>>(ceb, out + (size_t)ROWS * Cc);
}

// Round 14
// 1782.735 us; speedup vs baseline: 3.8833x; 1.0221x over previous
//
#include <hip/hip_runtime.h>
#include <cmath>

// Problem constants
#define Bb   64
#define Tt   128
#define Dd   2048
#define Hh   512
#define Gg   2048      // 4*H
#define Cc   101
#define PC   112       // classes padded to 7*16 for MFMA
#define ROWS 8192      // B*T

typedef unsigned short u16;
typedef __attribute__((ext_vector_type(8))) short bf16x8;
typedef __attribute__((ext_vector_type(4))) float f32x4;

// ---------------- bf16 hi/lo split helpers ----------------
__device__ __forceinline__ u16 bf16rne(float x) {
  unsigned u = __float_as_uint(x);
  unsigned r = (u + 0x7fffu + ((u >> 16) & 1u)) >> 16;
  return (u16)r;
}
__device__ __forceinline__ void split_bf16(float x, u16& h, u16& l) {
  h = bf16rne(x);
  l = bf16rne(x - __uint_as_float(((unsigned)h) << 16));
}
__device__ __forceinline__ float sigm(float x) { return 1.f / (1.f + expf(-x)); }

// X [ROWS x Dd] fp32 -> Xhi, Xlo bf16 (same layout)
__global__ __launch_bounds__(256)
void convert_hilo(const float* __restrict__ src, u16* __restrict__ hi,
                  u16* __restrict__ lo, int n4) {
  for (int i = blockIdx.x * 256 + threadIdx.x; i < n4; i += gridDim.x * 256) {
    const float4 v = ((const float4*)src)[i];
    ushort4 h, l;
    split_bf16(v.x, h.x, l.x);
    split_bf16(v.y, h.y, l.y);
    split_bf16(v.z, h.z, l.z);
    split_bf16(v.w, h.w, l.w);
    ((ushort4*)hi)[i] = h;
    ((ushort4*)lo)[i] = l;
  }
}

// W1 top [Dd x Gg] -> W1T hi/lo [Gg x Dd] bf16  (for gemm1 B operand)
__global__ __launch_bounds__(256)
void convertT_w1(const float* __restrict__ W1, u16* __restrict__ Th,
                 u16* __restrict__ Tl) {
  __shared__ float tl[32][33];
  const int tx = threadIdx.x, ty = threadIdx.y;   // 32, 8
  const int k0 = blockIdx.x * 32, c0 = blockIdx.y * 32;
#pragma unroll
  for (int j = 0; j < 4; ++j)
    tl[ty + j * 8][tx] = W1[(size_t)(k0 + ty + j * 8) * Gg + (c0 + tx)];
  __syncthreads();
#pragma unroll
  for (int j = 0; j < 4; ++j) {
    const float v = tl[tx][ty + j * 8];
    u16 h, l;
    split_bf16(v, h, l);
    const size_t o = (size_t)(c0 + ty + j * 8) * Dd + (k0 + tx);
    Th[o] = h;
    Tl[o] = l;
  }
}

// Wout [Hh x Cc] -> WoutT hi/lo [PC x Hh] (rows >= Cc zero)
__global__ __launch_bounds__(256)
void convert_woutT(const float* __restrict__ Wout, u16* __restrict__ Th,
                   u16* __restrict__ Tl) {
  const int c = blockIdx.x;
  for (int k = threadIdx.x; k < Hh; k += 256) {
    const float v = (c < Cc) ? Wout[k * Cc + c] : 0.f;
    u16 h, l;
    split_bf16(v, h, l);
    Th[c * Hh + k] = h;
    Tl[c * Hh + k] = l;
  }
}

// Recurrent weights, permuted + split:
// WP[cg 128][vc 16][K], vc = g*4 + m for col = g*512 + cg*4 + m.
__global__ __launch_bounds__(256)
void permuteW(const float* __restrict__ src, u16* __restrict__ dh,
              u16* __restrict__ dl, int K) {
  __shared__ float tl[32][33];
  const int tx = threadIdx.x, ty = threadIdx.y;   // 32, 8
  const int k0 = blockIdx.x * 32, c0 = blockIdx.y * 32;
#pragma unroll
  for (int j = 0; j < 4; ++j)
    tl[ty + j * 8][tx] = src[(size_t)(k0 + ty + j * 8) * Gg + (c0 + tx)];
  __syncthreads();
#pragma unroll
  for (int j = 0; j < 4; ++j) {
    const int col = c0 + ty + j * 8;
    const int g = col >> 9, mg = col & 511;
    const int cg = mg >> 2, m = mg & 3;
    const float v = tl[tx][ty + j * 8];
    u16 h, l;
    split_bf16(v, h, l);
    const size_t o = (size_t)(cg * 16 + g * 4 + m) * K + k0 + tx;
    dh[o] = h;
    dl[o] = l;
  }
}

// ---------------- MFMA bf16x3 GEMM: pre = X @ W1 + b1 ----------------
__global__ __launch_bounds__(256)
void gemm1_mfma(const u16* __restrict__ Ah, const u16* __restrict__ Al,
                const u16* __restrict__ Bh, const u16* __restrict__ Bl,
                const float* __restrict__ bias, float* __restrict__ C) {
  __shared__ u16 Ash[128][40];
  __shared__ u16 Asl[128][40];
  __shared__ u16 Bsh[128][40];
  __shared__ u16 Bsl[128][40];
  const int tid  = threadIdx.x;
  const int lane = tid & 63, wave = tid >> 6;
  const int wm = wave >> 1, wn = wave & 1;
  const int l15 = lane & 15, k8 = (lane >> 4) * 8, r4 = (lane >> 4) * 4;
  const int row0 = blockIdx.y * 128, col0 = blockIdx.x * 128;
  const int srow = tid >> 1, sk = (tid & 1) * 16;

  const u16* pAh = Ah + (size_t)(row0 + srow) * Dd + sk;
  const u16* pAl = Al + (size_t)(row0 + srow) * Dd + sk;
  const u16* pBh = Bh + (size_t)(col0 + srow) * Dd + sk;
  const u16* pBl = Bl + (size_t)(col0 + srow) * Dd + sk;

  f32x4 acc[4][4];
#pragma unroll
  for (int i = 0; i < 4; ++i)
#pragma unroll
    for (int j = 0; j < 4; ++j) acc[i][j] = (f32x4){0.f, 0.f, 0.f, 0.f};

  for (int k0 = 0; k0 < Dd; k0 += 32) {
    *(bf16x8*)(&Ash[srow][sk])     = *(const bf16x8*)(pAh + k0);
    *(bf16x8*)(&Ash[srow][sk + 8]) = *(const bf16x8*)(pAh + k0 + 8);
    *(bf16x8*)(&Asl[srow][sk])     = *(const bf16x8*)(pAl + k0);
    *(bf16x8*)(&Asl[srow][sk + 8]) = *(const bf16x8*)(pAl + k0 + 8);
    *(bf16x8*)(&Bsh[srow][sk])     = *(const bf16x8*)(pBh + k0);
    *(bf16x8*)(&Bsh[srow][sk + 8]) = *(const bf16x8*)(pBh + k0 + 8);
    *(bf16x8*)(&Bsl[srow][sk])     = *(const bf16x8*)(pBl + k0);
    *(bf16x8*)(&Bsl[srow][sk + 8]) = *(const bf16x8*)(pBl + k0 + 8);
    __syncthreads();

    bf16x8 afh[4], afl[4], bfh[4], bfl[4];
#pragma unroll
    for (int mt = 0; mt < 4; ++mt) {
      afh[mt] = *(const bf16x8*)(&Ash[wm * 64 + mt * 16 + l15][k8]);
      afl[mt] = *(const bf16x8*)(&Asl[wm * 64 + mt * 16 + l15][k8]);
    }
#pragma unroll
    for (int nt = 0; nt < 4; ++nt) {
      bfh[nt] = *(const bf16x8*)(&Bsh[wn * 64 + nt * 16 + l15][k8]);
      bfl[nt] = *(const bf16x8*)(&Bsl[wn * 64 + nt * 16 + l15][k8]);
    }
#pragma unroll
    for (int mt = 0; mt < 4; ++mt)
#pragma unroll
      for (int nt = 0; nt < 4; ++nt) {
        acc[mt][nt] = __builtin_amdgcn_mfma_f32_16x16x32_bf16(
            afh[mt], bfh[nt], acc[mt][nt], 0, 0, 0);
        acc[mt][nt] = __builtin_amdgcn_mfma_f32_16x16x32_bf16(
            afh[mt], bfl[nt], acc[mt][nt], 0, 0, 0);
        acc[mt][nt] = __builtin_amdgcn_mfma_f32_16x16x32_bf16(
            afl[mt], bfh[nt], acc[mt][nt], 0, 0, 0);
      }
    __syncthreads();
  }

#pragma unroll
  for (int nt = 0; nt < 4; ++nt) {
    const int col = col0 + wn * 64 + nt * 16 + l15;
    const float bj = bias[col];
#pragma unroll
    for (int mt = 0; mt < 4; ++mt) {
      float* Cp = C + (size_t)(row0 + wm * 64 + mt * 16 + r4) * Gg + col;
#pragma unroll
      for (int r = 0; r < 4; ++r)
        Cp[(size_t)r * Gg] = acc[mt][nt][r] + bj;
    }
  }
}

// ---------------- MFMA bf16x3 GEMM: logits = h2 @ WoutT^T + bout --------
// M=ROWS, N=PC(112), K=512. 64 blocks x 128 rows; wave w rows w*32..+31.
__global__ __launch_bounds__(256)
void gemm_proj(const u16* __restrict__ Ah, const u16* __restrict__ Al,
               const u16* __restrict__ Bh, const u16* __restrict__ Bl,
               const float* __restrict__ bout, float* __restrict__ logits) {
  __shared__ u16 Ash[128][40];
  __shared__ u16 Asl[128][40];
  __shared__ u16 Bsh[PC][40];
  __shared__ u16 Bsl[PC][40];
  const int tid  = threadIdx.x;
  const int lane = tid & 63, wave = tid >> 6;
  const int l15 = lane & 15, k8 = (lane >> 4) * 8, r4 = (lane >> 4) * 4;
  const int row0 = blockIdx.x * 128;
  const int srow = tid >> 1, sk = (tid & 1) * 16;

  const u16* pAh = Ah + (size_t)(row0 + srow) * Hh + sk;
  const u16* pAl = Al + (size_t)(row0 + srow) * Hh + sk;
  const u16* pBh = Bh + (size_t)srow * Hh + sk;
  const u16* pBl = Bl + (size_t)srow * Hh + sk;

  f32x4 acc[2][7];
#pragma unroll
  for (int i = 0; i < 2; ++i)
#pragma unroll
    for (int j = 0; j < 7; ++j) acc[i][j] = (f32x4){0.f, 0.f, 0.f, 0.f};

  for (int k0 = 0; k0 < Hh; k0 += 32) {
    *(bf16x8*)(&Ash[srow][sk])     = *(const bf16x8*)(pAh + k0);
    *(bf16x8*)(&Ash[srow][sk + 8]) = *(const bf16x8*)(pAh + k0 + 8);
    *(bf16x8*)(&Asl[srow][sk])     = *(const bf16x8*)(pAl + k0);
    *(bf16x8*)(&Asl[srow][sk + 8]) = *(const bf16x8*)(pAl + k0 + 8);
    if (srow < PC) {
      *(bf16x8*)(&Bsh[srow][sk])     = *(const bf16x8*)(pBh + k0);
      *(bf16x8*)(&Bsh[srow][sk + 8]) = *(const bf16x8*)(pBh + k0 + 8);
      *(bf16x8*)(&Bsl[srow][sk])     = *(const bf16x8*)(pBl + k0);
      *(bf16x8*)(&Bsl[srow][sk + 8]) = *(const bf16x8*)(pBl + k0 + 8);
    }
    __syncthreads();

    bf16x8 afh[2], afl[2], bfh[7], bfl[7];
#pragma unroll
    for (int mt = 0; mt < 2; ++mt) {
      afh[mt] = *(const bf16x8*)(&Ash[wave * 32 + mt * 16 + l15][k8]);
      afl[mt] = *(const bf16x8*)(&Asl[wave * 32 + mt * 16 + l15][k8]);
    }
#pragma unroll
    for (int nt = 0; nt < 7; ++nt) {
      bfh[nt] = *(const bf16x8*)(&Bsh[nt * 16 + l15][k8]);
      bfl[nt] = *(const bf16x8*)(&Bsl[nt * 16 + l15][k8]);
    }
#pragma unroll
    for (int mt = 0; mt < 2; ++mt)
#pragma unroll
      for (int nt = 0; nt < 7; ++nt) {
        acc[mt][nt] = __builtin_amdgcn_mfma_f32_16x16x32_bf16(
            afh[mt], bfh[nt], acc[mt][nt], 0, 0, 0);
        acc[mt][nt] = __builtin_amdgcn_mfma_f32_16x16x32_bf16(
            afh[mt], bfl[nt], acc[mt][nt], 0, 0, 0);
        acc[mt][nt] = __builtin_amdgcn_mfma_f32_16x16x32_bf16(
            afl[mt], bfh[nt], acc[mt][nt], 0, 0, 0);
      }
    __syncthreads();
  }

#pragma unroll
  for (int nt = 0; nt < 7; ++nt) {
    const int col = nt * 16 + l15;
    const float bj = (col < Cc) ? bout[col] : 0.f;
#pragma unroll
    for (int mt = 0; mt < 2; ++mt) {
      float* Lp = logits + (size_t)(row0 + wave * 32 + mt * 16 + r4) * PC + col;
#pragma unroll
      for (int r = 0; r < 4; ++r)
        Lp[(size_t)r * PC] = acc[mt][nt][r] + bj;
    }
  }
}

// ---------------- softmax + CE over logits rows ----------------
__global__ __launch_bounds__(256)
void softmax_ce(const float* __restrict__ logits, const int* __restrict__ labels,
                float* __restrict__ preds, float* __restrict__ ce) {
  const int lane = threadIdx.x & 63, wv = threadIdx.x >> 6;
  const int row = blockIdx.x * 4 + wv;
  const float* lg = logits + (size_t)row * PC;
  const bool a0 = (lane < Cc), a1 = (lane + 64 < Cc);
  const float v0 = a0 ? lg[lane] : -INFINITY;
  const float v1 = a1 ? lg[lane + 64] : -INFINITY;
  float m = fmaxf(v0, v1);
#pragma unroll
  for (int off = 32; off > 0; off >>= 1) m = fmaxf(m, __shfl_xor(m, off));
  const float e0 = a0 ? expf(v0 - m) : 0.f;
  const float e1 = a1 ? expf(v1 - m) : 0.f;
  float s = e0 + e1;
#pragma unroll
  for (int off = 32; off > 0; off >>= 1) s += __shfl_xor(s, off);
  if (a0) preds[(size_t)row * Cc + lane] = e0 / s;
  if (a1) preds[(size_t)row * Cc + lane + 64] = e1 / s;
  const int lab = labels[row];
  if (lab == lane)           ce[row] = logf(s) + m - v0;
  else if (lab == lane + 64) ce[row] = logf(s) + m - v1;
}

// ---------------- SGEMM (fp32 fallback if ws too small) ----------------
#define BM 128
#define BN 128
#define BK 16

__global__ __launch_bounds__(256)
void sgemm_bias(const float* __restrict__ A, const float* __restrict__ B,
                const float* __restrict__ bias, float* __restrict__ C,
                int M, int N, int K) {
  __shared__ float As[BK][BM];
  __shared__ float Bs[BK][BN];
  const int tid  = threadIdx.x;
  const int row0 = blockIdx.y * BM, col0 = blockIdx.x * BN;
  const int tr = (tid >> 4) << 3;
  const int tc = (tid & 15) << 3;

  float acc[8][8];
#pragma unroll
  for (int i = 0; i < 8; ++i)
#pragma unroll
    for (int j = 0; j < 8; ++j) acc[i][j] = 0.f;

  const int arow = tid >> 1;
  const int acol = (tid & 1) << 3;
  const int brow = tid >> 4;
  const int bcol = (tid & 15) << 3;
  const float* Ap = A + (size_t)(row0 + arow) * K + acol;
  const float* Bp = B + (size_t)brow * N + (col0 + bcol);

  for (int k0 = 0; k0 < K; k0 += BK) {
    const float4 a0 = *(const float4*)(Ap + k0);
    const float4 a1 = *(const float4*)(Ap + k0 + 4);
    const float4 bv0 = *(const float4*)(Bp + (size_t)k0 * N);
    const float4 bv1 = *(const float4*)(Bp + (size_t)k0 * N + 4);
    As[acol + 0][arow] = a0.x;
    As[acol + 1][arow] = a0.y;
    As[acol + 2][arow] = a0.z;
    As[acol + 3][arow] = a0.w;
    As[acol + 4][arow] = a1.x;
    As[acol + 5][arow] = a1.y;
    As[acol + 6][arow] = a1.z;
    As[acol + 7][arow] = a1.w;
    *(float4*)(&Bs[brow][bcol])     = bv0;
    *(float4*)(&Bs[brow][bcol + 4]) = bv1;
    __syncthreads();
#pragma unroll
    for (int k = 0; k < BK; ++k) {
      float a[8], b[8];
      *(float4*)(a)     = *(const float4*)(&As[k][tr]);
      *(float4*)(a + 4) = *(const float4*)(&As[k][tr + 4]);
      *(float4*)(b)     = *(const float4*)(&Bs[k][tc]);
      *(float4*)(b + 4) = *(const float4*)(&Bs[k][tc + 4]);
#pragma unroll
      for (int i = 0; i < 8; ++i)
#pragma unroll
        for (int j = 0; j < 8; ++j)
          acc[i][j] = fmaf(a[i], b[j], acc[i][j]);
    }
    __syncthreads();
  }

  float bj[8];
#pragma unroll
  for (int j = 0; j < 8; ++j) bj[j] = bias[col0 + tc + j];
#pragma unroll
  for (int i = 0; i < 8; ++i) {
    float* Cp = C + (size_t)(row0 + tr + i) * N + (col0 + tc);
    float4 o0, o1;
    o0.x = acc[i][0] + bj[0]; o0.y = acc[i][1] + bj[1];
    o0.z = acc[i][2] + bj[2]; o0.w = acc[i][3] + bj[3];
    o1.x = acc[i][4] + bj[4]; o1.y = acc[i][5] + bj[5];
    o1.z = acc[i][6] + bj[6]; o1.w = acc[i][7] + bj[7];
    *(float4*)(Cp)     = o0;
    *(float4*)(Cp + 4) = o1;
  }
}

// ---------------- MFMA fused step (128-k chunks; merged L2 loop) --------
// One launch per phase t: blocks 0..127 = L1 step t, 128..255 = L2 step t-1.
// Block: all 64 batches x 16 strided cols {g*512 + cg*4 + m}.
__device__ __forceinline__ void mm_half(
    const u16* __restrict__ hh_src, const u16* __restrict__ hl_src,
    const u16* __restrict__ wph, const u16* __restrict__ wpl, int Kw,
    f32x4& acc, u16 (*Ah)[64][136], u16 (*Al)[64][136],
    u16 (*Bh)[16][136], u16 (*Bl)[16][136], int tid, int lane, int w) {
  const int hr = tid >> 2, hk = (tid & 3) * 32;   // h: 4 thr/row, 32 u16 each
  const int wv = tid >> 4, wk = (tid & 15) * 8;   // W: 16 thr/row, 8 u16 each
  const int fr = lane & 15, f8 = (lane >> 4) * 8;

  bf16x8 rh[4], rl[4], rwh, rwl;
#pragma unroll
  for (int j = 0; j < 4; ++j) {
    rh[j] = *(const bf16x8*)(hh_src + hr * 512 + hk + j * 8);
    rl[j] = *(const bf16x8*)(hl_src + hr * 512 + hk + j * 8);
  }
  rwh = *(const bf16x8*)(wph + (size_t)wv * Kw + wk);
  rwl = *(const bf16x8*)(wpl + (size_t)wv * Kw + wk);
#pragma unroll
  for (int j = 0; j < 4; ++j) {
    *(bf16x8*)&Ah[0][hr][hk + j * 8] = rh[j];
    *(bf16x8*)&Al[0][hr][hk + j * 8] = rl[j];
  }
  *(bf16x8*)&Bh[0][wv][wk] = rwh;
  *(bf16x8*)&Bl[0][wv][wk] = rwl;
  __syncthreads();

  for (int kc = 0; kc < 4; ++kc) {
    const int cur = kc & 1;
    if (kc < 3) {
      const int ko = (kc + 1) * 128;
#pragma unroll
      for (int j = 0; j < 4; ++j) {
        rh[j] = *(const bf16x8*)(hh_src + hr * 512 + ko + hk + j * 8);
        rl[j] = *(const bf16x8*)(hl_src + hr * 512 + ko + hk + j * 8);
      }
      rwh = *(const bf16x8*)(wph + (size_t)wv * Kw + ko + wk);
      rwl = *(const bf16x8*)(wpl + (size_t)wv * Kw + ko + wk);
    }
#pragma unroll
    for (int s = 0; s < 4; ++s) {
      const bf16x8 afh = *(const bf16x8*)&Ah[cur][w * 16 + fr][s * 32 + f8];
      const bf16x8 afl = *(const bf16x8*)&Al[cur][w * 16 + fr][s * 32 + f8];
      const bf16x8 bfh = *(const bf16x8*)&Bh[cur][fr][s * 32 + f8];
      const bf16x8 bfl = *(const bf16x8*)&Bl[cur][fr][s * 32 + f8];
      acc = __builtin_amdgcn_mfma_f32_16x16x32_bf16(afh, bfh, acc, 0, 0, 0);
      acc = __builtin_amdgcn_mfma_f32_16x16x32_bf16(afh, bfl, acc, 0, 0, 0);
      acc = __builtin_amdgcn_mfma_f32_16x16x32_bf16(afl, bfh, acc, 0, 0, 0);
    }
    if (kc < 3) {
      const int nb = cur ^ 1;
#pragma unroll
      for (int j = 0; j < 4; ++j) {
        *(bf16x8*)&Ah[nb][hr][hk + j * 8] = rh[j];
        *(bf16x8*)&Al[nb][hr][hk + j * 8] = rl[j];
      }
      *(bf16x8*)&Bh[nb][wv][wk] = rwh;
      *(bf16x8*)&Bl[nb][wv][wk] = rwl;
    }
    __syncthreads();
  }
}

__global__ __launch_bounds__(256, 1)
void fused_step2(const float* __restrict__ pre,
                 const u16* __restrict__ WP1h, const u16* __restrict__ WP1l,
                 const u16* __restrict__ WP2h, const u16* __restrict__ WP2l,
                 const float* __restrict__ b2,
                 u16* __restrict__ h1hi, u16* __restrict__ h1lo,
                 u16* __restrict__ h2hi, u16* __restrict__ h2lo,
                 u16* __restrict__ h2fh, u16* __restrict__ h2fl,
                 float* __restrict__ c1, float* __restrict__ c2, int t) {
  __shared__ u16 Ah[2][64][136], Al[2][64][136];
  __shared__ u16 Bh[2][16][136], Bl[2][16][136];
  __shared__ float ex[4][16][17];
  const int tid = threadIdx.x;
  const int lane = tid & 63, w = tid >> 6;
  const int fr = lane & 15;
  const bool isL2 = blockIdx.x >= 128;
  const int cg = blockIdx.x & 127;

  f32x4 acc = {0.f, 0.f, 0.f, 0.f};
  bool have = false;

  if (!isL2) {
    if (t >= Tt) return;
    if (t > 0) {
      const int sl = (t - 1) & 1;
      mm_half(h1hi + (sl << 15), h1lo + (sl << 15),
              WP1h + (size_t)cg * 16 * 512, WP1l + (size_t)cg * 16 * 512, 512,
              acc, Ah, Al, Bh, Bl, tid, lane, w);
      have = true;
    }
  } else {
    if (t < 1) return;
    // merged K=1024 loop: chunks 0-3 A=h1[t-1], chunks 4-7 A=h2[t-2]
    const u16* A1h = h1hi + (((t - 1) & 1) << 15);
    const u16* A1l = h1lo + (((t - 1) & 1) << 15);
    const u16* A2h = h2hi + (((t - 2) & 1) << 15);
    const u16* A2l = h2lo + (((t - 2) & 1) << 15);
    const u16* ph = WP2h + (size_t)cg * 16 * 1024;
    const u16* pl = WP2l + (size_t)cg * 16 * 1024;
    const bool h2ok = (t >= 2);

    const int hr = tid >> 2, hk = (tid & 3) * 32;
    const int wv = tid >> 4, wk = (tid & 15) * 8;
    const int f8 = (lane >> 4) * 8;

    bf16x8 rh[4], rl[4], rwh, rwl;
#pragma unroll
    for (int j = 0; j < 4; ++j) {
      rh[j] = *(const bf16x8*)(A1h + hr * 512 + hk + j * 8);
      rl[j] = *(const bf16x8*)(A1l + hr * 512 + hk + j * 8);
    }
    rwh = *(const bf16x8*)(ph + (size_t)wv * 1024 + wk);
    rwl = *(const bf16x8*)(pl + (size_t)wv * 1024 + wk);
#pragma unroll
    for (int j = 0; j < 4; ++j) {
      *(bf16x8*)&Ah[0][hr][hk + j * 8] = rh[j];
      *(bf16x8*)&Al[0][hr][hk + j * 8] = rl[j];
    }
    *(bf16x8*)&Bh[0][wv][wk] = rwh;
    *(bf16x8*)&Bl[0][wv][wk] = rwl;
    __syncthreads();

    for (int kc = 0; kc < 8; ++kc) {
      const int cur = kc & 1;
      if (kc < 7) {
        const int nk = kc + 1;
        const u16* sh = (nk < 4) ? A1h : A2h;
        const u16* sl2 = (nk < 4) ? A1l : A2l;
        const int ko = (nk & 3) * 128;
#pragma unroll
        for (int j = 0; j < 4; ++j) {
          rh[j] = *(const bf16x8*)(sh + hr * 512 + ko + hk + j * 8);
          rl[j] = *(const bf16x8*)(sl2 + hr * 512 + ko + hk + j * 8);
        }
        rwh = *(const bf16x8*)(ph + (size_t)wv * 1024 + nk * 128 + wk);
        rwl = *(const bf16x8*)(pl + (size_t)wv * 1024 + nk * 128 + wk);
      }
      if (kc < 4 || h2ok) {
#pragma unroll
        for (int s = 0; s < 4; ++s) {
          const bf16x8 afh = *(const bf16x8*)&Ah[cur][w * 16 + fr][s * 32 + f8];
          const bf16x8 afl = *(const bf16x8*)&Al[cur][w * 16 + fr][s * 32 + f8];
          const bf16x8 bfh = *(const bf16x8*)&Bh[cur][fr][s * 32 + f8];
          const bf16x8 bfl = *(const bf16x8*)&Bl[cur][fr][s * 32 + f8];
          acc = __builtin_amdgcn_mfma_f32_16x16x32_bf16(afh, bfh, acc, 0, 0, 0);
          acc = __builtin_amdgcn_mfma_f32_16x16x32_bf16(afh, bfl, acc, 0, 0, 0);
          acc = __builtin_amdgcn_mfma_f32_16x16x32_bf16(afl, bfh, acc, 0, 0, 0);
        }
      }
      if (kc < 7) {
        const int nb = cur ^ 1;
#pragma unroll
        for (int j = 0; j < 4; ++j) {
          *(bf16x8*)&Ah[nb][hr][hk + j * 8] = rh[j];
          *(bf16x8*)&Al[nb][hr][hk + j * 8] = rl[j];
        }
        *(bf16x8*)&Bh[nb][wv][wk] = rwh;
        *(bf16x8*)&Bl[nb][wv][wk] = rwl;
      }
      __syncthreads();
    }
    have = true;
  }

  if (have) {
#pragma unroll
    for (int r = 0; r < 4; ++r)
      ex[w][(lane >> 4) * 4 + r][fr] = acc[r];
  }
  __syncthreads();

  // epilogue: thread -> (batch b, local m); col = cg*4 + m
  const int b = tid >> 2, m = tid & 3;
  float s0 = 0.f, s1 = 0.f, s2 = 0.f, s3 = 0.f;
  if (have) {
    s0 = ex[b >> 4][b & 15][0 + m];
    s1 = ex[b >> 4][b & 15][4 + m];
    s2 = ex[b >> 4][b & 15][8 + m];
    s3 = ex[b >> 4][b & 15][12 + m];
  }
  const int col = cg * 4 + m;
  const int ci = b * Hh + col;
  if (!isL2) {
    const float* pp = pre + ((size_t)b * Tt + t) * Gg + col;
    const float gi = pp[0] + s0, gj = pp[512] + s1;
    const float gf = pp[1024] + s2, go = pp[1536] + s3;
    const float cp = (t > 0) ? c1[ci] : 0.f;
    const float nc = fmaf(cp, sigm(gf + 1.f), sigm(gi) * tanhf(gj));
    c1[ci] = nc;
    const float nh = tanhf(nc) * sigm(go);
    u16 hh, hl;
    split_bf16(nh, hh, hl);
    const int hidx = ((t & 1) << 15) + ci;
    h1hi[hidx] = hh;
    h1lo[hidx] = hl;
  } else {
    const float gi = b2[col] + s0, gj = b2[512 + col] + s1;
    const float gf = b2[1024 + col] + s2, go = b2[1536 + col] + s3;
    const float cp = (t >= 2) ? c2[ci] : 0.f;
    const float nc = fmaf(cp, sigm(gf + 1.f), sigm(gi) * tanhf(gj));
    c2[ci] = nc;
    const float nh = tanhf(nc) * sigm(go);
    u16 hh, hl;
    split_bf16(nh, hh, hl);
    const int hidx = (((t - 1) & 1) << 15) + ci;
    h2hi[hidx] = hh;
    h2lo[hidx] = hl;
    const size_t fo = ((size_t)b * Tt + (t - 1)) * Hh + col;
    h2fh[fo] = hh;
    h2fl[fo] = hl;
  }
}

__global__ __launch_bounds__(256)
void reduce_cost(const float* __restrict__ ce, float* __restrict__ out) {
  __shared__ float red[256];
  const int tid = threadIdx.x;
  float s = 0.f;
  for (int i = tid; i < ROWS; i += 256) s += ce[i];
  red[tid] = s;
  __syncthreads();
  for (int st = 128; st > 0; st >>= 1) {
    if (tid < st) red[tid] += red[tid + st];
    __syncthreads();
  }
  if (tid == 0) out[0] = red[0] / (float)Bb;
}

// ---------------- launch ----------------
extern "C" void kernel_launch(void* const* d_in, const int* in_sizes, int n_in,
                              void* d_out, int out_size, void* d_ws, size_t ws_size,
                              hipStream_t stream) {
  const float* inputs = (const float*)d_in[0];
  const int*   labels = (const int*)d_in[1];
  const float* W1     = (const float*)d_in[2];
  const float* b1     = (const float*)d_in[3];
  const float* W2     = (const float*)d_in[4];
  const float* b2     = (const float*)d_in[5];
  const float* Wout   = (const float*)d_in[6];
  const float* bout   = (const float*)d_in[7];
  float* out = (float*)d_out;

  float* ws     = (float*)d_ws;
  float* pre    = ws;                              // ROWS*Gg   (16M f32)
  float* c1     = pre    + (size_t)ROWS * Gg;      // 64*512
  float* c2     = c1     + (size_t)Bb * Hh;
  float* ceb    = c2     + (size_t)Bb * Hh;        // ROWS
  float* logits = ceb    + ROWS;                   // ROWS*PC
  u16* h1hi = (u16*)(logits + (size_t)ROWS * PC);  // [2][64][512]
  u16* h1lo = h1hi + 2 * 64 * 512;
  u16* h2hi = h1lo + 2 * 64 * 512;
  u16* h2lo = h2hi + 2 * 64 * 512;
  u16* h2fh = h2lo + 2 * 64 * 512;                 // ROWS*Hh
  u16* h2fl = h2fh + (size_t)ROWS * Hh;
  u16* WP1h = h2fl + (size_t)ROWS * Hh;            // 128*16*512
  u16* WP1l = WP1h + 128 * 16 * 512;
  u16* WP2h = WP1l + 128 * 16 * 512;               // 128*16*1024
  u16* WP2l = WP2h + 128 * 16 * 1024;
  u16* WoTh = WP2l + 128 * 16 * 1024;              // PC*Hh
  u16* WoTl = WoTh + PC * Hh;
  u16* Xhi  = WoTl + PC * Hh;                      // ROWS*Dd
  u16* Xlo  = Xhi  + (size_t)ROWS * Dd;
  u16* W1Th = Xlo  + (size_t)ROWS * Dd;            // Gg*Dd
  u16* W1Tl = W1Th + (size_t)Gg * Dd;
  const size_t need = (size_t)((char*)(W1Tl + (size_t)Gg * Dd) - (char*)d_ws);
  const bool use_mfma = ws_size >= need;

  // weights: permute+split once
  permuteW<<<dim3(16, 64), dim3(32, 8), 0, stream>>>(
      W1 + (size_t)Dd * Gg, WP1h, WP1l, 512);
  permuteW<<<dim3(32, 64), dim3(32, 8), 0, stream>>>(W2, WP2h, WP2l, 1024);
  convert_woutT<<<PC, 256, 0, stream>>>(Wout, WoTh, WoTl);

  // Layer 1 input projection: pre = X @ W1[0:D,:] + b1
  if (use_mfma) {
    convert_hilo<<<2048, 256, 0, stream>>>(inputs, Xhi, Xlo, ROWS * Dd / 4);
    convertT_w1<<<dim3(64, 64), dim3(32, 8), 0, stream>>>(W1, W1Th, W1Tl);
    gemm1_mfma<<<dim3(Gg / 128, ROWS / 128), 256, 0, stream>>>(
        Xhi, Xlo, W1Th, W1Tl, b1, pre);
  } else {
    sgemm_bias<<<dim3(Gg / BN, ROWS / BM), dim3(256), 0, stream>>>(
        inputs, W1, b1, pre, ROWS, Gg, Dd);
  }

  // Recurrence: phase t = L1 step t (blocks 0..127) + L2 step t-1 (128..255)
  for (int t = 0; t <= Tt; ++t)
    fused_step2<<<256, 256, 0, stream>>>(pre, WP1h, WP1l, WP2h, WP2l, b2,
                                         h1hi, h1lo, h2hi, h2lo,
                                         h2fh, h2fl, c1, c2, t);

  // Output projection (MFMA) + softmax/CE + cost
  gemm_proj<<<ROWS / 128, 256, 0, stream>>>(h2fh, h2fl, WoTh, WoTl, bout, logits);
  softmax_ce<<<ROWS / 4, 256, 0, stream>>>(logits, labels, out, ceb);
  reduce_cost<<<1, 256, 0, stream>>>(ceb, out + (size_t)ROWS * Cc);
}

// Round 15
// 1528.519 us; speedup vs baseline: 4.5291x; 1.1663x over previous
//
#include <hip/hip_runtime.h>
#include <cmath>

// Problem constants
#define Bb   64
#define Tt   128
#define Dd   2048
#define Hh   512
#define Gg   2048      // 4*H
#define Cc   101
#define PC   112       // classes padded to 7*16 for MFMA
#define ROWS 8192      // B*T

typedef unsigned short u16;
typedef __attribute__((ext_vector_type(8))) short bf16x8;
typedef __attribute__((ext_vector_type(4))) float f32x4;

// ---------------- bf16 hi/lo split helpers ----------------
__device__ __forceinline__ u16 bf16rne(float x) {
  unsigned u = __float_as_uint(x);
  unsigned r = (u + 0x7fffu + ((u >> 16) & 1u)) >> 16;
  return (u16)r;
}
__device__ __forceinline__ void split_bf16(float x, u16& h, u16& l) {
  h = bf16rne(x);
  l = bf16rne(x - __uint_as_float(((unsigned)h) << 16));
}
__device__ __forceinline__ float sigm(float x) { return 1.f / (1.f + expf(-x)); }

// X [ROWS x Dd] fp32 -> Xhi, Xlo bf16 (same layout)
__global__ __launch_bounds__(256)
void convert_hilo(const float* __restrict__ src, u16* __restrict__ hi,
                  u16* __restrict__ lo, int n4) {
  for (int i = blockIdx.x * 256 + threadIdx.x; i < n4; i += gridDim.x * 256) {
    const float4 v = ((const float4*)src)[i];
    ushort4 h, l;
    split_bf16(v.x, h.x, l.x);
    split_bf16(v.y, h.y, l.y);
    split_bf16(v.z, h.z, l.z);
    split_bf16(v.w, h.w, l.w);
    ((ushort4*)hi)[i] = h;
    ((ushort4*)lo)[i] = l;
  }
}

// W1 top [Dd x Gg] -> W1T hi/lo [Gg x Dd] bf16  (for gemm1 B operand)
__global__ __launch_bounds__(256)
void convertT_w1(const float* __restrict__ W1, u16* __restrict__ Th,
                 u16* __restrict__ Tl) {
  __shared__ float tl[32][33];
  const int tx = threadIdx.x, ty = threadIdx.y;   // 32, 8
  const int k0 = blockIdx.x * 32, c0 = blockIdx.y * 32;
#pragma unroll
  for (int j = 0; j < 4; ++j)
    tl[ty + j * 8][tx] = W1[(size_t)(k0 + ty + j * 8) * Gg + (c0 + tx)];
  __syncthreads();
#pragma unroll
  for (int j = 0; j < 4; ++j) {
    const float v = tl[tx][ty + j * 8];
    u16 h, l;
    split_bf16(v, h, l);
    const size_t o = (size_t)(c0 + ty + j * 8) * Dd + (k0 + tx);
    Th[o] = h;
    Tl[o] = l;
  }
}

// Wout [Hh x Cc] -> WoutT hi/lo [PC x Hh] (rows >= Cc zero)
__global__ __launch_bounds__(256)
void convert_woutT(const float* __restrict__ Wout, u16* __restrict__ Th,
                   u16* __restrict__ Tl) {
  const int c = blockIdx.x;
  for (int k = threadIdx.x; k < Hh; k += 256) {
    const float v = (c < Cc) ? Wout[k * Cc + c] : 0.f;
    u16 h, l;
    split_bf16(v, h, l);
    Th[c * Hh + k] = h;
    Tl[c * Hh + k] = l;
  }
}

// Recurrent weights, permuted + split:
// WP[cg 128][vc 16][K], vc = g*4 + m for col = g*512 + cg*4 + m.
__global__ __launch_bounds__(256)
void permuteW(const float* __restrict__ src, u16* __restrict__ dh,
              u16* __restrict__ dl, int K) {
  __shared__ float tl[32][33];
  const int tx = threadIdx.x, ty = threadIdx.y;   // 32, 8
  const int k0 = blockIdx.x * 32, c0 = blockIdx.y * 32;
#pragma unroll
  for (int j = 0; j < 4; ++j)
    tl[ty + j * 8][tx] = src[(size_t)(k0 + ty + j * 8) * Gg + (c0 + tx)];
  __syncthreads();
#pragma unroll
  for (int j = 0; j < 4; ++j) {
    const int col = c0 + ty + j * 8;
    const int g = col >> 9, mg = col & 511;
    const int cg = mg >> 2, m = mg & 3;
    const float v = tl[tx][ty + j * 8];
    u16 h, l;
    split_bf16(v, h, l);
    const size_t o = (size_t)(cg * 16 + g * 4 + m) * K + k0 + tx;
    dh[o] = h;
    dl[o] = l;
  }
}

// ---------------- MFMA bf16x3 GEMM: pre = X @ W1 + b1 ----------------
__global__ __launch_bounds__(256)
void gemm1_mfma(const u16* __restrict__ Ah, const u16* __restrict__ Al,
                const u16* __restrict__ Bh, const u16* __restrict__ Bl,
                const float* __restrict__ bias, float* __restrict__ C) {
  __shared__ u16 Ash[128][40];
  __shared__ u16 Asl[128][40];
  __shared__ u16 Bsh[128][40];
  __shared__ u16 Bsl[128][40];
  const int tid  = threadIdx.x;
  const int lane = tid & 63, wave = tid >> 6;
  const int wm = wave >> 1, wn = wave & 1;
  const int l15 = lane & 15, k8 = (lane >> 4) * 8, r4 = (lane >> 4) * 4;
  const int row0 = blockIdx.y * 128, col0 = blockIdx.x * 128;
  const int srow = tid >> 1, sk = (tid & 1) * 16;

  const u16* pAh = Ah + (size_t)(row0 + srow) * Dd + sk;
  const u16* pAl = Al + (size_t)(row0 + srow) * Dd + sk;
  const u16* pBh = Bh + (size_t)(col0 + srow) * Dd + sk;
  const u16* pBl = Bl + (size_t)(col0 + srow) * Dd + sk;

  f32x4 acc[4][4];
#pragma unroll
  for (int i = 0; i < 4; ++i)
#pragma unroll
    for (int j = 0; j < 4; ++j) acc[i][j] = (f32x4){0.f, 0.f, 0.f, 0.f};

  for (int k0 = 0; k0 < Dd; k0 += 32) {
    *(bf16x8*)(&Ash[srow][sk])     = *(const bf16x8*)(pAh + k0);
    *(bf16x8*)(&Ash[srow][sk + 8]) = *(const bf16x8*)(pAh + k0 + 8);
    *(bf16x8*)(&Asl[srow][sk])     = *(const bf16x8*)(pAl + k0);
    *(bf16x8*)(&Asl[srow][sk + 8]) = *(const bf16x8*)(pAl + k0 + 8);
    *(bf16x8*)(&Bsh[srow][sk])     = *(const bf16x8*)(pBh + k0);
    *(bf16x8*)(&Bsh[srow][sk + 8]) = *(const bf16x8*)(pBh + k0 + 8);
    *(bf16x8*)(&Bsl[srow][sk])     = *(const bf16x8*)(pBl + k0);
    *(bf16x8*)(&Bsl[srow][sk + 8]) = *(const bf16x8*)(pBl + k0 + 8);
    __syncthreads();

    bf16x8 afh[4], afl[4], bfh[4], bfl[4];
#pragma unroll
    for (int mt = 0; mt < 4; ++mt) {
      afh[mt] = *(const bf16x8*)(&Ash[wm * 64 + mt * 16 + l15][k8]);
      afl[mt] = *(const bf16x8*)(&Asl[wm * 64 + mt * 16 + l15][k8]);
    }
#pragma unroll
    for (int nt = 0; nt < 4; ++nt) {
      bfh[nt] = *(const bf16x8*)(&Bsh[wn * 64 + nt * 16 + l15][k8]);
      bfl[nt] = *(const bf16x8*)(&Bsl[wn * 64 + nt * 16 + l15][k8]);
    }
#pragma unroll
    for (int mt = 0; mt < 4; ++mt)
#pragma unroll
      for (int nt = 0; nt < 4; ++nt) {
        acc[mt][nt] = __builtin_amdgcn_mfma_f32_16x16x32_bf16(
            afh[mt], bfh[nt], acc[mt][nt], 0, 0, 0);
        acc[mt][nt] = __builtin_amdgcn_mfma_f32_16x16x32_bf16(
            afh[mt], bfl[nt], acc[mt][nt], 0, 0, 0);
        acc[mt][nt] = __builtin_amdgcn_mfma_f32_16x16x32_bf16(
            afl[mt], bfh[nt], acc[mt][nt], 0, 0, 0);
      }
    __syncthreads();
  }

#pragma unroll
  for (int nt = 0; nt < 4; ++nt) {
    const int col = col0 + wn * 64 + nt * 16 + l15;
    const float bj = bias[col];
#pragma unroll
    for (int mt = 0; mt < 4; ++mt) {
      float* Cp = C + (size_t)(row0 + wm * 64 + mt * 16 + r4) * Gg + col;
#pragma unroll
      for (int r = 0; r < 4; ++r)
        Cp[(size_t)r * Gg] = acc[mt][nt][r] + bj;
    }
  }
}

// ---------------- MFMA bf16x3 GEMM: logits = h2 @ WoutT^T + bout --------
__global__ __launch_bounds__(256)
void gemm_proj(const u16* __restrict__ Ah, const u16* __restrict__ Al,
               const u16* __restrict__ Bh, const u16* __restrict__ Bl,
               const float* __restrict__ bout, float* __restrict__ logits) {
  __shared__ u16 Ash[128][40];
  __shared__ u16 Asl[128][40];
  __shared__ u16 Bsh[PC][40];
  __shared__ u16 Bsl[PC][40];
  const int tid  = threadIdx.x;
  const int lane = tid & 63, wave = tid >> 6;
  const int l15 = lane & 15, k8 = (lane >> 4) * 8, r4 = (lane >> 4) * 4;
  const int row0 = blockIdx.x * 128;
  const int srow = tid >> 1, sk = (tid & 1) * 16;

  const u16* pAh = Ah + (size_t)(row0 + srow) * Hh + sk;
  const u16* pAl = Al + (size_t)(row0 + srow) * Hh + sk;
  const u16* pBh = Bh + (size_t)srow * Hh + sk;
  const u16* pBl = Bl + (size_t)srow * Hh + sk;

  f32x4 acc[2][7];
#pragma unroll
  for (int i = 0; i < 2; ++i)
#pragma unroll
    for (int j = 0; j < 7; ++j) acc[i][j] = (f32x4){0.f, 0.f, 0.f, 0.f};

  for (int k0 = 0; k0 < Hh; k0 += 32) {
    *(bf16x8*)(&Ash[srow][sk])     = *(const bf16x8*)(pAh + k0);
    *(bf16x8*)(&Ash[srow][sk + 8]) = *(const bf16x8*)(pAh + k0 + 8);
    *(bf16x8*)(&Asl[srow][sk])     = *(const bf16x8*)(pAl + k0);
    *(bf16x8*)(&Asl[srow][sk + 8]) = *(const bf16x8*)(pAl + k0 + 8);
    if (srow < PC) {
      *(bf16x8*)(&Bsh[srow][sk])     = *(const bf16x8*)(pBh + k0);
      *(bf16x8*)(&Bsh[srow][sk + 8]) = *(const bf16x8*)(pBh + k0 + 8);
      *(bf16x8*)(&Bsl[srow][sk])     = *(const bf16x8*)(pBl + k0);
      *(bf16x8*)(&Bsl[srow][sk + 8]) = *(const bf16x8*)(pBl + k0 + 8);
    }
    __syncthreads();

    bf16x8 afh[2], afl[2], bfh[7], bfl[7];
#pragma unroll
    for (int mt = 0; mt < 2; ++mt) {
      afh[mt] = *(const bf16x8*)(&Ash[wave * 32 + mt * 16 + l15][k8]);
      afl[mt] = *(const bf16x8*)(&Asl[wave * 32 + mt * 16 + l15][k8]);
    }
#pragma unroll
    for (int nt = 0; nt < 7; ++nt) {
      bfh[nt] = *(const bf16x8*)(&Bsh[nt * 16 + l15][k8]);
      bfl[nt] = *(const bf16x8*)(&Bsl[nt * 16 + l15][k8]);
    }
#pragma unroll
    for (int mt = 0; mt < 2; ++mt)
#pragma unroll
      for (int nt = 0; nt < 7; ++nt) {
        acc[mt][nt] = __builtin_amdgcn_mfma_f32_16x16x32_bf16(
            afh[mt], bfh[nt], acc[mt][nt], 0, 0, 0);
        acc[mt][nt] = __builtin_amdgcn_mfma_f32_16x16x32_bf16(
            afh[mt], bfl[nt], acc[mt][nt], 0, 0, 0);
        acc[mt][nt] = __builtin_amdgcn_mfma_f32_16x16x32_bf16(
            afl[mt], bfh[nt], acc[mt][nt], 0, 0, 0);
      }
    __syncthreads();
  }

#pragma unroll
  for (int nt = 0; nt < 7; ++nt) {
    const int col = nt * 16 + l15;
    const float bj = (col < Cc) ? bout[col] : 0.f;
#pragma unroll
    for (int mt = 0; mt < 2; ++mt) {
      float* Lp = logits + (size_t)(row0 + wave * 32 + mt * 16 + r4) * PC + col;
#pragma unroll
      for (int r = 0; r < 4; ++r)
        Lp[(size_t)r * PC] = acc[mt][nt][r] + bj;
    }
  }
}

// ---------------- softmax + CE over logits rows ----------------
__global__ __launch_bounds__(256)
void softmax_ce(const float* __restrict__ logits, const int* __restrict__ labels,
                float* __restrict__ preds, float* __restrict__ ce) {
  const int lane = threadIdx.x & 63, wv = threadIdx.x >> 6;
  const int row = blockIdx.x * 4 + wv;
  const float* lg = logits + (size_t)row * PC;
  const bool a0 = (lane < Cc), a1 = (lane + 64 < Cc);
  const float v0 = a0 ? lg[lane] : -INFINITY;
  const float v1 = a1 ? lg[lane + 64] : -INFINITY;
  float m = fmaxf(v0, v1);
#pragma unroll
  for (int off = 32; off > 0; off >>= 1) m = fmaxf(m, __shfl_xor(m, off));
  const float e0 = a0 ? expf(v0 - m) : 0.f;
  const float e1 = a1 ? expf(v1 - m) : 0.f;
  float s = e0 + e1;
#pragma unroll
  for (int off = 32; off > 0; off >>= 1) s += __shfl_xor(s, off);
  if (a0) preds[(size_t)row * Cc + lane] = e0 / s;
  if (a1) preds[(size_t)row * Cc + lane + 64] = e1 / s;
  const int lab = labels[row];
  if (lab == lane)           ce[row] = logf(s) + m - v0;
  else if (lab == lane + 64) ce[row] = logf(s) + m - v1;
}

// ---------------- SGEMM (fp32 fallback if ws too small) ----------------
#define BM 128
#define BN 128
#define BK 16

__global__ __launch_bounds__(256)
void sgemm_bias(const float* __restrict__ A, const float* __restrict__ B,
                const float* __restrict__ bias, float* __restrict__ C,
                int M, int N, int K) {
  __shared__ float As[BK][BM];
  __shared__ float Bs[BK][BN];
  const int tid  = threadIdx.x;
  const int row0 = blockIdx.y * BM, col0 = blockIdx.x * BN;
  const int tr = (tid >> 4) << 3;
  const int tc = (tid & 15) << 3;

  float acc[8][8];
#pragma unroll
  for (int i = 0; i < 8; ++i)
#pragma unroll
    for (int j = 0; j < 8; ++j) acc[i][j] = 0.f;

  const int arow = tid >> 1;
  const int acol = (tid & 1) << 3;
  const int brow = tid >> 4;
  const int bcol = (tid & 15) << 3;
  const float* Ap = A + (size_t)(row0 + arow) * K + acol;
  const float* Bp = B + (size_t)brow * N + (col0 + bcol);

  for (int k0 = 0; k0 < K; k0 += BK) {
    const float4 a0 = *(const float4*)(Ap + k0);
    const float4 a1 = *(const float4*)(Ap + k0 + 4);
    const float4 bv0 = *(const float4*)(Bp + (size_t)k0 * N);
    const float4 bv1 = *(const float4*)(Bp + (size_t)k0 * N + 4);
    As[acol + 0][arow] = a0.x;
    As[acol + 1][arow] = a0.y;
    As[acol + 2][arow] = a0.z;
    As[acol + 3][arow] = a0.w;
    As[acol + 4][arow] = a1.x;
    As[acol + 5][arow] = a1.y;
    As[acol + 6][arow] = a1.z;
    As[acol + 7][arow] = a1.w;
    *(float4*)(&Bs[brow][bcol])     = bv0;
    *(float4*)(&Bs[brow][bcol + 4]) = bv1;
    __syncthreads();
#pragma unroll
    for (int k = 0; k < BK; ++k) {
      float a[8], b[8];
      *(float4*)(a)     = *(const float4*)(&As[k][tr]);
      *(float4*)(a + 4) = *(const float4*)(&As[k][tr + 4]);
      *(float4*)(b)     = *(const float4*)(&Bs[k][tc]);
      *(float4*)(b + 4) = *(const float4*)(&Bs[k][tc + 4]);
#pragma unroll
      for (int i = 0; i < 8; ++i)
#pragma unroll
        for (int j = 0; j < 8; ++j)
          acc[i][j] = fmaf(a[i], b[j], acc[i][j]);
    }
    __syncthreads();
  }

  float bj[8];
#pragma unroll
  for (int j = 0; j < 8; ++j) bj[j] = bias[col0 + tc + j];
#pragma unroll
  for (int i = 0; i < 8; ++i) {
    float* Cp = C + (size_t)(row0 + tr + i) * N + (col0 + tc);
    float4 o0, o1;
    o0.x = acc[i][0] + bj[0]; o0.y = acc[i][1] + bj[1];
    o0.z = acc[i][2] + bj[2]; o0.w = acc[i][3] + bj[3];
    o1.x = acc[i][4] + bj[4]; o1.y = acc[i][5] + bj[5];
    o1.z = acc[i][6] + bj[6]; o1.w = acc[i][7] + bj[7];
    *(float4*)(Cp)     = o0;
    *(float4*)(Cp + 4) = o1;
  }
}

// ---------------- MFMA fused step v5: 2 blocks/CU for cross-block overlap
// Grid 512: blocks 0..255 = L1 step t, 256..511 = L2 step t-1.
// Block (bg,cg): 32 batches (bg*32..) x 16 vc cols {g*512 + cg*4 + m}.
// 4 waves = (K-half kh) x (batch-tile bt); partials summed via ex.
__global__ __launch_bounds__(256, 2)
void fused_step3(const float* __restrict__ pre,
                 const u16* __restrict__ WP1h, const u16* __restrict__ WP1l,
                 const u16* __restrict__ WP2h, const u16* __restrict__ WP2l,
                 const float* __restrict__ b2,
                 u16* __restrict__ h1hi, u16* __restrict__ h1lo,
                 u16* __restrict__ h2hi, u16* __restrict__ h2lo,
                 u16* __restrict__ h2fh, u16* __restrict__ h2fl,
                 float* __restrict__ c1, float* __restrict__ c2, int t) {
  __shared__ u16 Ah[2][32][136], Al[2][32][136];
  __shared__ u16 Bh[2][16][136], Bl[2][16][136];
  __shared__ float ex[2][2][16][17];   // [kh][bt][batch16][vc]
  const int tid = threadIdx.x;
  const int lane = tid & 63, w = tid >> 6;
  const int bt = w & 1, kh = w >> 1;
  const int fr = lane & 15, f8 = (lane >> 4) * 8, r4 = (lane >> 4) * 4;
  const bool isL2 = blockIdx.x >= 256;
  const int idx = blockIdx.x & 255;
  const int cg = idx & 127, bg = idx >> 7;
  const int b0 = bg * 32;

  // staging indices: A 32x128 chunk (16 u16/thread), B 16x128 (8 u16/thread)
  const int hr = tid >> 3, hk = (tid & 7) * 16;
  const int wv = tid >> 4, wk = (tid & 15) * 8;

  f32x4 acc = {0.f, 0.f, 0.f, 0.f};
  bool have = false;
  float p0 = 0.f, p1 = 0.f, p2 = 0.f, p3 = 0.f;

  // epilogue mapping: threads 0..127 -> (batch-local b, m)
  const int eb = tid >> 2, em = tid & 3;
  const int col = cg * 4 + em;
  const int ci = (b0 + eb) * Hh + col;

  if (!isL2) {
    if (t >= Tt) return;
    if (tid < 128) {  // prefetch pre-gate inputs
      const float* pp = pre + ((size_t)(b0 + eb) * Tt + t) * Gg + col;
      p0 = pp[0]; p1 = pp[512]; p2 = pp[1024]; p3 = pp[1536];
    }
    if (t > 0) {
      const int sl = (t - 1) & 1;
      const u16* A_h = h1hi + (sl << 15) + (b0 + hr) * 512 + hk;
      const u16* A_l = h1lo + (sl << 15) + (b0 + hr) * 512 + hk;
      const u16* B_h = WP1h + (size_t)(cg * 16 + wv) * 512 + wk;
      const u16* B_l = WP1l + (size_t)(cg * 16 + wv) * 512 + wk;

      bf16x8 ra0, ra1, rl0, rl1, rwh, rwl;
      ra0 = *(const bf16x8*)(A_h);     ra1 = *(const bf16x8*)(A_h + 8);
      rl0 = *(const bf16x8*)(A_l);     rl1 = *(const bf16x8*)(A_l + 8);
      rwh = *(const bf16x8*)(B_h);     rwl = *(const bf16x8*)(B_l);
      *(bf16x8*)&Ah[0][hr][hk] = ra0;  *(bf16x8*)&Ah[0][hr][hk + 8] = ra1;
      *(bf16x8*)&Al[0][hr][hk] = rl0;  *(bf16x8*)&Al[0][hr][hk + 8] = rl1;
      *(bf16x8*)&Bh[0][wv][wk] = rwh;  *(bf16x8*)&Bl[0][wv][wk] = rwl;
      __syncthreads();

      for (int kc = 0; kc < 4; ++kc) {
        const int cur = kc & 1;
        if (kc < 3) {
          const int ko = (kc + 1) * 128;
          ra0 = *(const bf16x8*)(A_h + ko);     ra1 = *(const bf16x8*)(A_h + ko + 8);
          rl0 = *(const bf16x8*)(A_l + ko);     rl1 = *(const bf16x8*)(A_l + ko + 8);
          rwh = *(const bf16x8*)(B_h + ko);     rwl = *(const bf16x8*)(B_l + ko);
        }
#pragma unroll
        for (int s = 0; s < 2; ++s) {
          const int c0 = kh * 64 + s * 32 + f8;
          const bf16x8 afh = *(const bf16x8*)&Ah[cur][bt * 16 + fr][c0];
          const bf16x8 afl = *(const bf16x8*)&Al[cur][bt * 16 + fr][c0];
          const bf16x8 bfh = *(const bf16x8*)&Bh[cur][fr][c0];
          const bf16x8 bfl = *(const bf16x8*)&Bl[cur][fr][c0];
          acc = __builtin_amdgcn_mfma_f32_16x16x32_bf16(afh, bfh, acc, 0, 0, 0);
          acc = __builtin_amdgcn_mfma_f32_16x16x32_bf16(afh, bfl, acc, 0, 0, 0);
          acc = __builtin_amdgcn_mfma_f32_16x16x32_bf16(afl, bfh, acc, 0, 0, 0);
        }
        if (kc < 3) {
          const int nb = cur ^ 1;
          *(bf16x8*)&Ah[nb][hr][hk] = ra0;  *(bf16x8*)&Ah[nb][hr][hk + 8] = ra1;
          *(bf16x8*)&Al[nb][hr][hk] = rl0;  *(bf16x8*)&Al[nb][hr][hk + 8] = rl1;
          *(bf16x8*)&Bh[nb][wv][wk] = rwh;  *(bf16x8*)&Bl[nb][wv][wk] = rwl;
        }
        __syncthreads();
      }
      have = true;
    }
  } else {
    if (t < 1) return;
    // merged K=1024: chunks 0-3 A=h1[t-1], 4-7 A=h2[t-2] (skip MFMA if t<2)
    const u16* A1h = h1hi + (((t - 1) & 1) << 15) + (b0 + hr) * 512 + hk;
    const u16* A1l = h1lo + (((t - 1) & 1) << 15) + (b0 + hr) * 512 + hk;
    const u16* A2h = h2hi + (((t - 2) & 1) << 15) + (b0 + hr) * 512 + hk;
    const u16* A2l = h2lo + (((t - 2) & 1) << 15) + (b0 + hr) * 512 + hk;
    const u16* B_h = WP2h + (size_t)(cg * 16 + wv) * 1024 + wk;
    const u16* B_l = WP2l + (size_t)(cg * 16 + wv) * 1024 + wk;
    const bool h2ok = (t >= 2);

    bf16x8 ra0, ra1, rl0, rl1, rwh, rwl;
    ra0 = *(const bf16x8*)(A1h);     ra1 = *(const bf16x8*)(A1h + 8);
    rl0 = *(const bf16x8*)(A1l);     rl1 = *(const bf16x8*)(A1l + 8);
    rwh = *(const bf16x8*)(B_h);     rwl = *(const bf16x8*)(B_l);
    *(bf16x8*)&Ah[0][hr][hk] = ra0;  *(bf16x8*)&Ah[0][hr][hk + 8] = ra1;
    *(bf16x8*)&Al[0][hr][hk] = rl0;  *(bf16x8*)&Al[0][hr][hk + 8] = rl1;
    *(bf16x8*)&Bh[0][wv][wk] = rwh;  *(bf16x8*)&Bl[0][wv][wk] = rwl;
    __syncthreads();

    for (int kc = 0; kc < 8; ++kc) {
      const int cur = kc & 1;
      if (kc < 7) {
        const int nk = kc + 1;
        const u16* sh  = (nk < 4) ? A1h : A2h;
        const u16* sl2 = (nk < 4) ? A1l : A2l;
        const int ko = (nk & 3) * 128;
        ra0 = *(const bf16x8*)(sh + ko);      ra1 = *(const bf16x8*)(sh + ko + 8);
        rl0 = *(const bf16x8*)(sl2 + ko);     rl1 = *(const bf16x8*)(sl2 + ko + 8);
        rwh = *(const bf16x8*)(B_h + nk * 128);
        rwl = *(const bf16x8*)(B_l + nk * 128);
      }
      if (kc < 4 || h2ok) {
#pragma unroll
        for (int s = 0; s < 2; ++s) {
          const int c0 = kh * 64 + s * 32 + f8;
          const bf16x8 afh = *(const bf16x8*)&Ah[cur][bt * 16 + fr][c0];
          const bf16x8 afl = *(const bf16x8*)&Al[cur][bt * 16 + fr][c0];
          const bf16x8 bfh = *(const bf16x8*)&Bh[cur][fr][c0];
          const bf16x8 bfl = *(const bf16x8*)&Bl[cur][fr][c0];
          acc = __builtin_amdgcn_mfma_f32_16x16x32_bf16(afh, bfh, acc, 0, 0, 0);
          acc = __builtin_amdgcn_mfma_f32_16x16x32_bf16(afh, bfl, acc, 0, 0, 0);
          acc = __builtin_amdgcn_mfma_f32_16x16x32_bf16(afl, bfh, acc, 0, 0, 0);
        }
      }
      if (kc < 7) {
        const int nb = cur ^ 1;
        *(bf16x8*)&Ah[nb][hr][hk] = ra0;  *(bf16x8*)&Ah[nb][hr][hk + 8] = ra1;
        *(bf16x8*)&Al[nb][hr][hk] = rl0;  *(bf16x8*)&Al[nb][hr][hk + 8] = rl1;
        *(bf16x8*)&Bh[nb][wv][wk] = rwh;  *(bf16x8*)&Bl[nb][wv][wk] = rwl;
      }
      __syncthreads();
    }
    have = true;
  }

  if (have) {
#pragma unroll
    for (int r = 0; r < 4; ++r)
      ex[kh][bt][r4 + r][fr] = acc[r];
  }
  __syncthreads();

  if (tid < 128) {
    const int bte = eb >> 4, bl = eb & 15;
    float s0 = 0.f, s1 = 0.f, s2 = 0.f, s3 = 0.f;
    if (have) {
      s0 = ex[0][bte][bl][0 + em] + ex[1][bte][bl][0 + em];
      s1 = ex[0][bte][bl][4 + em] + ex[1][bte][bl][4 + em];
      s2 = ex[0][bte][bl][8 + em] + ex[1][bte][bl][8 + em];
      s3 = ex[0][bte][bl][12 + em] + ex[1][bte][bl][12 + em];
    }
    if (!isL2) {
      const float gi = p0 + s0, gj = p1 + s1, gf = p2 + s2, go = p3 + s3;
      const float cp = (t > 0) ? c1[ci] : 0.f;
      const float nc = fmaf(cp, sigm(gf + 1.f), sigm(gi) * tanhf(gj));
      c1[ci] = nc;
      const float nh = tanhf(nc) * sigm(go);
      u16 hh, hl;
      split_bf16(nh, hh, hl);
      const int hidx = ((t & 1) << 15) + ci;
      h1hi[hidx] = hh;
      h1lo[hidx] = hl;
    } else {
      const float gi = b2[col] + s0, gj = b2[512 + col] + s1;
      const float gf = b2[1024 + col] + s2, go = b2[1536 + col] + s3;
      const float cp = (t >= 2) ? c2[ci] : 0.f;
      const float nc = fmaf(cp, sigm(gf + 1.f), sigm(gi) * tanhf(gj));
      c2[ci] = nc;
      const float nh = tanhf(nc) * sigm(go);
      u16 hh, hl;
      split_bf16(nh, hh, hl);
      const int hidx = (((t - 1) & 1) << 15) + ci;
      h2hi[hidx] = hh;
      h2lo[hidx] = hl;
      const size_t fo = ((size_t)(b0 + eb) * Tt + (t - 1)) * Hh + col;
      h2fh[fo] = hh;
      h2fl[fo] = hl;
    }
  }
}

__global__ __launch_bounds__(256)
void reduce_cost(const float* __restrict__ ce, float* __restrict__ out) {
  __shared__ float red[256];
  const int tid = threadIdx.x;
  float s = 0.f;
  for (int i = tid; i < ROWS; i += 256) s += ce[i];
  red[tid] = s;
  __syncthreads();
  for (int st = 128; st > 0; st >>= 1) {
    if (tid < st) red[tid] += red[tid + st];
    __syncthreads();
  }
  if (tid == 0) out[0] = red[0] / (float)Bb;
}

// ---------------- launch ----------------
extern "C" void kernel_launch(void* const* d_in, const int* in_sizes, int n_in,
                              void* d_out, int out_size, void* d_ws, size_t ws_size,
                              hipStream_t stream) {
  const float* inputs = (const float*)d_in[0];
  const int*   labels = (const int*)d_in[1];
  const float* W1     = (const float*)d_in[2];
  const float* b1     = (const float*)d_in[3];
  const float* W2     = (const float*)d_in[4];
  const float* b2     = (const float*)d_in[5];
  const float* Wout   = (const float*)d_in[6];
  const float* bout   = (const float*)d_in[7];
  float* out = (float*)d_out;

  float* ws     = (float*)d_ws;
  float* pre    = ws;                              // ROWS*Gg   (16M f32)
  float* c1     = pre    + (size_t)ROWS * Gg;      // 64*512
  float* c2     = c1     + (size_t)Bb * Hh;
  float* ceb    = c2     + (size_t)Bb * Hh;        // ROWS
  float* logits = ceb    + ROWS;                   // ROWS*PC
  u16* h1hi = (u16*)(logits + (size_t)ROWS * PC);  // [2][64][512]
  u16* h1lo = h1hi + 2 * 64 * 512;
  u16* h2hi = h1lo + 2 * 64 * 512;
  u16* h2lo = h2hi + 2 * 64 * 512;
  u16* h2fh = h2lo + 2 * 64 * 512;                 // ROWS*Hh
  u16* h2fl = h2fh + (size_t)ROWS * Hh;
  u16* WP1h = h2fl + (size_t)ROWS * Hh;            // 128*16*512
  u16* WP1l = WP1h + 128 * 16 * 512;
  u16* WP2h = WP1l + 128 * 16 * 512;               // 128*16*1024
  u16* WP2l = WP2h + 128 * 16 * 1024;
  u16* WoTh = WP2l + 128 * 16 * 1024;              // PC*Hh
  u16* WoTl = WoTh + PC * Hh;
  u16* Xhi  = WoTl + PC * Hh;                      // ROWS*Dd
  u16* Xlo  = Xhi  + (size_t)ROWS * Dd;
  u16* W1Th = Xlo  + (size_t)ROWS * Dd;            // Gg*Dd
  u16* W1Tl = W1Th + (size_t)Gg * Dd;
  const size_t need = (size_t)((char*)(W1Tl + (size_t)Gg * Dd) - (char*)d_ws);
  const bool use_mfma = ws_size >= need;

  // weights: permute+split once
  permuteW<<<dim3(16, 64), dim3(32, 8), 0, stream>>>(
      W1 + (size_t)Dd * Gg, WP1h, WP1l, 512);
  permuteW<<<dim3(32, 64), dim3(32, 8), 0, stream>>>(W2, WP2h, WP2l, 1024);
  convert_woutT<<<PC, 256, 0, stream>>>(Wout, WoTh, WoTl);

  // Layer 1 input projection: pre = X @ W1[0:D,:] + b1
  if (use_mfma) {
    convert_hilo<<<2048, 256, 0, stream>>>(inputs, Xhi, Xlo, ROWS * Dd / 4);
    convertT_w1<<<dim3(64, 64), dim3(32, 8), 0, stream>>>(W1, W1Th, W1Tl);
    gemm1_mfma<<<dim3(Gg / 128, ROWS / 128), 256, 0, stream>>>(
        Xhi, Xlo, W1Th, W1Tl, b1, pre);
  } else {
    sgemm_bias<<<dim3(Gg / BN, ROWS / BM), dim3(256), 0, stream>>>(
        inputs, W1, b1, pre, ROWS, Gg, Dd);
  }

  // Recurrence: phase t = L1 step t (blocks 0..255) + L2 step t-1 (256..511)
  for (int t = 0; t <= Tt; ++t)
    fused_step3<<<512, 256, 0, stream>>>(pre, WP1h, WP1l, WP2h, WP2l, b2,
                                         h1hi, h1lo, h2hi, h2lo,
                                         h2fh, h2fl, c1, c2, t);

  // Output projection (MFMA) + softmax/CE + cost
  gemm_proj<<<ROWS / 128, 256, 0, stream>>>(h2fh, h2fl, WoTh, WoTl, bout, logits);
  softmax_ce<<<ROWS / 4, 256, 0, stream>>>(logits, labels, out, ceb);
  reduce_cost<<<1, 256, 0, stream>>>(ceb, out + (size_t)ROWS * Cc);
}

// Round 16
// 1520.351 us; speedup vs baseline: 4.5535x; 1.0054x over previous
//
#include <hip/hip_runtime.h>
#include <cmath>

// Problem constants
#define Bb   64
#define Tt   128
#define Dd   2048
#define Hh   512
#define Gg   2048      // 4*H
#define Cc   101
#define PC   112       // classes padded to 7*16 for MFMA
#define ROWS 8192      // B*T

typedef unsigned short u16;
typedef __attribute__((ext_vector_type(8))) short bf16x8;
typedef __attribute__((ext_vector_type(4))) float f32x4;

// ---------------- bf16 hi/lo split helpers ----------------
__device__ __forceinline__ u16 bf16rne(float x) {
  unsigned u = __float_as_uint(x);
  unsigned r = (u + 0x7fffu + ((u >> 16) & 1u)) >> 16;
  return (u16)r;
}
__device__ __forceinline__ void split_bf16(float x, u16& h, u16& l) {
  h = bf16rne(x);
  l = bf16rne(x - __uint_as_float(((unsigned)h) << 16));
}
__device__ __forceinline__ float sigm(float x) { return 1.f / (1.f + expf(-x)); }

// X [ROWS x Dd] fp32 -> Xhi, Xlo bf16 (same layout)
__global__ __launch_bounds__(256)
void convert_hilo(const float* __restrict__ src, u16* __restrict__ hi,
                  u16* __restrict__ lo, int n4) {
  for (int i = blockIdx.x * 256 + threadIdx.x; i < n4; i += gridDim.x * 256) {
    const float4 v = ((const float4*)src)[i];
    ushort4 h, l;
    split_bf16(v.x, h.x, l.x);
    split_bf16(v.y, h.y, l.y);
    split_bf16(v.z, h.z, l.z);
    split_bf16(v.w, h.w, l.w);
    ((ushort4*)hi)[i] = h;
    ((ushort4*)lo)[i] = l;
  }
}

// W1 top [Dd x Gg] -> W1T hi/lo [Gg x Dd] bf16  (for gemm1 B operand)
__global__ __launch_bounds__(256)
void convertT_w1(const float* __restrict__ W1, u16* __restrict__ Th,
                 u16* __restrict__ Tl) {
  __shared__ float tl[32][33];
  const int tx = threadIdx.x, ty = threadIdx.y;   // 32, 8
  const int k0 = blockIdx.x * 32, c0 = blockIdx.y * 32;
#pragma unroll
  for (int j = 0; j < 4; ++j)
    tl[ty + j * 8][tx] = W1[(size_t)(k0 + ty + j * 8) * Gg + (c0 + tx)];
  __syncthreads();
#pragma unroll
  for (int j = 0; j < 4; ++j) {
    const float v = tl[tx][ty + j * 8];
    u16 h, l;
    split_bf16(v, h, l);
    const size_t o = (size_t)(c0 + ty + j * 8) * Dd + (k0 + tx);
    Th[o] = h;
    Tl[o] = l;
  }
}

// Wout [Hh x Cc] -> WoutT hi/lo [PC x Hh] (rows >= Cc zero)
__global__ __launch_bounds__(256)
void convert_woutT(const float* __restrict__ Wout, u16* __restrict__ Th,
                   u16* __restrict__ Tl) {
  const int c = blockIdx.x;
  for (int k = threadIdx.x; k < Hh; k += 256) {
    const float v = (c < Cc) ? Wout[k * Cc + c] : 0.f;
    u16 h, l;
    split_bf16(v, h, l);
    Th[c * Hh + k] = h;
    Tl[c * Hh + k] = l;
  }
}

// Recurrent weights, permuted + split:
// WP[cg 128][vc 16][K], vc = g*4 + m for col = g*512 + cg*4 + m.
__global__ __launch_bounds__(256)
void permuteW(const float* __restrict__ src, u16* __restrict__ dh,
              u16* __restrict__ dl, int K) {
  __shared__ float tl[32][33];
  const int tx = threadIdx.x, ty = threadIdx.y;   // 32, 8
  const int k0 = blockIdx.x * 32, c0 = blockIdx.y * 32;
#pragma unroll
  for (int j = 0; j < 4; ++j)
    tl[ty + j * 8][tx] = src[(size_t)(k0 + ty + j * 8) * Gg + (c0 + tx)];
  __syncthreads();
#pragma unroll
  for (int j = 0; j < 4; ++j) {
    const int col = c0 + ty + j * 8;
    const int g = col >> 9, mg = col & 511;
    const int cg = mg >> 2, m = mg & 3;
    const float v = tl[tx][ty + j * 8];
    u16 h, l;
    split_bf16(v, h, l);
    const size_t o = (size_t)(cg * 16 + g * 4 + m) * K + k0 + tx;
    dh[o] = h;
    dl[o] = l;
  }
}

// ---------------- MFMA bf16x3 GEMM: pre = X @ W1 + b1 ----------------
__global__ __launch_bounds__(256)
void gemm1_mfma(const u16* __restrict__ Ah, const u16* __restrict__ Al,
                const u16* __restrict__ Bh, const u16* __restrict__ Bl,
                const float* __restrict__ bias, float* __restrict__ C) {
  __shared__ u16 Ash[128][40];
  __shared__ u16 Asl[128][40];
  __shared__ u16 Bsh[128][40];
  __shared__ u16 Bsl[128][40];
  const int tid  = threadIdx.x;
  const int lane = tid & 63, wave = tid >> 6;
  const int wm = wave >> 1, wn = wave & 1;
  const int l15 = lane & 15, k8 = (lane >> 4) * 8, r4 = (lane >> 4) * 4;
  const int row0 = blockIdx.y * 128, col0 = blockIdx.x * 128;
  const int srow = tid >> 1, sk = (tid & 1) * 16;

  const u16* pAh = Ah + (size_t)(row0 + srow) * Dd + sk;
  const u16* pAl = Al + (size_t)(row0 + srow) * Dd + sk;
  const u16* pBh = Bh + (size_t)(col0 + srow) * Dd + sk;
  const u16* pBl = Bl + (size_t)(col0 + srow) * Dd + sk;

  f32x4 acc[4][4];
#pragma unroll
  for (int i = 0; i < 4; ++i)
#pragma unroll
    for (int j = 0; j < 4; ++j) acc[i][j] = (f32x4){0.f, 0.f, 0.f, 0.f};

  for (int k0 = 0; k0 < Dd; k0 += 32) {
    *(bf16x8*)(&Ash[srow][sk])     = *(const bf16x8*)(pAh + k0);
    *(bf16x8*)(&Ash[srow][sk + 8]) = *(const bf16x8*)(pAh + k0 + 8);
    *(bf16x8*)(&Asl[srow][sk])     = *(const bf16x8*)(pAl + k0);
    *(bf16x8*)(&Asl[srow][sk + 8]) = *(const bf16x8*)(pAl + k0 + 8);
    *(bf16x8*)(&Bsh[srow][sk])     = *(const bf16x8*)(pBh + k0);
    *(bf16x8*)(&Bsh[srow][sk + 8]) = *(const bf16x8*)(pBh + k0 + 8);
    *(bf16x8*)(&Bsl[srow][sk])     = *(const bf16x8*)(pBl + k0);
    *(bf16x8*)(&Bsl[srow][sk + 8]) = *(const bf16x8*)(pBl + k0 + 8);
    __syncthreads();

    bf16x8 afh[4], afl[4], bfh[4], bfl[4];
#pragma unroll
    for (int mt = 0; mt < 4; ++mt) {
      afh[mt] = *(const bf16x8*)(&Ash[wm * 64 + mt * 16 + l15][k8]);
      afl[mt] = *(const bf16x8*)(&Asl[wm * 64 + mt * 16 + l15][k8]);
    }
#pragma unroll
    for (int nt = 0; nt < 4; ++nt) {
      bfh[nt] = *(const bf16x8*)(&Bsh[wn * 64 + nt * 16 + l15][k8]);
      bfl[nt] = *(const bf16x8*)(&Bsl[wn * 64 + nt * 16 + l15][k8]);
    }
#pragma unroll
    for (int mt = 0; mt < 4; ++mt)
#pragma unroll
      for (int nt = 0; nt < 4; ++nt) {
        acc[mt][nt] = __builtin_amdgcn_mfma_f32_16x16x32_bf16(
            afh[mt], bfh[nt], acc[mt][nt], 0, 0, 0);
        acc[mt][nt] = __builtin_amdgcn_mfma_f32_16x16x32_bf16(
            afh[mt], bfl[nt], acc[mt][nt], 0, 0, 0);
        acc[mt][nt] = __builtin_amdgcn_mfma_f32_16x16x32_bf16(
            afl[mt], bfh[nt], acc[mt][nt], 0, 0, 0);
      }
    __syncthreads();
  }

#pragma unroll
  for (int nt = 0; nt < 4; ++nt) {
    const int col = col0 + wn * 64 + nt * 16 + l15;
    const float bj = bias[col];
#pragma unroll
    for (int mt = 0; mt < 4; ++mt) {
      float* Cp = C + (size_t)(row0 + wm * 64 + mt * 16 + r4) * Gg + col;
#pragma unroll
      for (int r = 0; r < 4; ++r)
        Cp[(size_t)r * Gg] = acc[mt][nt][r] + bj;
    }
  }
}

// ---------------- MFMA bf16x3 GEMM: logits = h2 @ WoutT^T + bout --------
__global__ __launch_bounds__(256)
void gemm_proj(const u16* __restrict__ Ah, const u16* __restrict__ Al,
               const u16* __restrict__ Bh, const u16* __restrict__ Bl,
               const float* __restrict__ bout, float* __restrict__ logits) {
  __shared__ u16 Ash[128][40];
  __shared__ u16 Asl[128][40];
  __shared__ u16 Bsh[PC][40];
  __shared__ u16 Bsl[PC][40];
  const int tid  = threadIdx.x;
  const int lane = tid & 63, wave = tid >> 6;
  const int l15 = lane & 15, k8 = (lane >> 4) * 8, r4 = (lane >> 4) * 4;
  const int row0 = blockIdx.x * 128;
  const int srow = tid >> 1, sk = (tid & 1) * 16;

  const u16* pAh = Ah + (size_t)(row0 + srow) * Hh + sk;
  const u16* pAl = Al + (size_t)(row0 + srow) * Hh + sk;
  const u16* pBh = Bh + (size_t)srow * Hh + sk;
  const u16* pBl = Bl + (size_t)srow * Hh + sk;

  f32x4 acc[2][7];
#pragma unroll
  for (int i = 0; i < 2; ++i)
#pragma unroll
    for (int j = 0; j < 7; ++j) acc[i][j] = (f32x4){0.f, 0.f, 0.f, 0.f};

  for (int k0 = 0; k0 < Hh; k0 += 32) {
    *(bf16x8*)(&Ash[srow][sk])     = *(const bf16x8*)(pAh + k0);
    *(bf16x8*)(&Ash[srow][sk + 8]) = *(const bf16x8*)(pAh + k0 + 8);
    *(bf16x8*)(&Asl[srow][sk])     = *(const bf16x8*)(pAl + k0);
    *(bf16x8*)(&Asl[srow][sk + 8]) = *(const bf16x8*)(pAl + k0 + 8);
    if (srow < PC) {
      *(bf16x8*)(&Bsh[srow][sk])     = *(const bf16x8*)(pBh + k0);
      *(bf16x8*)(&Bsh[srow][sk + 8]) = *(const bf16x8*)(pBh + k0 + 8);
      *(bf16x8*)(&Bsl[srow][sk])     = *(const bf16x8*)(pBl + k0);
      *(bf16x8*)(&Bsl[srow][sk + 8]) = *(const bf16x8*)(pBl + k0 + 8);
    }
    __syncthreads();

    bf16x8 afh[2], afl[2], bfh[7], bfl[7];
#pragma unroll
    for (int mt = 0; mt < 2; ++mt) {
      afh[mt] = *(const bf16x8*)(&Ash[wave * 32 + mt * 16 + l15][k8]);
      afl[mt] = *(const bf16x8*)(&Asl[wave * 32 + mt * 16 + l15][k8]);
    }
#pragma unroll
    for (int nt = 0; nt < 7; ++nt) {
      bfh[nt] = *(const bf16x8*)(&Bsh[nt * 16 + l15][k8]);
      bfl[nt] = *(const bf16x8*)(&Bsl[nt * 16 + l15][k8]);
    }
#pragma unroll
    for (int mt = 0; mt < 2; ++mt)
#pragma unroll
      for (int nt = 0; nt < 7; ++nt) {
        acc[mt][nt] = __builtin_amdgcn_mfma_f32_16x16x32_bf16(
            afh[mt], bfh[nt], acc[mt][nt], 0, 0, 0);
        acc[mt][nt] = __builtin_amdgcn_mfma_f32_16x16x32_bf16(
            afh[mt], bfl[nt], acc[mt][nt], 0, 0, 0);
        acc[mt][nt] = __builtin_amdgcn_mfma_f32_16x16x32_bf16(
            afl[mt], bfh[nt], acc[mt][nt], 0, 0, 0);
      }
    __syncthreads();
  }

#pragma unroll
  for (int nt = 0; nt < 7; ++nt) {
    const int col = nt * 16 + l15;
    const float bj = (col < Cc) ? bout[col] : 0.f;
#pragma unroll
    for (int mt = 0; mt < 2; ++mt) {
      float* Lp = logits + (size_t)(row0 + wave * 32 + mt * 16 + r4) * PC + col;
#pragma unroll
      for (int r = 0; r < 4; ++r)
        Lp[(size_t)r * PC] = acc[mt][nt][r] + bj;
    }
  }
}

// ---------------- softmax + CE over logits rows ----------------
__global__ __launch_bounds__(256)
void softmax_ce(const float* __restrict__ logits, const int* __restrict__ labels,
                float* __restrict__ preds, float* __restrict__ ce) {
  const int lane = threadIdx.x & 63, wv = threadIdx.x >> 6;
  const int row = blockIdx.x * 4 + wv;
  const float* lg = logits + (size_t)row * PC;
  const bool a0 = (lane < Cc), a1 = (lane + 64 < Cc);
  const float v0 = a0 ? lg[lane] : -INFINITY;
  const float v1 = a1 ? lg[lane + 64] : -INFINITY;
  float m = fmaxf(v0, v1);
#pragma unroll
  for (int off = 32; off > 0; off >>= 1) m = fmaxf(m, __shfl_xor(m, off));
  const float e0 = a0 ? expf(v0 - m) : 0.f;
  const float e1 = a1 ? expf(v1 - m) : 0.f;
  float s = e0 + e1;
#pragma unroll
  for (int off = 32; off > 0; off >>= 1) s += __shfl_xor(s, off);
  if (a0) preds[(size_t)row * Cc + lane] = e0 / s;
  if (a1) preds[(size_t)row * Cc + lane + 64] = e1 / s;
  const int lab = labels[row];
  if (lab == lane)           ce[row] = logf(s) + m - v0;
  else if (lab == lane + 64) ce[row] = logf(s) + m - v1;
}

// ---------------- SGEMM (fp32 fallback if ws too small) ----------------
#define BM 128
#define BN 128
#define BK 16

__global__ __launch_bounds__(256)
void sgemm_bias(const float* __restrict__ A, const float* __restrict__ B,
                const float* __restrict__ bias, float* __restrict__ C,
                int M, int N, int K) {
  __shared__ float As[BK][BM];
  __shared__ float Bs[BK][BN];
  const int tid  = threadIdx.x;
  const int row0 = blockIdx.y * BM, col0 = blockIdx.x * BN;
  const int tr = (tid >> 4) << 3;
  const int tc = (tid & 15) << 3;

  float acc[8][8];
#pragma unroll
  for (int i = 0; i < 8; ++i)
#pragma unroll
    for (int j = 0; j < 8; ++j) acc[i][j] = 0.f;

  const int arow = tid >> 1;
  const int acol = (tid & 1) << 3;
  const int brow = tid >> 4;
  const int bcol = (tid & 15) << 3;
  const float* Ap = A + (size_t)(row0 + arow) * K + acol;
  const float* Bp = B + (size_t)brow * N + (col0 + bcol);

  for (int k0 = 0; k0 < K; k0 += BK) {
    const float4 a0 = *(const float4*)(Ap + k0);
    const float4 a1 = *(const float4*)(Ap + k0 + 4);
    const float4 bv0 = *(const float4*)(Bp + (size_t)k0 * N);
    const float4 bv1 = *(const float4*)(Bp + (size_t)k0 * N + 4);
    As[acol + 0][arow] = a0.x;
    As[acol + 1][arow] = a0.y;
    As[acol + 2][arow] = a0.z;
    As[acol + 3][arow] = a0.w;
    As[acol + 4][arow] = a1.x;
    As[acol + 5][arow] = a1.y;
    As[acol + 6][arow] = a1.z;
    As[acol + 7][arow] = a1.w;
    *(float4*)(&Bs[brow][bcol])     = bv0;
    *(float4*)(&Bs[brow][bcol + 4]) = bv1;
    __syncthreads();
#pragma unroll
    for (int k = 0; k < BK; ++k) {
      float a[8], b[8];
      *(float4*)(a)     = *(const float4*)(&As[k][tr]);
      *(float4*)(a + 4) = *(const float4*)(&As[k][tr + 4]);
      *(float4*)(b)     = *(const float4*)(&Bs[k][tc]);
      *(float4*)(b + 4) = *(const float4*)(&Bs[k][tc + 4]);
#pragma unroll
      for (int i = 0; i < 8; ++i)
#pragma unroll
        for (int j = 0; j < 8; ++j)
          acc[i][j] = fmaf(a[i], b[j], acc[i][j]);
    }
    __syncthreads();
  }

  float bj[8];
#pragma unroll
  for (int j = 0; j < 8; ++j) bj[j] = bias[col0 + tc + j];
#pragma unroll
  for (int i = 0; i < 8; ++i) {
    float* Cp = C + (size_t)(row0 + tr + i) * N + (col0 + tc);
    float4 o0, o1;
    o0.x = acc[i][0] + bj[0]; o0.y = acc[i][1] + bj[1];
    o0.z = acc[i][2] + bj[2]; o0.w = acc[i][3] + bj[3];
    o1.x = acc[i][4] + bj[4]; o1.y = acc[i][5] + bj[5];
    o1.z = acc[i][6] + bj[6]; o1.w = acc[i][7] + bj[7];
    *(float4*)(Cp)     = o0;
    *(float4*)(Cp + 4) = o1;
  }
}

// ---------------- MFMA fused step v6: 4 blocks/CU ----------------
// Grid 1024: blocks 0..511 = L1 step t, 512..1023 = L2 step t-1.
// Block (bg,cg): 16 batches (bg*16..) x 16 vc cols {g*512 + cg*4 + m}.
// 4 waves = K-quarters (kh); partials summed via ex[4][16][17].
// LDS 38.3 KB -> 4 blocks/CU for deep cross-block latency overlap.
__global__ __launch_bounds__(256, 4)
void fused_step4(const float* __restrict__ pre,
                 const u16* __restrict__ WP1h, const u16* __restrict__ WP1l,
                 const u16* __restrict__ WP2h, const u16* __restrict__ WP2l,
                 const float* __restrict__ b2,
                 u16* __restrict__ h1hi, u16* __restrict__ h1lo,
                 u16* __restrict__ h2hi, u16* __restrict__ h2lo,
                 u16* __restrict__ h2fh, u16* __restrict__ h2fl,
                 float* __restrict__ c1, float* __restrict__ c2, int t) {
  __shared__ u16 Ah[2][16][136], Al[2][16][136];
  __shared__ u16 Bh[2][16][136], Bl[2][16][136];
  __shared__ float ex[4][16][17];   // [kh][batch16][vc]
  const int tid = threadIdx.x;
  const int lane = tid & 63, kh = tid >> 6;   // wave = K-quarter
  const int fr = lane & 15, f8 = (lane >> 4) * 8, r4 = (lane >> 4) * 4;
  const bool isL2 = blockIdx.x >= 512;
  const int idx = blockIdx.x & 511;
  const int cg = idx & 127, bg = idx >> 7;    // 128 col-groups x 4 b-groups
  const int b0 = bg * 16;

  // staging: A/B 16 rows x 128 k-chunk; 16 thr/row, 8 u16/thread
  const int hr = tid >> 4, hk = (tid & 15) * 8;

  f32x4 acc = {0.f, 0.f, 0.f, 0.f};
  bool have = false;
  float p0 = 0.f, p1 = 0.f, p2 = 0.f, p3 = 0.f;

  // epilogue ownership (tid < 64): (batch-local eb, m)
  const int eb = tid >> 2, em = tid & 3;
  const int col = cg * 4 + em;
  const int ci = (b0 + eb) * Hh + col;

  if (!isL2) {
    if (t >= Tt) return;
    if (tid < 64) {  // prefetch pre-gate inputs (hidden under matmul)
      const float* pp = pre + ((size_t)(b0 + eb) * Tt + t) * Gg + col;
      p0 = pp[0]; p1 = pp[512]; p2 = pp[1024]; p3 = pp[1536];
    }
    if (t > 0) {
      const int sl = (t - 1) & 1;
      const u16* A_h = h1hi + (sl << 15) + (b0 + hr) * 512 + hk;
      const u16* A_l = h1lo + (sl << 15) + (b0 + hr) * 512 + hk;
      const u16* B_h = WP1h + (size_t)(cg * 16 + hr) * 512 + hk;
      const u16* B_l = WP1l + (size_t)(cg * 16 + hr) * 512 + hk;

      bf16x8 ra, rl_, rbh, rbl;
      ra = *(const bf16x8*)(A_h);   rl_ = *(const bf16x8*)(A_l);
      rbh = *(const bf16x8*)(B_h);  rbl = *(const bf16x8*)(B_l);
      *(bf16x8*)&Ah[0][hr][hk] = ra;   *(bf16x8*)&Al[0][hr][hk] = rl_;
      *(bf16x8*)&Bh[0][hr][hk] = rbh;  *(bf16x8*)&Bl[0][hr][hk] = rbl;
      __syncthreads();

      for (int kc = 0; kc < 4; ++kc) {
        const int cur = kc & 1;
        if (kc < 3) {
          const int ko = (kc + 1) * 128;
          ra = *(const bf16x8*)(A_h + ko);   rl_ = *(const bf16x8*)(A_l + ko);
          rbh = *(const bf16x8*)(B_h + ko);  rbl = *(const bf16x8*)(B_l + ko);
        }
        {
          const int c0 = kh * 32 + f8;
          const bf16x8 afh = *(const bf16x8*)&Ah[cur][fr][c0];
          const bf16x8 afl = *(const bf16x8*)&Al[cur][fr][c0];
          const bf16x8 bfh = *(const bf16x8*)&Bh[cur][fr][c0];
          const bf16x8 bfl = *(const bf16x8*)&Bl[cur][fr][c0];
          acc = __builtin_amdgcn_mfma_f32_16x16x32_bf16(afh, bfh, acc, 0, 0, 0);
          acc = __builtin_amdgcn_mfma_f32_16x16x32_bf16(afh, bfl, acc, 0, 0, 0);
          acc = __builtin_amdgcn_mfma_f32_16x16x32_bf16(afl, bfh, acc, 0, 0, 0);
        }
        if (kc < 3) {
          const int nb = cur ^ 1;
          *(bf16x8*)&Ah[nb][hr][hk] = ra;   *(bf16x8*)&Al[nb][hr][hk] = rl_;
          *(bf16x8*)&Bh[nb][hr][hk] = rbh;  *(bf16x8*)&Bl[nb][hr][hk] = rbl;
        }
        __syncthreads();
      }
      have = true;
    }
  } else {
    if (t < 1) return;
    // merged K=1024: chunks 0-3 A=h1[t-1], 4-7 A=h2[t-2] (MFMA skipped t<2)
    const u16* A1h = h1hi + (((t - 1) & 1) << 15) + (b0 + hr) * 512 + hk;
    const u16* A1l = h1lo + (((t - 1) & 1) << 15) + (b0 + hr) * 512 + hk;
    const u16* A2h = h2hi + (((t - 2) & 1) << 15) + (b0 + hr) * 512 + hk;
    const u16* A2l = h2lo + (((t - 2) & 1) << 15) + (b0 + hr) * 512 + hk;
    const u16* B_h = WP2h + (size_t)(cg * 16 + hr) * 1024 + hk;
    const u16* B_l = WP2l + (size_t)(cg * 16 + hr) * 1024 + hk;
    const bool h2ok = (t >= 2);

    bf16x8 ra, rl_, rbh, rbl;
    ra = *(const bf16x8*)(A1h);   rl_ = *(const bf16x8*)(A1l);
    rbh = *(const bf16x8*)(B_h);  rbl = *(const bf16x8*)(B_l);
    *(bf16x8*)&Ah[0][hr][hk] = ra;   *(bf16x8*)&Al[0][hr][hk] = rl_;
    *(bf16x8*)&Bh[0][hr][hk] = rbh;  *(bf16x8*)&Bl[0][hr][hk] = rbl;
    __syncthreads();

    for (int kc = 0; kc < 8; ++kc) {
      const int cur = kc & 1;
      if (kc < 7) {
        const int nk = kc + 1;
        const u16* sh  = (nk < 4) ? A1h : A2h;
        const u16* sl2 = (nk < 4) ? A1l : A2l;
        const int ko = (nk & 3) * 128;
        ra = *(const bf16x8*)(sh + ko);    rl_ = *(const bf16x8*)(sl2 + ko);
        rbh = *(const bf16x8*)(B_h + nk * 128);
        rbl = *(const bf16x8*)(B_l + nk * 128);
      }
      if (kc < 4 || h2ok) {
        const int c0 = kh * 32 + f8;
        const bf16x8 afh = *(const bf16x8*)&Ah[cur][fr][c0];
        const bf16x8 afl = *(const bf16x8*)&Al[cur][fr][c0];
        const bf16x8 bfh = *(const bf16x8*)&Bh[cur][fr][c0];
        const bf16x8 bfl = *(const bf16x8*)&Bl[cur][fr][c0];
        acc = __builtin_amdgcn_mfma_f32_16x16x32_bf16(afh, bfh, acc, 0, 0, 0);
        acc = __builtin_amdgcn_mfma_f32_16x16x32_bf16(afh, bfl, acc, 0, 0, 0);
        acc = __builtin_amdgcn_mfma_f32_16x16x32_bf16(afl, bfh, acc, 0, 0, 0);
      }
      if (kc < 7) {
        const int nb = cur ^ 1;
        *(bf16x8*)&Ah[nb][hr][hk] = ra;   *(bf16x8*)&Al[nb][hr][hk] = rl_;
        *(bf16x8*)&Bh[nb][hr][hk] = rbh;  *(bf16x8*)&Bl[nb][hr][hk] = rbl;
      }
      __syncthreads();
    }
    have = true;
  }

  if (have) {
#pragma unroll
    for (int r = 0; r < 4; ++r)
      ex[kh][r4 + r][fr] = acc[r];
  }
  __syncthreads();

  if (tid < 64) {
    float s0 = 0.f, s1 = 0.f, s2 = 0.f, s3 = 0.f;
    if (have) {
#pragma unroll
      for (int q = 0; q < 4; ++q) {
        s0 += ex[q][eb][0 + em];
        s1 += ex[q][eb][4 + em];
        s2 += ex[q][eb][8 + em];
        s3 += ex[q][eb][12 + em];
      }
    }
    if (!isL2) {
      const float gi = p0 + s0, gj = p1 + s1, gf = p2 + s2, go = p3 + s3;
      const float cp = (t > 0) ? c1[ci] : 0.f;
      const float nc = fmaf(cp, sigm(gf + 1.f), sigm(gi) * tanhf(gj));
      c1[ci] = nc;
      const float nh = tanhf(nc) * sigm(go);
      u16 hh, hl;
      split_bf16(nh, hh, hl);
      const int hidx = ((t & 1) << 15) + ci;
      h1hi[hidx] = hh;
      h1lo[hidx] = hl;
    } else {
      const float gi = b2[col] + s0, gj = b2[512 + col] + s1;
      const float gf = b2[1024 + col] + s2, go = b2[1536 + col] + s3;
      const float cp = (t >= 2) ? c2[ci] : 0.f;
      const float nc = fmaf(cp, sigm(gf + 1.f), sigm(gi) * tanhf(gj));
      c2[ci] = nc;
      const float nh = tanhf(nc) * sigm(go);
      u16 hh, hl;
      split_bf16(nh, hh, hl);
      const int hidx = (((t - 1) & 1) << 15) + ci;
      h2hi[hidx] = hh;
      h2lo[hidx] = hl;
      const size_t fo = ((size_t)(b0 + eb) * Tt + (t - 1)) * Hh + col;
      h2fh[fo] = hh;
      h2fl[fo] = hl;
    }
  }
}

__global__ __launch_bounds__(256)
void reduce_cost(const float* __restrict__ ce, float* __restrict__ out) {
  __shared__ float red[256];
  const int tid = threadIdx.x;
  float s = 0.f;
  for (int i = tid; i < ROWS; i += 256) s += ce[i];
  red[tid] = s;
  __syncthreads();
  for (int st = 128; st > 0; st >>= 1) {
    if (tid < st) red[tid] += red[tid + st];
    __syncthreads();
  }
  if (tid == 0) out[0] = red[0] / (float)Bb;
}

// ---------------- launch ----------------
extern "C" void kernel_launch(void* const* d_in, const int* in_sizes, int n_in,
                              void* d_out, int out_size, void* d_ws, size_t ws_size,
                              hipStream_t stream) {
  const float* inputs = (const float*)d_in[0];
  const int*   labels = (const int*)d_in[1];
  const float* W1     = (const float*)d_in[2];
  const float* b1     = (const float*)d_in[3];
  const float* W2     = (const float*)d_in[4];
  const float* b2     = (const float*)d_in[5];
  const float* Wout   = (const float*)d_in[6];
  const float* bout   = (const float*)d_in[7];
  float* out = (float*)d_out;

  float* ws     = (float*)d_ws;
  float* pre    = ws;                              // ROWS*Gg   (16M f32)
  float* c1     = pre    + (size_t)ROWS * Gg;      // 64*512
  float* c2     = c1     + (size_t)Bb * Hh;
  float* ceb    = c2     + (size_t)Bb * Hh;        // ROWS
  float* logits = ceb    + ROWS;                   // ROWS*PC
  u16* h1hi = (u16*)(logits + (size_t)ROWS * PC);  // [2][64][512]
  u16* h1lo = h1hi + 2 * 64 * 512;
  u16* h2hi = h1lo + 2 * 64 * 512;
  u16* h2lo = h2hi + 2 * 64 * 512;
  u16* h2fh = h2lo + 2 * 64 * 512;                 // ROWS*Hh
  u16* h2fl = h2fh + (size_t)ROWS * Hh;
  u16* WP1h = h2fl + (size_t)ROWS * Hh;            // 128*16*512
  u16* WP1l = WP1h + 128 * 16 * 512;
  u16* WP2h = WP1l + 128 * 16 * 512;               // 128*16*1024
  u16* WP2l = WP2h + 128 * 16 * 1024;
  u16* WoTh = WP2l + 128 * 16 * 1024;              // PC*Hh
  u16* WoTl = WoTh + PC * Hh;
  u16* Xhi  = WoTl + PC * Hh;                      // ROWS*Dd
  u16* Xlo  = Xhi  + (size_t)ROWS * Dd;
  u16* W1Th = Xlo  + (size_t)ROWS * Dd;            // Gg*Dd
  u16* W1Tl = W1Th + (size_t)Gg * Dd;
  const size_t need = (size_t)((char*)(W1Tl + (size_t)Gg * Dd) - (char*)d_ws);
  const bool use_mfma = ws_size >= need;

  // weights: permute+split once
  permuteW<<<dim3(16, 64), dim3(32, 8), 0, stream>>>(
      W1 + (size_t)Dd * Gg, WP1h, WP1l, 512);
  permuteW<<<dim3(32, 64), dim3(32, 8), 0, stream>>>(W2, WP2h, WP2l, 1024);
  convert_woutT<<<PC, 256, 0, stream>>>(Wout, WoTh, WoTl);

  // Layer 1 input projection: pre = X @ W1[0:D,:] + b1
  if (use_mfma) {
    convert_hilo<<<2048, 256, 0, stream>>>(inputs, Xhi, Xlo, ROWS * Dd / 4);
    convertT_w1<<<dim3(64, 64), dim3(32, 8), 0, stream>>>(W1, W1Th, W1Tl);
    gemm1_mfma<<<dim3(Gg / 128, ROWS / 128), 256, 0, stream>>>(
        Xhi, Xlo, W1Th, W1Tl, b1, pre);
  } else {
    sgemm_bias<<<dim3(Gg / BN, ROWS / BM), dim3(256), 0, stream>>>(
        inputs, W1, b1, pre, ROWS, Gg, Dd);
  }

  // Recurrence: phase t = L1 step t (blocks 0..511) + L2 step t-1 (512..1023)
  for (int t = 0; t <= Tt; ++t)
    fused_step4<<<1024, 256, 0, stream>>>(pre, WP1h, WP1l, WP2h, WP2l, b2,
                                          h1hi, h1lo, h2hi, h2lo,
                                          h2fh, h2fl, c1, c2, t);

  // Output projection (MFMA) + softmax/CE + cost
  gemm_proj<<<ROWS / 128, 256, 0, stream>>>(h2fh, h2fl, WoTh, WoTl, bout, logits);
  softmax_ce<<<ROWS / 4, 256, 0, stream>>>(logits, labels, out, ceb);
  reduce_cost<<<1, 256, 0, stream>>>(ceb, out + (size_t)ROWS * Cc);
}